// Round 1
// baseline (3864.903 us; speedup 1.0000x reference)
//
#include <hip/hip_runtime.h>
#include <cstddef>

#define NE 32768
#define NM 65536
#define NR 49152
#define NTOT (NE + NM + NR)   /* 147456 */
#define EDGES 262144

// ---------------------------------------------------------------------------
// LayerNorm over all three node types; writes normalized feats to `out`
// (d_out doubles as scratch until the FFN pass overwrites it).
// one wave (64 lanes) per row, 2 floats per lane.
// ---------------------------------------------------------------------------
__global__ __launch_bounds__(256) void ln1_kernel(
    const float* __restrict__ he, const float* __restrict__ hm, const float* __restrict__ hr,
    const float* __restrict__ g, const float* __restrict__ b, float* __restrict__ out)
{
    int row  = blockIdx.x * 4 + (threadIdx.x >> 6);
    int lane = threadIdx.x & 63;
    const float* src; int ti; int lr;
    if (row < NE)           { src = he; ti = 0; lr = row; }
    else if (row < NE + NM) { src = hm; ti = 1; lr = row - NE; }
    else                    { src = hr; ti = 2; lr = row - NE - NM; }
    float2 x = *(const float2*)(src + (size_t)lr * 128 + lane * 2);
    float s = x.x + x.y;
#pragma unroll
    for (int o = 32; o; o >>= 1) s += __shfl_xor(s, o);
    float mean = s * (1.0f / 128.0f);
    float dx = x.x - mean, dy = x.y - mean;
    float v = dx * dx + dy * dy;
#pragma unroll
    for (int o = 32; o; o >>= 1) v += __shfl_xor(v, o);
    float rstd = rsqrtf(v * (1.0f / 128.0f) + 1e-5f);
    int c = lane * 2;
    float2 o2;
    o2.x = g[ti * 128 + c]     * dx * rstd + b[ti * 128 + c];
    o2.y = g[ti * 128 + c + 1] * dy * rstd + b[ti * 128 + c + 1];
    *(float2*)(out + (size_t)row * 128 + c) = o2;
}

// ---------------------------------------------------------------------------
// C[m][j] = sum_k A[m][k] * W[k][j] (+ bias[j]).  M must be a multiple of 64.
// 64-row tile, 256 threads, 4 rows x 8 cols per thread (cols strided by 16 so
// LDS W reads are conflict-free; A tile padded to 132 -> free 2-way).
// ---------------------------------------------------------------------------
template <bool BIAS>
__global__ __launch_bounds__(256) void gemm128(
    const float* __restrict__ A, const float* __restrict__ W,
    const float* __restrict__ bias, float* __restrict__ C)
{
    __shared__ float As[64][132];
    __shared__ float Ws[128][128];
    int t = threadIdx.x;
    size_t row0 = (size_t)blockIdx.x * 64;
    for (int i = t; i < 64 * 32; i += 256) {
        int r = i >> 5, c4 = (i & 31) << 2;
        *(float4*)(&As[r][c4]) = *(const float4*)(A + (row0 + r) * 128 + c4);
    }
    for (int i = t; i < 128 * 32; i += 256) {
        int r = i >> 5, c4 = (i & 31) << 2;
        *(float4*)(&Ws[r][c4]) = *(const float4*)(W + (size_t)r * 128 + c4);
    }
    __syncthreads();
    int tr = t >> 4, tc = t & 15;
    float acc[4][8] = {};
#pragma unroll 2
    for (int k = 0; k < 128; ++k) {
        float a0 = As[tr * 4 + 0][k], a1 = As[tr * 4 + 1][k];
        float a2 = As[tr * 4 + 2][k], a3 = As[tr * 4 + 3][k];
#pragma unroll
        for (int u = 0; u < 8; ++u) {
            float wv = Ws[k][tc + 16 * u];
            acc[0][u] += a0 * wv; acc[1][u] += a1 * wv;
            acc[2][u] += a2 * wv; acc[3][u] += a3 * wv;
        }
    }
#pragma unroll
    for (int r = 0; r < 4; ++r)
#pragma unroll
        for (int u = 0; u < 8; ++u) {
            int col = tc + 16 * u;
            float o = acc[r][u];
            if (BIAS) o += bias[col];
            C[(row0 + tr * 4 + r) * 128 + col] = o;
        }
}

// ---------------------------------------------------------------------------
// Per-node GAT head logits, folded:  ls[n,h] = sum_k X[n,k] * Q[k,h],
// Q[k,h] = sum_d W[k,32h+d] * a[h,d].  Computes src and/or dst logits.
// ---------------------------------------------------------------------------
__global__ __launch_bounds__(256) void node_logits(
    const float* __restrict__ X, const float* __restrict__ W,
    const float* __restrict__ aS, const float* __restrict__ aD,
    float* __restrict__ ls, float* __restrict__ ld)
{
    __shared__ float Q[128][8];
    int t = threadIdx.x;
    for (int i = t; i < 1024; i += 256) {
        int k = i >> 3, q = i & 7, h = q & 3;
        const float* a = (q < 4) ? aS : aD;
        float s = 0.f;
        if (a != nullptr) {
            const float* wr = W + k * 128 + h * 32;
            const float* ar = a + h * 32;
#pragma unroll 8
            for (int d = 0; d < 32; ++d) s += wr[d] * ar[d];
        }
        Q[k][q] = s;
    }
    __syncthreads();
    size_t n = (size_t)blockIdx.x * 256 + t;
    const float* xr = X + n * 128;
    float as[4] = {0, 0, 0, 0}, ad[4] = {0, 0, 0, 0};
    for (int k = 0; k < 128; k += 4) {
        float4 x = *(const float4*)(xr + k);
#pragma unroll
        for (int h = 0; h < 4; ++h) {
            as[h] += x.x * Q[k][h]     + x.y * Q[k + 1][h]     + x.z * Q[k + 2][h]     + x.w * Q[k + 3][h];
            ad[h] += x.x * Q[k][4 + h] + x.y * Q[k + 1][4 + h] + x.z * Q[k + 2][4 + h] + x.w * Q[k + 3][4 + h];
        }
    }
    if (aS) *(float4*)(ls + n * 4) = make_float4(as[0], as[1], as[2], as[3]);
    if (aD) *(float4*)(ld + n * 4) = make_float4(ad[0], ad[1], ad[2], ad[3]);
}

// ---------------------------------------------------------------------------
__global__ __launch_bounds__(256) void deg_kernel(const int* __restrict__ dst,
                                                  unsigned* __restrict__ deg)
{
    int e = blockIdx.x * 256 + threadIdx.x;
    atomicAdd(&deg[dst[e]], 1u);
}

// KineticConv scatter: acc[dst] += P[src] / max(deg[dst],1).  1 wave / edge.
__global__ __launch_bounds__(256) void phys_scatter(
    const int* __restrict__ src, const int* __restrict__ dst,
    const float* __restrict__ P, const unsigned* __restrict__ deg,
    float* __restrict__ acc)
{
    int wid = threadIdx.x >> 6, lane = threadIdx.x & 63;
    int e = blockIdx.x * 4 + wid;
    int s = src[e], d = dst[e];
    unsigned dg = deg[d];
    float inv = 1.0f / (float)(dg ? dg : 1u);
    float2 p = *(const float2*)(P + (size_t)s * 128 + lane * 2);
    float* a = acc + (size_t)d * 128 + lane * 2;
    atomicAdd(a, p.x * inv);
    atomicAdd(a + 1, p.y * inv);
}

// ---------------------------------------------------------------------------
// GAT edge pass A: logits (+edge-feature term via tiny 8x4 M), leaky-relu,
// exp (softmax shift skipped: mathematically identical, logits are ~|0.1|),
// store per-edge exp, atomic-accumulate denominator per (dst, head).
// ---------------------------------------------------------------------------
template <bool HAS_EF>
__global__ __launch_bounds__(256) void gat_edge_a(
    const int* __restrict__ src, const int* __restrict__ dst,
    const float* __restrict__ ls, const float* __restrict__ ld,
    const float* __restrict__ ef, const float* __restrict__ we,
    const float* __restrict__ ae,
    float* __restrict__ exbuf, float* __restrict__ den)
{
    __shared__ float M[8][4];
    int t = threadIdx.x;
    if (HAS_EF) {
        if (t < 32) {
            int f = t >> 2, h = t & 3;
            float s = 0.f;
#pragma unroll 8
            for (int d = 0; d < 32; ++d) s += we[f * 128 + h * 32 + d] * ae[h * 32 + d];
            M[f][h] = s;
        }
        __syncthreads();
    }
    int e = blockIdx.x * 256 + t;
    int s_ = src[e], d_ = dst[e];
    float4 a = *(const float4*)(ls + (size_t)s_ * 4);
    float4 b = *(const float4*)(ld + (size_t)d_ * 4);
    float l[4] = {a.x + b.x, a.y + b.y, a.z + b.z, a.w + b.w};
    if (HAS_EF) {
#pragma unroll
        for (int f = 0; f < 8; ++f) {
            float efv = ef[(size_t)e * 8 + f];
#pragma unroll
            for (int h = 0; h < 4; ++h) l[h] += efv * M[f][h];
        }
    }
    float ex[4];
#pragma unroll
    for (int h = 0; h < 4; ++h) {
        float x = l[h];
        x = (x > 0.f) ? x : 0.2f * x;   // leaky_relu(0.2)
        ex[h] = expf(x);
    }
    *(float4*)(exbuf + (size_t)e * 4) = make_float4(ex[0], ex[1], ex[2], ex[3]);
#pragma unroll
    for (int h = 0; h < 4; ++h) atomicAdd(&den[(size_t)d_ * 4 + h], ex[h]);
}

// GAT edge pass B: acc[dst] += alpha * Z[src].  1 wave / edge, head = lane>>4.
__global__ __launch_bounds__(256) void gat_edge_b(
    const int* __restrict__ src, const int* __restrict__ dst,
    const float* __restrict__ Z, const float* __restrict__ exbuf,
    const float* __restrict__ den, float* __restrict__ acc)
{
    int wid = threadIdx.x >> 6, lane = threadIdx.x & 63;
    int e = blockIdx.x * 4 + wid;
    int s_ = src[e], d_ = dst[e];
    int h = lane >> 4;
    float al = exbuf[(size_t)e * 4 + h] / fmaxf(den[(size_t)d_ * 4 + h], 1e-9f);
    float2 z = *(const float2*)(Z + (size_t)s_ * 128 + lane * 2);
    float* a = acc + (size_t)d_ * 128 + lane * 2;
    atomicAdd(a, al * z.x);
    atomicAdd(a + 1, al * z.y);
}

// ---------------------------------------------------------------------------
// Fused: h_new = h + acc*invC;  out = h_new + W2 GELU(W1 LN(h_new) + b1) + b2.
// 64 rows/block; hidden stays in LDS/regs; W staged in 64-row half tiles.
// LDS total = 2*33.8KB + 32KB = 100.4 KB.
// ---------------------------------------------------------------------------
__global__ __launch_bounds__(256) void ffn_kernel(
    const float* __restrict__ h, const float* __restrict__ acc,
    const float* __restrict__ g, const float* __restrict__ b,
    const float* __restrict__ w1, const float* __restrict__ b1,
    const float* __restrict__ w2, const float* __restrict__ b2,
    float* __restrict__ out, float invC)
{
    __shared__ float HN[64][132];   // h_new, later reused for hidden (post-GELU)
    __shared__ float NB[64][132];   // LN output
    __shared__ float WB[64][128];   // weight half-tile
    int t = threadIdx.x;
    size_t row0 = (size_t)blockIdx.x * 64;

    // step 1: h_new -> LDS + global (residual kept in out)
    for (int i = t; i < 64 * 32; i += 256) {
        int r = i >> 5, c4 = (i & 31) << 2;
        float4 hv = *(const float4*)(h + (row0 + r) * 128 + c4);
        float4 av = *(const float4*)(acc + (row0 + r) * 128 + c4);
        float4 hn;
        hn.x = hv.x + av.x * invC; hn.y = hv.y + av.y * invC;
        hn.z = hv.z + av.z * invC; hn.w = hv.w + av.w * invC;
        *(float4*)(&HN[r][c4]) = hn;
        *(float4*)(out + (row0 + r) * 128 + c4) = hn;
    }
    __syncthreads();

    // step 2: LayerNorm rows (1 wave -> 16 rows)
    int wid = t >> 6, lane = t & 63;
    for (int r = wid; r < 64; r += 4) {
        float x0 = HN[r][lane * 2], x1 = HN[r][lane * 2 + 1];
        float s = x0 + x1;
#pragma unroll
        for (int o = 32; o; o >>= 1) s += __shfl_xor(s, o);
        float mean = s * (1.0f / 128.f);
        float d0 = x0 - mean, d1 = x1 - mean;
        float v = d0 * d0 + d1 * d1;
#pragma unroll
        for (int o = 32; o; o >>= 1) v += __shfl_xor(v, o);
        float rstd = rsqrtf(v * (1.0f / 128.f) + 1e-5f);
        int c = lane * 2;
        NB[r][c]     = g[c] * d0 * rstd + b[c];
        NB[r][c + 1] = g[c + 1] * d1 * rstd + b[c + 1];
    }
    __syncthreads();

    int tr = t >> 4, tc = t & 15;
    float facc[4][8] = {};
    for (int ch = 0; ch < 4; ++ch) {          // 4 chunks of 128 hidden cols
        float hacc[4][8];
#pragma unroll
        for (int r = 0; r < 4; ++r)
#pragma unroll
            for (int u = 0; u < 8; ++u) hacc[r][u] = b1[ch * 128 + tc + 16 * u];

        for (int half = 0; half < 2; ++half) {          // K halves of w1
            for (int i = t; i < 64 * 32; i += 256) {
                int kk = i >> 5, c4 = (i & 31) << 2;
                *(float4*)(&WB[kk][c4]) =
                    *(const float4*)(w1 + (size_t)(half * 64 + kk) * 512 + ch * 128 + c4);
            }
            __syncthreads();
#pragma unroll 2
            for (int kk = 0; kk < 64; ++kk) {
                int k = half * 64 + kk;
                float a0 = NB[tr * 4 + 0][k], a1 = NB[tr * 4 + 1][k];
                float a2 = NB[tr * 4 + 2][k], a3 = NB[tr * 4 + 3][k];
#pragma unroll
                for (int u = 0; u < 8; ++u) {
                    float wv = WB[kk][tc + 16 * u];
                    hacc[0][u] += a0 * wv; hacc[1][u] += a1 * wv;
                    hacc[2][u] += a2 * wv; hacc[3][u] += a3 * wv;
                }
            }
            __syncthreads();
        }
        // exact GELU, hidden -> HN
#pragma unroll
        for (int r = 0; r < 4; ++r)
#pragma unroll
            for (int u = 0; u < 8; ++u) {
                float x = hacc[r][u];
                HN[tr * 4 + r][tc + 16 * u] = 0.5f * x * (1.0f + erff(x * 0.70710678118654752f));
            }
        for (int half = 0; half < 2; ++half) {          // K halves of w2
            __syncthreads();
            for (int i = t; i < 64 * 32; i += 256) {
                int kk = i >> 5, c4 = (i & 31) << 2;
                *(float4*)(&WB[kk][c4]) =
                    *(const float4*)(w2 + (size_t)(ch * 128 + half * 64 + kk) * 128 + c4);
            }
            __syncthreads();
#pragma unroll 2
            for (int kk = 0; kk < 64; ++kk) {
                int k = half * 64 + kk;
                float a0 = HN[tr * 4 + 0][k], a1 = HN[tr * 4 + 1][k];
                float a2 = HN[tr * 4 + 2][k], a3 = HN[tr * 4 + 3][k];
#pragma unroll
                for (int u = 0; u < 8; ++u) {
                    float wv = WB[kk][tc + 16 * u];
                    facc[0][u] += a0 * wv; facc[1][u] += a1 * wv;
                    facc[2][u] += a2 * wv; facc[3][u] += a3 * wv;
                }
            }
        }
        __syncthreads();
    }
#pragma unroll
    for (int r = 0; r < 4; ++r)
#pragma unroll
        for (int u = 0; u < 8; ++u) {
            int col = tc + 16 * u;
            size_t idx = (row0 + tr * 4 + r) * 128 + col;
            out[idx] = out[idx] + facc[r][u] + b2[col];
        }
}

// ---------------------------------------------------------------------------
extern "C" void kernel_launch(void* const* d_in, const int* in_sizes, int n_in,
                              void* d_out, int out_size, void* d_ws, size_t ws_size,
                              hipStream_t stream)
{
    const float* h_enz  = (const float*)d_in[0];
    const float* h_met  = (const float*)d_in[1];
    const float* h_rxn  = (const float*)d_in[2];
    const float* ef_mod = (const float*)d_in[3];
    const float* ef_sig = (const float*)d_in[4];
    const float* ef_brg = (const float*)d_in[5];
    const float* ef_trn = (const float*)d_in[6];
    const float* ln1_g  = (const float*)d_in[7];
    const float* ln1_b  = (const float*)d_in[8];
    const float* ln2_g  = (const float*)d_in[9];
    const float* ln2_b  = (const float*)d_in[10];
    const float* wp     = (const float*)d_in[11];
    const float* bp     = (const float*)d_in[12];
    const float* wl     = (const float*)d_in[13];
    const float* a_src  = (const float*)d_in[14];
    const float* a_dst  = (const float*)d_in[15];
    const float* we     = (const float*)d_in[16];
    const float* a_edge = (const float*)d_in[17];
    const float* w1     = (const float*)d_in[18];
    const float* b1     = (const float*)d_in[19];
    const float* w2     = (const float*)d_in[20];
    const float* b2     = (const float*)d_in[21];
    const int* src_sub  = (const int*)d_in[22];
    const int* dst_sub  = (const int*)d_in[23];
    const int* src_prod = (const int*)d_in[24];
    const int* dst_prod = (const int*)d_in[25];
    const int* src_cat  = (const int*)d_in[26];
    const int* dst_cat  = (const int*)d_in[27];
    const int* src_mod  = (const int*)d_in[28];
    const int* dst_mod  = (const int*)d_in[29];
    const int* src_reg  = (const int*)d_in[30];
    const int* dst_reg  = (const int*)d_in[31];
    const int* src_sig  = (const int*)d_in[32];
    const int* dst_sig  = (const int*)d_in[33];
    const int* src_brg  = (const int*)d_in[34];
    const int* dst_brg  = (const int*)d_in[35];
    const int* src_trn  = (const int*)d_in[36];
    const int* dst_trn  = (const int*)d_in[37];
    float* out = (float*)d_out;

    // workspace layout (116.7 MB total)
    float* acc  = (float*)d_ws;                      // NTOT*128
    float* zbuf = acc + (size_t)NTOT * 128;          // NM*128 (shared proj buffer)
    float* exb  = zbuf + (size_t)NM * 128;           // EDGES*4
    float* den  = exb + (size_t)EDGES * 4;           // NM*4
    float* lsb  = den + (size_t)NM * 4;              // NM*4
    float* ldb  = lsb + (size_t)NM * 4;              // NM*4
    unsigned* deg = (unsigned*)(ldb + (size_t)NM * 4); // NM
    size_t need = ((size_t)NTOT * 128 + (size_t)NM * 128 + (size_t)EDGES * 4 +
                   (size_t)NM * 4 * 3 + (size_t)NM) * 4;
    if (ws_size < need) return;  // fail loudly (output stays poisoned)

    float* norm = out;  // d_out as scratch for normalized features
    const float* n_enz = norm;
    const float* n_met = norm + (size_t)NE * 128;
    const float* n_rxn = norm + (size_t)(NE + NM) * 128;
    float* acc_enz = acc;
    float* acc_met = acc + (size_t)NE * 128;
    float* acc_rxn = acc + (size_t)(NE + NM) * 128;

    hipMemsetAsync(acc, 0, (size_t)NTOT * 128 * sizeof(float), stream);
    ln1_kernel<<<NTOT / 4, 256, 0, stream>>>(h_enz, h_met, h_rxn, ln1_g, ln1_b, norm);

    // ---- phys: substrate_of (met -> rxn), wp[0]
    gemm128<true><<<NM / 64, 256, 0, stream>>>(n_met, wp + 0, bp + 0, zbuf);
    hipMemsetAsync(deg, 0, NR * sizeof(unsigned), stream);
    deg_kernel<<<EDGES / 256, 256, 0, stream>>>(dst_sub, deg);
    phys_scatter<<<EDGES / 4, 256, 0, stream>>>(src_sub, dst_sub, zbuf, deg, acc_rxn);
    // ---- phys: produces (rxn -> met), wp[1]
    gemm128<true><<<NR / 64, 256, 0, stream>>>(n_rxn, wp + 16384, bp + 128, zbuf);
    hipMemsetAsync(deg, 0, NM * sizeof(unsigned), stream);
    deg_kernel<<<EDGES / 256, 256, 0, stream>>>(dst_prod, deg);
    phys_scatter<<<EDGES / 4, 256, 0, stream>>>(src_prod, dst_prod, zbuf, deg, acc_met);
    // ---- phys: catalyzes (enz -> rxn), wp[2]
    gemm128<true><<<NE / 64, 256, 0, stream>>>(n_enz, wp + 2 * 16384, bp + 256, zbuf);
    hipMemsetAsync(deg, 0, NR * sizeof(unsigned), stream);
    deg_kernel<<<EDGES / 256, 256, 0, stream>>>(dst_cat, deg);
    phys_scatter<<<EDGES / 4, 256, 0, stream>>>(src_cat, dst_cat, zbuf, deg, acc_rxn);

    // ---- gat: modulates (enz -> rxn), wl[0], ef_mod/we[0]/ae[0]
    gemm128<false><<<NE / 64, 256, 0, stream>>>(n_enz, wl + 0, nullptr, zbuf);
    node_logits<<<NE / 256, 256, 0, stream>>>(n_enz, wl + 0, a_src + 0, nullptr, lsb, nullptr);
    node_logits<<<NR / 256, 256, 0, stream>>>(n_rxn, wl + 0, nullptr, a_dst + 0, nullptr, ldb);
    hipMemsetAsync(den, 0, (size_t)NR * 4 * sizeof(float), stream);
    gat_edge_a<true><<<EDGES / 256, 256, 0, stream>>>(src_mod, dst_mod, lsb, ldb,
                                                      ef_mod, we + 0, a_edge + 0, exb, den);
    gat_edge_b<<<EDGES / 4, 256, 0, stream>>>(src_mod, dst_mod, zbuf, exb, den, acc_rxn);

    // ---- gat: regulates (enz -> enz), wl[1], no ef
    gemm128<false><<<NE / 64, 256, 0, stream>>>(n_enz, wl + 16384, nullptr, zbuf);
    node_logits<<<NE / 256, 256, 0, stream>>>(n_enz, wl + 16384, a_src + 128, a_dst + 128, lsb, ldb);
    hipMemsetAsync(den, 0, (size_t)NE * 4 * sizeof(float), stream);
    gat_edge_a<false><<<EDGES / 256, 256, 0, stream>>>(src_reg, dst_reg, lsb, ldb,
                                                       nullptr, nullptr, nullptr, exb, den);
    gat_edge_b<<<EDGES / 4, 256, 0, stream>>>(src_reg, dst_reg, zbuf, exb, den, acc_enz);

    // ---- gat: signaling (met -> enz), wl[2], ef_sig/we[1]/ae[1]
    gemm128<false><<<NM / 64, 256, 0, stream>>>(n_met, wl + 2 * 16384, nullptr, zbuf);
    node_logits<<<NM / 256, 256, 0, stream>>>(n_met, wl + 2 * 16384, a_src + 256, nullptr, lsb, nullptr);
    node_logits<<<NE / 256, 256, 0, stream>>>(n_enz, wl + 2 * 16384, nullptr, a_dst + 256, nullptr, ldb);
    hipMemsetAsync(den, 0, (size_t)NE * 4 * sizeof(float), stream);
    gat_edge_a<true><<<EDGES / 256, 256, 0, stream>>>(src_sig, dst_sig, lsb, ldb,
                                                      ef_sig, we + 1024, a_edge + 128, exb, den);
    gat_edge_b<<<EDGES / 4, 256, 0, stream>>>(src_sig, dst_sig, zbuf, exb, den, acc_enz);

    // ---- gat: bridges (met -> met), wl[3], ef_brg/we[2]/ae[2]
    gemm128<false><<<NM / 64, 256, 0, stream>>>(n_met, wl + 3 * 16384, nullptr, zbuf);
    node_logits<<<NM / 256, 256, 0, stream>>>(n_met, wl + 3 * 16384, a_src + 384, a_dst + 384, lsb, ldb);
    hipMemsetAsync(den, 0, (size_t)NM * 4 * sizeof(float), stream);
    gat_edge_a<true><<<EDGES / 256, 256, 0, stream>>>(src_brg, dst_brg, lsb, ldb,
                                                      ef_brg, we + 2048, a_edge + 256, exb, den);
    gat_edge_b<<<EDGES / 4, 256, 0, stream>>>(src_brg, dst_brg, zbuf, exb, den, acc_met);

    // ---- gat: transports_to (met -> met), wl[4], ef_trn/we[3]/ae[3]
    gemm128<false><<<NM / 64, 256, 0, stream>>>(n_met, wl + 4 * 16384, nullptr, zbuf);
    node_logits<<<NM / 256, 256, 0, stream>>>(n_met, wl + 4 * 16384, a_src + 512, a_dst + 512, lsb, ldb);
    hipMemsetAsync(den, 0, (size_t)NM * 4 * sizeof(float), stream);
    gat_edge_a<true><<<EDGES / 256, 256, 0, stream>>>(src_trn, dst_trn, lsb, ldb,
                                                      ef_trn, we + 3072, a_edge + 384, exb, den);
    gat_edge_b<<<EDGES / 4, 256, 0, stream>>>(src_trn, dst_trn, zbuf, exb, den, acc_met);

    // ---- fused combine + LN2 + FFN (+ residual), per node type
    ffn_kernel<<<NE / 64, 256, 0, stream>>>(h_enz, acc_enz, ln2_g + 0, ln2_b + 0,
                                            w1 + 0, b1 + 0, w2 + 0, b2 + 0,
                                            out + 0, 0.5f);
    ffn_kernel<<<NM / 64, 256, 0, stream>>>(h_met, acc_met, ln2_g + 128, ln2_b + 128,
                                            w1 + 65536, b1 + 512, w2 + 65536, b2 + 128,
                                            out + (size_t)NE * 128, 1.0f / 3.0f);
    ffn_kernel<<<NR / 64, 256, 0, stream>>>(h_rxn, acc_rxn, ln2_g + 256, ln2_b + 256,
                                            w1 + 2 * 65536, b1 + 1024, w2 + 2 * 65536, b2 + 256,
                                            out + (size_t)(NE + NM) * 128, 1.0f / 3.0f);
}

// Round 2
// 1581.164 us; speedup vs baseline: 2.4443x; 2.4443x over previous
//
#include <hip/hip_runtime.h>
#include <cstddef>

#define NE 32768
#define NM 65536
#define NR 49152
#define NTOT 147456
#define E2 262144
#define NDPAD 65536
#define RPS 65537
#define W1T_OFF 131072
#define W2T_OFF 327680

typedef __attribute__((ext_vector_type(8))) short bf16x8;
typedef __attribute__((ext_vector_type(4))) float f32x4;

__device__ __forceinline__ unsigned short f2bf(float x) {
    unsigned u = __float_as_uint(x);
    return (unsigned short)((u + 0x7FFFu + ((u >> 16) & 1u)) >> 16);
}
__device__ __forceinline__ float bf2f(unsigned s) {
    return __uint_as_float(s << 16);
}

// ---------------------------------------------------------------------------
// Weight conversion: all matmul weights -> bf16, transposed to [n][k] so MFMA
// B-fragments (lane l: n = l&15, k = (l>>4)*8 + j) are contiguous 16B loads.
// Layout in wbf:
//   [0, 8*16384): square 128x128: mats 0..2 = wp[0..2], 3..7 = wl[0..4]
//   [W1T_OFF, +3*65536): w1t per type  [n(512)][k(128)]
//   [W2T_OFF, +3*65536): w2t per type  [n(128)][k(512)]
// ---------------------------------------------------------------------------
__global__ __launch_bounds__(256) void convw(
    const float* __restrict__ wp, const float* __restrict__ wl,
    const float* __restrict__ w1, const float* __restrict__ w2,
    unsigned short* __restrict__ wbf)
{
    int i = blockIdx.x * 256 + threadIdx.x;
    float v;
    if (i < 131072) {
        int mat = i >> 14, pos = i & 16383;
        int n = pos >> 7, k = pos & 127;
        const float* src = (mat < 3) ? (wp + mat * 16384) : (wl + (mat - 3) * 16384);
        v = src[k * 128 + n];
    } else if (i < 327680) {
        int j = i - 131072; int mat = j >> 16, pos = j & 65535;
        int n = pos >> 7, k = pos & 127;          // n in [0,512)
        v = w1[mat * 65536 + k * 512 + n];
    } else {
        int j = i - 327680; int mat = j >> 16, pos = j & 65535;
        int n = pos >> 9, k = pos & 511;          // n in [0,128), k in [0,512)
        v = w2[mat * 65536 + k * 128 + n];
    }
    wbf[i] = f2bf(v);
}

// ---------------------------------------------------------------------------
// LN1 over all types -> packed bf16 pairs (u32) into d_out-as-scratch.
// ---------------------------------------------------------------------------
__global__ __launch_bounds__(256) void ln1_kernel(
    const float* __restrict__ he, const float* __restrict__ hm, const float* __restrict__ hr,
    const float* __restrict__ g, const float* __restrict__ b, unsigned* __restrict__ nout)
{
    int row  = blockIdx.x * 4 + (threadIdx.x >> 6);
    int lane = threadIdx.x & 63;
    const float* src; int ti; int lr;
    if (row < NE)           { src = he; ti = 0; lr = row; }
    else if (row < NE + NM) { src = hm; ti = 1; lr = row - NE; }
    else                    { src = hr; ti = 2; lr = row - NE - NM; }
    float2 x = *(const float2*)(src + (size_t)lr * 128 + lane * 2);
    float s = x.x + x.y;
#pragma unroll
    for (int o = 32; o; o >>= 1) s += __shfl_xor(s, o);
    float mean = s * (1.0f / 128.0f);
    float dx = x.x - mean, dy = x.y - mean;
    float v = dx * dx + dy * dy;
#pragma unroll
    for (int o = 32; o; o >>= 1) v += __shfl_xor(v, o);
    float rstd = rsqrtf(v * (1.0f / 128.0f) + 1e-5f);
    int c = lane * 2;
    float y0 = g[ti * 128 + c]     * dx * rstd + b[ti * 128 + c];
    float y1 = g[ti * 128 + c + 1] * dy * rstd + b[ti * 128 + c + 1];
    nout[(size_t)row * 64 + lane] = (unsigned)f2bf(y0) | ((unsigned)f2bf(y1) << 16);
}

// ---------------------------------------------------------------------------
// Z[M,128] = A[M,128](bf16) @ W[128,128] (+bias).  Wt given as [n][k] bf16.
// 256 thr = 4 waves; tile 128 rows; wave w: rows w*32..+32, all 128 cols.
// MFMA 16x16x32 bf16: A lane l -> row l&15, k=(l>>4)*8+j ; D: col=l&15+16n,
// row=(l>>4)*4+reg+16r (m89-verified).
// ---------------------------------------------------------------------------
template <bool BIAS>
__global__ __launch_bounds__(256) void gemm_mfma(
    const unsigned short* __restrict__ A, const unsigned short* __restrict__ Wt,
    const float* __restrict__ bias, float* __restrict__ Z)
{
    int t = threadIdx.x, w = t >> 6, l = t & 63;
    int l15 = l & 15, lq = l >> 4;
    size_t row0 = (size_t)blockIdx.x * 128 + w * 32;
    f32x4 acc[2][8];
#pragma unroll
    for (int r = 0; r < 2; ++r)
#pragma unroll
        for (int n = 0; n < 8; ++n) acc[r][n] = (f32x4){0.f, 0.f, 0.f, 0.f};
#pragma unroll
    for (int ks = 0; ks < 4; ++ks) {
        int k0 = ks * 32 + lq * 8;
        bf16x8 a0 = *(const bf16x8*)(A + (row0 + l15) * 128 + k0);
        bf16x8 a1 = *(const bf16x8*)(A + (row0 + 16 + l15) * 128 + k0);
#pragma unroll
        for (int n = 0; n < 8; ++n) {
            bf16x8 bw = *(const bf16x8*)(Wt + (size_t)(n * 16 + l15) * 128 + k0);
            acc[0][n] = __builtin_amdgcn_mfma_f32_16x16x32_bf16(a0, bw, acc[0][n], 0, 0, 0);
            acc[1][n] = __builtin_amdgcn_mfma_f32_16x16x32_bf16(a1, bw, acc[1][n], 0, 0, 0);
        }
    }
#pragma unroll
    for (int n = 0; n < 8; ++n) {
        int col = n * 16 + l15;
        float bv = BIAS ? bias[col] : 0.0f;
#pragma unroll
        for (int r = 0; r < 2; ++r)
#pragma unroll
            for (int reg = 0; reg < 4; ++reg) {
                size_t row = row0 + r * 16 + lq * 4 + reg;
                Z[row * 128 + col] = acc[r][n][reg] + bv;
            }
    }
}

// ---------------------------------------------------------------------------
// Per-node logits from Z: l[n,h] = sum_d Z[n,32h+d] * a[h,d].  1 wave/node.
// ---------------------------------------------------------------------------
__global__ __launch_bounds__(256) void logits_z(
    const float* __restrict__ Z, const float* __restrict__ aS, const float* __restrict__ aD,
    float* __restrict__ ls, float* __restrict__ ld, int n_nodes, int both)
{
    int t = threadIdx.x, w = t >> 6, l = t & 63;
    int h = l >> 4;
    int d0 = (2 * l) & 31;
    float as0 = aS[h * 32 + d0], as1 = aS[h * 32 + d0 + 1];
    float ad0 = 0.f, ad1 = 0.f;
    if (both) { ad0 = aD[h * 32 + d0]; ad1 = aD[h * 32 + d0 + 1]; }
    int n = blockIdx.x * 4 + w;
    if (n >= n_nodes) return;
    float2 z = *(const float2*)(Z + (size_t)n * 128 + 2 * l);
    float ps = z.x * as0 + z.y * as1;
    float pd = z.x * ad0 + z.y * ad1;
#pragma unroll
    for (int o = 8; o; o >>= 1) { ps += __shfl_xor(ps, o); pd += __shfl_xor(pd, o); }
    if ((l & 15) == 0) {
        ls[(size_t)n * 4 + h] = ps;
        if (both) ld[(size_t)n * 4 + h] = pd;
    }
}

// Dst-side logits when dst type != src type: ld = X @ (W . a_d), folded.
__global__ __launch_bounds__(256) void logits_fold(
    const unsigned* __restrict__ X32, const float* __restrict__ W,
    const float* __restrict__ aD, float* __restrict__ ld, int n_nodes)
{
    __shared__ float Q[128][4];
    int t = threadIdx.x;
    if (t < 128) {
#pragma unroll
        for (int hh = 0; hh < 4; ++hh) {
            float s = 0.f;
#pragma unroll 8
            for (int d = 0; d < 32; ++d) s += W[t * 128 + hh * 32 + d] * aD[hh * 32 + d];
            Q[t][hh] = s;
        }
    }
    __syncthreads();
    int w = t >> 6, l = t & 63;
    int n = blockIdx.x * 4 + w;
    if (n >= n_nodes) return;
    unsigned pp = X32[(size_t)n * 64 + l];
    float x0 = bf2f(pp & 0xffffu), x1 = bf2f(pp >> 16);
    float p0 = x0 * Q[2 * l][0] + x1 * Q[2 * l + 1][0];
    float p1 = x0 * Q[2 * l][1] + x1 * Q[2 * l + 1][1];
    float p2 = x0 * Q[2 * l][2] + x1 * Q[2 * l + 1][2];
    float p3 = x0 * Q[2 * l][3] + x1 * Q[2 * l + 1][3];
#pragma unroll
    for (int o = 32; o; o >>= 1) {
        p0 += __shfl_xor(p0, o); p1 += __shfl_xor(p1, o);
        p2 += __shfl_xor(p2, o); p3 += __shfl_xor(p3, o);
    }
    if (l == 0) *(float4*)(ld + (size_t)n * 4) = make_float4(p0, p1, p2, p3);
}

// ---------------------------------------------------------------------------
// Batched CSR build for all 8 relations (dst-side).
// ---------------------------------------------------------------------------
struct P8 { const int* a[8]; };

__global__ __launch_bounds__(256) void hist_all(P8 dsts, unsigned* __restrict__ hist)
{
    int i = blockIdx.x * 256 + threadIdx.x;
    int rel = i >> 18, e = i & (E2 - 1);
    atomicAdd(&hist[(size_t)rel * NDPAD + dsts.a[rel][e]], 1u);
}

__global__ __launch_bounds__(256) void scan1(const unsigned* __restrict__ hist,
                                             unsigned* __restrict__ rowptr,
                                             unsigned* __restrict__ blksum)
{
    __shared__ unsigned s[256];
    int b = blockIdx.x, rel = b >> 8, c = b & 255, t = threadIdx.x;
    unsigned v = hist[(size_t)rel * NDPAD + c * 256 + t];
    s[t] = v; __syncthreads();
    for (int off = 1; off < 256; off <<= 1) {
        unsigned x = (t >= off) ? s[t - off] : 0u;
        __syncthreads();
        s[t] += x;
        __syncthreads();
    }
    rowptr[(size_t)rel * RPS + c * 256 + t] = s[t] - v;   // exclusive (within block)
    if (t == 255) blksum[rel * 256 + c] = s[255];
}

__global__ __launch_bounds__(256) void scan2(unsigned* __restrict__ blksum,
                                             unsigned* __restrict__ rowptr)
{
    __shared__ unsigned s[256];
    int rel = blockIdx.x, t = threadIdx.x;
    unsigned v = blksum[rel * 256 + t];
    s[t] = v; __syncthreads();
    for (int off = 1; off < 256; off <<= 1) {
        unsigned x = (t >= off) ? s[t - off] : 0u;
        __syncthreads();
        s[t] += x;
        __syncthreads();
    }
    blksum[rel * 256 + t] = s[t] - v;                      // exclusive
    if (t == 255) rowptr[(size_t)rel * RPS + 65536] = s[255];
}

__global__ __launch_bounds__(256) void scan3(unsigned* __restrict__ rowptr,
                                             const unsigned* __restrict__ blksum)
{
    int b = blockIdx.x, rel = b >> 8, c = b & 255, t = threadIdx.x;
    rowptr[(size_t)rel * RPS + c * 256 + t] += blksum[rel * 256 + c];
}

__global__ __launch_bounds__(256) void scatter_all(P8 dsts, const unsigned* __restrict__ rowptr,
                                                   unsigned* __restrict__ cur,
                                                   unsigned* __restrict__ eidx)
{
    int i = blockIdx.x * 256 + threadIdx.x;
    int rel = i >> 18, e = i & (E2 - 1);
    int d = dsts.a[rel][e];
    unsigned pos = atomicAdd(&cur[(size_t)rel * NDPAD + d], 1u);
    eidx[(size_t)rel * E2 + rowptr[(size_t)rel * RPS + d] + pos] = (unsigned)e;
}

// ---------------------------------------------------------------------------
// KineticConv gather: acc[d] (+)= mean_{e in seg(d)} Z[src[e]].  1 wave/node.
// acc is packed bf16 pairs (u32/lane).
// ---------------------------------------------------------------------------
__global__ __launch_bounds__(256) void phys_gather(
    const unsigned* __restrict__ rowptr, const unsigned* __restrict__ eidx,
    const int* __restrict__ srcarr, const float* __restrict__ Z,
    unsigned* __restrict__ accp, int n_nodes, int accum)
{
    int t = threadIdx.x, w = t >> 6, l = t & 63;
    int d = blockIdx.x * 4 + w;
    if (d >= n_nodes) return;
    unsigned s0 = rowptr[d], s1 = rowptr[d + 1];
    float r0 = 0.f, r1 = 0.f;
    for (unsigned i = s0; i < s1; ++i) {
        int s = srcarr[eidx[i]];
        float2 z = *(const float2*)(Z + (size_t)s * 128 + 2 * l);
        r0 += z.x; r1 += z.y;
    }
    unsigned dg = s1 - s0;
    float inv = 1.0f / (float)(dg ? dg : 1u);
    r0 *= inv; r1 *= inv;
    unsigned* ap = accp + (size_t)d * 64 + l;
    if (accum) { unsigned o = *ap; r0 += bf2f(o & 0xffffu); r1 += bf2f(o >> 16); }
    *ap = (unsigned)f2bf(r0) | ((unsigned)f2bf(r1) << 16);
}

// ---------------------------------------------------------------------------
// GAT gather: segment softmax (denominator pass + alpha*Z pass, exp recomputed
// identically; max-shift skipped: logits are O(0.1), softmax shift-invariant).
// ---------------------------------------------------------------------------
template <bool HAS_EF>
__global__ __launch_bounds__(256) void gat_gather(
    const unsigned* __restrict__ rowptr, const unsigned* __restrict__ eidx,
    const int* __restrict__ srcarr, const float* __restrict__ Z,
    const float* __restrict__ ls, const float* __restrict__ ld,
    const float* __restrict__ ef, const float* __restrict__ we, const float* __restrict__ ae,
    unsigned* __restrict__ accp, int n_nodes, int accum)
{
    __shared__ float M[8][4];
    int t = threadIdx.x;
    if (HAS_EF) {
        if (t < 32) {
            int f = t >> 2, hh = t & 3;
            float s = 0.f;
#pragma unroll 8
            for (int d2 = 0; d2 < 32; ++d2) s += we[f * 128 + hh * 32 + d2] * ae[hh * 32 + d2];
            M[f][hh] = s;
        }
        __syncthreads();
    }
    int w = t >> 6, l = t & 63, h = l >> 4;
    int d = blockIdx.x * 4 + w;
    if (d >= n_nodes) return;
    unsigned s0 = rowptr[d], s1 = rowptr[d + 1];
    float ldv = ld[(size_t)d * 4 + h];
    float den = 0.f;
    for (unsigned i = s0; i < s1; ++i) {
        unsigned e = eidx[i];
        int s = srcarr[e];
        float lg = ls[(size_t)s * 4 + h] + ldv;
        if (HAS_EF) {
            float4 e0 = *(const float4*)(ef + (size_t)e * 8);
            float4 e1 = *(const float4*)(ef + (size_t)e * 8 + 4);
            lg += e0.x * M[0][h] + e0.y * M[1][h] + e0.z * M[2][h] + e0.w * M[3][h]
                + e1.x * M[4][h] + e1.y * M[5][h] + e1.z * M[6][h] + e1.w * M[7][h];
        }
        lg = lg > 0.f ? lg : 0.2f * lg;
        den += expf(lg);
    }
    float iden = 1.0f / fmaxf(den, 1e-9f);
    float r0 = 0.f, r1 = 0.f;
    for (unsigned i = s0; i < s1; ++i) {
        unsigned e = eidx[i];
        int s = srcarr[e];
        float lg = ls[(size_t)s * 4 + h] + ldv;
        if (HAS_EF) {
            float4 e0 = *(const float4*)(ef + (size_t)e * 8);
            float4 e1 = *(const float4*)(ef + (size_t)e * 8 + 4);
            lg += e0.x * M[0][h] + e0.y * M[1][h] + e0.z * M[2][h] + e0.w * M[3][h]
                + e1.x * M[4][h] + e1.y * M[5][h] + e1.z * M[6][h] + e1.w * M[7][h];
        }
        lg = lg > 0.f ? lg : 0.2f * lg;
        float al = expf(lg) * iden;
        float2 z = *(const float2*)(Z + (size_t)s * 128 + 2 * l);
        r0 += al * z.x; r1 += al * z.y;
    }
    unsigned* ap = accp + (size_t)d * 64 + l;
    if (accum) { unsigned o = *ap; r0 += bf2f(o & 0xffffu); r1 += bf2f(o >> 16); }
    *ap = (unsigned)f2bf(r0) | ((unsigned)f2bf(r1) << 16);
}

// ---------------------------------------------------------------------------
// Fused combine + LN2 + FFN, MFMA version.  64 rows/block, 256 thr = 4 waves.
// LDS: NB (LN out, bf16 packed, swizzled) 16KB + HB (f32, swizzled) 64KB = 80KB
// -> 2 blocks/CU.  Swizzle: idx ^= (row&7)<<2 (16B granules) both sides.
// ---------------------------------------------------------------------------
__global__ __launch_bounds__(256) void ffn_mfma(
    const float* __restrict__ h, const unsigned* __restrict__ accp,
    const float* __restrict__ g, const float* __restrict__ b,
    const unsigned short* __restrict__ w1t, const float* __restrict__ b1,
    const unsigned short* __restrict__ w2t, const float* __restrict__ b2,
    float* __restrict__ out, float invC)
{
    __shared__ unsigned NB[64 * 64];
    __shared__ float HB[64 * 256];
    int t = threadIdx.x, w = t >> 6, l = t & 63;
    int l15 = l & 15, lq = l >> 4;
    size_t row0 = (size_t)blockIdx.x * 64;

    // step 1: h_new = h + acc*invC -> HB (swizzled f32, cols 0..127)
    for (int i = t; i < 64 * 32; i += 256) {
        int r = i >> 5, c4 = (i & 31) << 2;
        float4 hv = *(const float4*)(h + (row0 + r) * 128 + c4);
        unsigned p0 = accp[(row0 + r) * 64 + (c4 >> 1)];
        unsigned p1 = accp[(row0 + r) * 64 + (c4 >> 1) + 1];
        float4 hn;
        hn.x = hv.x + bf2f(p0 & 0xffffu) * invC;
        hn.y = hv.y + bf2f(p0 >> 16) * invC;
        hn.z = hv.z + bf2f(p1 & 0xffffu) * invC;
        hn.w = hv.w + bf2f(p1 >> 16) * invC;
        *(float4*)(&HB[(r * 256 + c4) ^ ((r & 7) << 2)]) = hn;
    }
    __syncthreads();

    // step 2: LN rows -> NB (bf16 pairs, swizzled)
    for (int r = w; r < 64; r += 4) {
        int sw = (r & 7) << 2;
        float2 x = *(const float2*)(&HB[(r * 256 + 2 * l) ^ sw]);
        float s = x.x + x.y;
#pragma unroll
        for (int o = 32; o; o >>= 1) s += __shfl_xor(s, o);
        float mean = s * (1.0f / 128.0f);
        float d0 = x.x - mean, d1 = x.y - mean;
        float v = d0 * d0 + d1 * d1;
#pragma unroll
        for (int o = 32; o; o >>= 1) v += __shfl_xor(v, o);
        float rstd = rsqrtf(v * (1.0f / 128.0f) + 1e-5f);
        float y0 = g[2 * l] * d0 * rstd + b[2 * l];
        float y1 = g[2 * l + 1] * d1 * rstd + b[2 * l + 1];
        NB[(r * 64 + l) ^ sw] = (unsigned)f2bf(y0) | ((unsigned)f2bf(y1) << 16);
    }
    __syncthreads();

    f32x4 facc[8];
#pragma unroll
    for (int n = 0; n < 8; ++n) facc[n] = (f32x4){0.f, 0.f, 0.f, 0.f};
    int swA = (l15 & 7) << 2;

    for (int ch = 0; ch < 2; ++ch) {
        // phase 1: hidden[64][256] = NB @ w1t-cols  (wave w: 64 cols)
        f32x4 acc1[4][4];
#pragma unroll
        for (int rf = 0; rf < 4; ++rf)
#pragma unroll
            for (int nf = 0; nf < 4; ++nf) acc1[rf][nf] = (f32x4){0.f, 0.f, 0.f, 0.f};
#pragma unroll
        for (int ks = 0; ks < 4; ++ks) {
            int k0 = ks * 32 + lq * 8;
            bf16x8 af[4];
#pragma unroll
            for (int rf = 0; rf < 4; ++rf) {
                int row = rf * 16 + l15;
                af[rf] = *(const bf16x8*)(&NB[(row * 64 + (k0 >> 1)) ^ swA]);
            }
#pragma unroll
            for (int nf = 0; nf < 4; ++nf) {
                int col = ch * 256 + w * 64 + nf * 16 + l15;
                bf16x8 bw = *(const bf16x8*)(w1t + (size_t)col * 128 + k0);
#pragma unroll
                for (int rf = 0; rf < 4; ++rf)
                    acc1[rf][nf] = __builtin_amdgcn_mfma_f32_16x16x32_bf16(af[rf], bw, acc1[rf][nf], 0, 0, 0);
            }
        }
        __syncthreads();   // previous HB readers (step2 / prev phase2) done
        // GELU(hidden)+b1 -> HB (swizzled)
#pragma unroll
        for (int rf = 0; rf < 4; ++rf)
#pragma unroll
            for (int nf = 0; nf < 4; ++nf)
#pragma unroll
                for (int reg = 0; reg < 4; ++reg) {
                    int row = rf * 16 + lq * 4 + reg;
                    int col = w * 64 + nf * 16 + l15;
                    float x = acc1[rf][nf][reg] + b1[ch * 256 + col];
                    float ge = 0.5f * x * (1.0f + erff(x * 0.70710678118654752f));
                    HB[(row * 256 + col) ^ ((row & 7) << 2)] = ge;
                }
        __syncthreads();
        // phase 2: out += hidden_bf16 @ w2t  (wave w: rows 16w..16w+16)
        int rowA = w * 16 + l15;
        int swH = (rowA & 7) << 2;
#pragma unroll
        for (int ks = 0; ks < 8; ++ks) {
            int k0 = ks * 32 + lq * 8;
            int base = rowA * 256 + k0;
            f32x4 h0 = *(const f32x4*)(&HB[base ^ swH]);
            f32x4 h1 = *(const f32x4*)(&HB[(base + 4) ^ swH]);
            union { bf16x8 v; unsigned short u[8]; } cv;
#pragma unroll
            for (int j = 0; j < 4; ++j) { cv.u[j] = f2bf(h0[j]); cv.u[4 + j] = f2bf(h1[j]); }
#pragma unroll
            for (int nf = 0; nf < 8; ++nf) {
                bf16x8 bw = *(const bf16x8*)(w2t + (size_t)(nf * 16 + l15) * 512 + ch * 256 + k0);
                facc[nf] = __builtin_amdgcn_mfma_f32_16x16x32_bf16(cv.v, bw, facc[nf], 0, 0, 0);
            }
        }
    }
    // epilogue: out = h_new + ffn + b2 (h_new recomputed -> no global RMW fence)
#pragma unroll
    for (int nf = 0; nf < 8; ++nf)
#pragma unroll
        for (int reg = 0; reg < 4; ++reg) {
            int row = w * 16 + lq * 4 + reg;
            int col = nf * 16 + l15;
            size_t gi = (row0 + row) * 128 + col;
            unsigned pp = accp[(row0 + row) * 64 + (col >> 1)];
            float av = bf2f((col & 1) ? (pp >> 16) : (pp & 0xffffu));
            out[gi] = h[gi] + av * invC + facc[nf][reg] + b2[col];
        }
}

// ---------------------------------------------------------------------------
extern "C" void kernel_launch(void* const* d_in, const int* in_sizes, int n_in,
                              void* d_out, int out_size, void* d_ws, size_t ws_size,
                              hipStream_t stream)
{
    const float* h_enz  = (const float*)d_in[0];
    const float* h_met  = (const float*)d_in[1];
    const float* h_rxn  = (const float*)d_in[2];
    const float* ef_mod = (const float*)d_in[3];
    const float* ef_sig = (const float*)d_in[4];
    const float* ef_brg = (const float*)d_in[5];
    const float* ef_trn = (const float*)d_in[6];
    const float* ln1_g  = (const float*)d_in[7];
    const float* ln1_b  = (const float*)d_in[8];
    const float* ln2_g  = (const float*)d_in[9];
    const float* ln2_b  = (const float*)d_in[10];
    const float* wp     = (const float*)d_in[11];
    const float* bp     = (const float*)d_in[12];
    const float* wl     = (const float*)d_in[13];
    const float* a_src  = (const float*)d_in[14];
    const float* a_dst  = (const float*)d_in[15];
    const float* we     = (const float*)d_in[16];
    const float* a_edge = (const float*)d_in[17];
    const float* w1     = (const float*)d_in[18];
    const float* b1     = (const float*)d_in[19];
    const float* w2     = (const float*)d_in[20];
    const float* b2     = (const float*)d_in[21];
    const int* src_sub  = (const int*)d_in[22];
    const int* dst_sub  = (const int*)d_in[23];
    const int* src_prod = (const int*)d_in[24];
    const int* dst_prod = (const int*)d_in[25];
    const int* src_cat  = (const int*)d_in[26];
    const int* dst_cat  = (const int*)d_in[27];
    const int* src_mod  = (const int*)d_in[28];
    const int* dst_mod  = (const int*)d_in[29];
    const int* src_reg  = (const int*)d_in[30];
    const int* dst_reg  = (const int*)d_in[31];
    const int* src_sig  = (const int*)d_in[32];
    const int* dst_sig  = (const int*)d_in[33];
    const int* src_brg  = (const int*)d_in[34];
    const int* dst_brg  = (const int*)d_in[35];
    const int* src_trn  = (const int*)d_in[36];
    const int* dst_trn  = (const int*)d_in[37];
    float* out = (float*)d_out;

    // workspace layout (~87 MB; round-1 proved ws_size >= 116.6 MB)
    char* p = (char*)d_ws;
    unsigned short* accbf = (unsigned short*)p;  p += (size_t)NTOT * 128 * 2;
    float* zbuf = (float*)p;                     p += (size_t)NM * 128 * 4;
    float* lsb  = (float*)p;                     p += (size_t)NM * 4 * 4;
    float* ldb  = (float*)p;                     p += (size_t)NM * 4 * 4;
    unsigned short* wbf = (unsigned short*)p;    p += (size_t)524288 * 2;
    unsigned* hist = (unsigned*)p;               p += (size_t)8 * NDPAD * 4;
    unsigned* rowptr = (unsigned*)p;             p += (size_t)8 * RPS * 4;
    unsigned* eidx = (unsigned*)p;               p += (size_t)8 * E2 * 4;
    unsigned* blksum = (unsigned*)p;             p += (size_t)8 * 256 * 4;
    if (ws_size < (size_t)(p - (char*)d_ws)) return;

    // normalized features (bf16 packed) live in d_out-as-scratch until FFN
    unsigned* nrm32 = (unsigned*)d_out;
    const unsigned short* nbf_enz = (const unsigned short*)d_out;
    const unsigned short* nbf_met = nbf_enz + (size_t)NE * 128;
    const unsigned short* nbf_rxn = nbf_enz + (size_t)(NE + NM) * 128;
    const unsigned* n32_enz = (const unsigned*)nbf_enz;
    const unsigned* n32_rxn = (const unsigned*)nbf_rxn;
    unsigned* acc_enz = (unsigned*)accbf;
    unsigned* acc_met = acc_enz + (size_t)NE * 64;
    unsigned* acc_rxn = acc_enz + (size_t)(NE + NM) * 64;

    P8 dsts;
    dsts.a[0] = dst_sub; dsts.a[1] = dst_prod; dsts.a[2] = dst_cat; dsts.a[3] = dst_mod;
    dsts.a[4] = dst_reg; dsts.a[5] = dst_sig;  dsts.a[6] = dst_brg; dsts.a[7] = dst_trn;

    // ---- prep: weights, LN1, CSR for all 8 relations
    hipMemsetAsync(hist, 0, (size_t)8 * NDPAD * 4, stream);
    convw<<<2048, 256, 0, stream>>>(wp, wl, w1, w2, wbf);
    ln1_kernel<<<NTOT / 4, 256, 0, stream>>>(h_enz, h_met, h_rxn, ln1_g, ln1_b, nrm32);
    hist_all<<<8192, 256, 0, stream>>>(dsts, hist);
    scan1<<<2048, 256, 0, stream>>>(hist, rowptr, blksum);
    scan2<<<8, 256, 0, stream>>>(blksum, rowptr);
    scan3<<<2048, 256, 0, stream>>>(rowptr, blksum);
    hipMemsetAsync(hist, 0, (size_t)8 * NDPAD * 4, stream);
    scatter_all<<<8192, 256, 0, stream>>>(dsts, rowptr, hist, eidx);

#define RP(r) (rowptr + (size_t)(r) * RPS)
#define EI(r) (eidx + (size_t)(r) * E2)

    // ---- rel 0: substrate_of (met->rxn), wp0
    gemm_mfma<true><<<NM / 128, 256, 0, stream>>>(nbf_met, wbf + 0 * 16384, bp + 0, zbuf);
    phys_gather<<<NR / 4, 256, 0, stream>>>(RP(0), EI(0), src_sub, zbuf, acc_rxn, NR, 0);
    // ---- rel 1: produces (rxn->met), wp1
    gemm_mfma<true><<<NR / 128, 256, 0, stream>>>(nbf_rxn, wbf + 1 * 16384, bp + 128, zbuf);
    phys_gather<<<NM / 4, 256, 0, stream>>>(RP(1), EI(1), src_prod, zbuf, acc_met, NM, 0);
    // ---- rel 2: catalyzes (enz->rxn), wp2
    gemm_mfma<true><<<NE / 128, 256, 0, stream>>>(nbf_enz, wbf + 2 * 16384, bp + 256, zbuf);
    phys_gather<<<NR / 4, 256, 0, stream>>>(RP(2), EI(2), src_cat, zbuf, acc_rxn, NR, 1);

    // ---- rel 3: modulates (enz->rxn), wl0, ef_mod/we0/ae0
    gemm_mfma<false><<<NE / 128, 256, 0, stream>>>(nbf_enz, wbf + 3 * 16384, nullptr, zbuf);
    logits_z<<<NE / 4, 256, 0, stream>>>(zbuf, a_src + 0, nullptr, lsb, nullptr, NE, 0);
    logits_fold<<<NR / 4, 256, 0, stream>>>(n32_rxn, wl + 0, a_dst + 0, ldb, NR);
    gat_gather<true><<<NR / 4, 256, 0, stream>>>(RP(3), EI(3), src_mod, zbuf, lsb, ldb,
                                                 ef_mod, we + 0, a_edge + 0, acc_rxn, NR, 1);
    // ---- rel 4: regulates (enz->enz), wl1, no ef
    gemm_mfma<false><<<NE / 128, 256, 0, stream>>>(nbf_enz, wbf + 4 * 16384, nullptr, zbuf);
    logits_z<<<NE / 4, 256, 0, stream>>>(zbuf, a_src + 128, a_dst + 128, lsb, ldb, NE, 1);
    gat_gather<false><<<NE / 4, 256, 0, stream>>>(RP(4), EI(4), src_reg, zbuf, lsb, ldb,
                                                  nullptr, nullptr, nullptr, acc_enz, NE, 0);
    // ---- rel 5: signaling (met->enz), wl2, ef_sig/we1/ae1
    gemm_mfma<false><<<NM / 128, 256, 0, stream>>>(nbf_met, wbf + 5 * 16384, nullptr, zbuf);
    logits_z<<<NM / 4, 256, 0, stream>>>(zbuf, a_src + 256, nullptr, lsb, nullptr, NM, 0);
    logits_fold<<<NE / 4, 256, 0, stream>>>(n32_enz, wl + 2 * 16384, a_dst + 256, ldb, NE);
    gat_gather<true><<<NE / 4, 256, 0, stream>>>(RP(5), EI(5), src_sig, zbuf, lsb, ldb,
                                                 ef_sig, we + 1024, a_edge + 128, acc_enz, NE, 1);
    // ---- rel 6: bridges (met->met), wl3, ef_brg/we2/ae2
    gemm_mfma<false><<<NM / 128, 256, 0, stream>>>(nbf_met, wbf + 6 * 16384, nullptr, zbuf);
    logits_z<<<NM / 4, 256, 0, stream>>>(zbuf, a_src + 384, a_dst + 384, lsb, ldb, NM, 1);
    gat_gather<true><<<NM / 4, 256, 0, stream>>>(RP(6), EI(6), src_brg, zbuf, lsb, ldb,
                                                 ef_brg, we + 2048, a_edge + 256, acc_met, NM, 1);
    // ---- rel 7: transports_to (met->met), wl4, ef_trn/we3/ae3
    gemm_mfma<false><<<NM / 128, 256, 0, stream>>>(nbf_met, wbf + 7 * 16384, nullptr, zbuf);
    logits_z<<<NM / 4, 256, 0, stream>>>(zbuf, a_src + 512, a_dst + 512, lsb, ldb, NM, 1);
    gat_gather<true><<<NM / 4, 256, 0, stream>>>(RP(7), EI(7), src_trn, zbuf, lsb, ldb,
                                                 ef_trn, we + 3072, a_edge + 384, acc_met, NM, 1);

    // ---- fused combine + LN2 + FFN (+residual), per node type
    ffn_mfma<<<NE / 64, 256, 0, stream>>>(h_enz, acc_enz, ln2_g + 0, ln2_b + 0,
                                          wbf + W1T_OFF + 0 * 65536, b1 + 0,
                                          wbf + W2T_OFF + 0 * 65536, b2 + 0,
                                          out + 0, 0.5f);
    ffn_mfma<<<NM / 64, 256, 0, stream>>>(h_met, acc_met, ln2_g + 128, ln2_b + 128,
                                          wbf + W1T_OFF + 1 * 65536, b1 + 512,
                                          wbf + W2T_OFF + 1 * 65536, b2 + 128,
                                          out + (size_t)NE * 128, 1.0f / 3.0f);
    ffn_mfma<<<NR / 64, 256, 0, stream>>>(h_rxn, acc_rxn, ln2_g + 256, ln2_b + 256,
                                          wbf + W1T_OFF + 2 * 65536, b1 + 1024,
                                          wbf + W2T_OFF + 2 * 65536, b2 + 256,
                                          out + (size_t)(NE + NM) * 128, 1.0f / 3.0f);
#undef RP
#undef EI
}

// Round 3
// 1294.649 us; speedup vs baseline: 2.9853x; 1.2213x over previous
//
#include <hip/hip_runtime.h>
#include <cstddef>

#define NE 32768
#define NM 65536
#define NR 49152
#define NTOT 147456
#define E2 262144
#define NDPAD 65536
#define RPS 65537
#define W1T_OFF 131072
#define W2T_OFF 327680

typedef __attribute__((ext_vector_type(8))) short bf16x8;
typedef __attribute__((ext_vector_type(4))) float f32x4;

__device__ __forceinline__ unsigned short f2bf(float x) {
    unsigned u = __float_as_uint(x);
    return (unsigned short)((u + 0x7FFFu + ((u >> 16) & 1u)) >> 16);
}
__device__ __forceinline__ float bf2f(unsigned s) { return __uint_as_float(s << 16); }
__device__ __forceinline__ unsigned pk2(float a, float b) {
    return (unsigned)f2bf(a) | ((unsigned)f2bf(b) << 16);
}
__device__ __forceinline__ bf16x8 pack8(const float* v) {
    union { bf16x8 b; unsigned u[4]; } r;
#pragma unroll
    for (int i = 0; i < 4; ++i) r.u[i] = pk2(v[2 * i], v[2 * i + 1]);
    return r.b;
}

// ---------------------------------------------------------------------------
// Weights -> bf16 transposed [n][k] (square: wp0..2, wl0..4; then w1t, w2t).
// ---------------------------------------------------------------------------
__global__ __launch_bounds__(256) void convw(
    const float* __restrict__ wp, const float* __restrict__ wl,
    const float* __restrict__ w1, const float* __restrict__ w2,
    unsigned short* __restrict__ wbf)
{
    int i = blockIdx.x * 256 + threadIdx.x;
    float v;
    if (i < 131072) {
        int mat = i >> 14, pos = i & 16383;
        int n = pos >> 7, k = pos & 127;
        const float* src = (mat < 3) ? (wp + mat * 16384) : (wl + (mat - 3) * 16384);
        v = src[k * 128 + n];
    } else if (i < 327680) {
        int j = i - 131072; int mat = j >> 16, pos = j & 65535;
        int n = pos >> 7, k = pos & 127;
        v = w1[mat * 65536 + k * 512 + n];
    } else {
        int j = i - 327680; int mat = j >> 16, pos = j & 65535;
        int n = pos >> 9, k = pos & 511;
        v = w2[mat * 65536 + k * 128 + n];
    }
    wbf[i] = f2bf(v);
}

// ---------------------------------------------------------------------------
// LN1 -> packed bf16 pairs (standard col order) into d_out-as-scratch.
// ---------------------------------------------------------------------------
__global__ __launch_bounds__(256) void ln1_kernel(
    const float* __restrict__ he, const float* __restrict__ hm, const float* __restrict__ hr,
    const float* __restrict__ g, const float* __restrict__ b, unsigned* __restrict__ nout)
{
    int row  = blockIdx.x * 4 + (threadIdx.x >> 6);
    int lane = threadIdx.x & 63;
    const float* src; int ti; int lr;
    if (row < NE)           { src = he; ti = 0; lr = row; }
    else if (row < NE + NM) { src = hm; ti = 1; lr = row - NE; }
    else                    { src = hr; ti = 2; lr = row - NE - NM; }
    float2 x = *(const float2*)(src + (size_t)lr * 128 + lane * 2);
    float s = x.x + x.y;
#pragma unroll
    for (int o = 32; o; o >>= 1) s += __shfl_xor(s, o);
    float mean = s * (1.0f / 128.0f);
    float dx = x.x - mean, dy = x.y - mean;
    float v = dx * dx + dy * dy;
#pragma unroll
    for (int o = 32; o; o >>= 1) v += __shfl_xor(v, o);
    float rstd = rsqrtf(v * (1.0f / 128.0f) + 1e-5f);
    int c = lane * 2;
    float y0 = g[ti * 128 + c]     * dx * rstd + b[ti * 128 + c];
    float y1 = g[ti * 128 + c + 1] * dy * rstd + b[ti * 128 + c + 1];
    nout[(size_t)row * 64 + lane] = pk2(y0, y1);
}

// ---------------------------------------------------------------------------
// GEMM + optional bias + optional fused src/dst logits.
// Z stored packed bf16: u32[row][64], u32 p -> cols (p, p+64).
// LOG: 0 none, 1 src logits, 2 src+dst logits.
// ---------------------------------------------------------------------------
template <int LOG, bool BIAS>
__global__ __launch_bounds__(256) void gemm_mfma(
    const unsigned short* __restrict__ A, const unsigned short* __restrict__ Wt,
    const float* __restrict__ bias, unsigned* __restrict__ Zp,
    const float* __restrict__ aS, const float* __restrict__ aD,
    float* __restrict__ ls, float* __restrict__ ld)
{
    int t = threadIdx.x, w = t >> 6, l = t & 63;
    int l15 = l & 15, lq = l >> 4;
    size_t row0 = (size_t)blockIdx.x * 128 + w * 32;
    f32x4 acc[2][8];
#pragma unroll
    for (int r = 0; r < 2; ++r)
#pragma unroll
        for (int n = 0; n < 8; ++n) acc[r][n] = (f32x4){0.f, 0.f, 0.f, 0.f};
#pragma unroll
    for (int ks = 0; ks < 4; ++ks) {
        int k0 = ks * 32 + lq * 8;
        bf16x8 a0 = *(const bf16x8*)(A + (row0 + l15) * 128 + k0);
        bf16x8 a1 = *(const bf16x8*)(A + (row0 + 16 + l15) * 128 + k0);
#pragma unroll
        for (int n = 0; n < 8; ++n) {
            bf16x8 bw = *(const bf16x8*)(Wt + (size_t)(n * 16 + l15) * 128 + k0);
            acc[0][n] = __builtin_amdgcn_mfma_f32_16x16x32_bf16(a0, bw, acc[0][n], 0, 0, 0);
            acc[1][n] = __builtin_amdgcn_mfma_f32_16x16x32_bf16(a1, bw, acc[1][n], 0, 0, 0);
        }
    }
    // store Zp: pack (col, col+64) = (n, n+4)
#pragma unroll
    for (int n = 0; n < 4; ++n) {
        float bl = BIAS ? bias[n * 16 + l15] : 0.f;
        float bh = BIAS ? bias[n * 16 + l15 + 64] : 0.f;
#pragma unroll
        for (int r = 0; r < 2; ++r)
#pragma unroll
            for (int reg = 0; reg < 4; ++reg) {
                size_t row = row0 + r * 16 + lq * 4 + reg;
                Zp[row * 64 + n * 16 + l15] = pk2(acc[r][n][reg] + bl, acc[r][n + 4][reg] + bh);
            }
    }
    if constexpr (LOG >= 1) {
        float asl[4], ash[4], adl[4], adh[4];
#pragma unroll
        for (int h = 0; h < 4; ++h) {
            asl[h] = aS[h * 32 + l15]; ash[h] = aS[h * 32 + 16 + l15];
            if constexpr (LOG == 2) { adl[h] = aD[h * 32 + l15]; adh[h] = aD[h * 32 + 16 + l15]; }
        }
#pragma unroll
        for (int r = 0; r < 2; ++r)
#pragma unroll
            for (int reg = 0; reg < 4; ++reg) {
                float ps[4], pd[4];
#pragma unroll
                for (int h = 0; h < 4; ++h) {
                    ps[h] = acc[r][2 * h][reg] * asl[h] + acc[r][2 * h + 1][reg] * ash[h];
                    if constexpr (LOG == 2)
                        pd[h] = acc[r][2 * h][reg] * adl[h] + acc[r][2 * h + 1][reg] * adh[h];
                }
#pragma unroll
                for (int o = 1; o < 16; o <<= 1) {
#pragma unroll
                    for (int h = 0; h < 4; ++h) {
                        ps[h] += __shfl_xor(ps[h], o);
                        if constexpr (LOG == 2) pd[h] += __shfl_xor(pd[h], o);
                    }
                }
                if (l15 == 0) {
                    size_t row = row0 + r * 16 + lq * 4 + reg;
                    *(float4*)(ls + row * 4) = make_float4(ps[0], ps[1], ps[2], ps[3]);
                    if constexpr (LOG == 2)
                        *(float4*)(ld + row * 4) = make_float4(pd[0], pd[1], pd[2], pd[3]);
                }
            }
    }
}

// Dst logits when dst type != src type: ld = X @ (W . a_d), folded.
__global__ __launch_bounds__(256) void logits_fold(
    const unsigned* __restrict__ X32, const float* __restrict__ W,
    const float* __restrict__ aD, float* __restrict__ ld, int n_nodes)
{
    __shared__ float Q[128][4];
    int t = threadIdx.x;
    if (t < 128) {
#pragma unroll
        for (int hh = 0; hh < 4; ++hh) {
            float s = 0.f;
#pragma unroll 8
            for (int d = 0; d < 32; ++d) s += W[t * 128 + hh * 32 + d] * aD[hh * 32 + d];
            Q[t][hh] = s;
        }
    }
    __syncthreads();
    int w = t >> 6, l = t & 63;
    int n = blockIdx.x * 4 + w;
    if (n >= n_nodes) return;
    unsigned pp = X32[(size_t)n * 64 + l];
    float x0 = bf2f(pp & 0xffffu), x1 = bf2f(pp >> 16);
    float p0 = x0 * Q[2 * l][0] + x1 * Q[2 * l + 1][0];
    float p1 = x0 * Q[2 * l][1] + x1 * Q[2 * l + 1][1];
    float p2 = x0 * Q[2 * l][2] + x1 * Q[2 * l + 1][2];
    float p3 = x0 * Q[2 * l][3] + x1 * Q[2 * l + 1][3];
#pragma unroll
    for (int o = 32; o; o >>= 1) {
        p0 += __shfl_xor(p0, o); p1 += __shfl_xor(p1, o);
        p2 += __shfl_xor(p2, o); p3 += __shfl_xor(p3, o);
    }
    if (l == 0) *(float4*)(ld + (size_t)n * 4) = make_float4(p0, p1, p2, p3);
}

// ---------------------------------------------------------------------------
// Batched CSR build (dst-side), value = src id (+ edge id).
// ---------------------------------------------------------------------------
struct P8 { const int* a[8]; };

__global__ __launch_bounds__(256) void hist_all(P8 dsts, unsigned* __restrict__ hist)
{
    int i = blockIdx.x * 256 + threadIdx.x;
    int rel = i >> 18, e = i & (E2 - 1);
    atomicAdd(&hist[(size_t)rel * NDPAD + dsts.a[rel][e]], 1u);
}

__global__ __launch_bounds__(256) void scan1(const unsigned* __restrict__ hist,
                                             unsigned* __restrict__ rowptr,
                                             unsigned* __restrict__ blksum)
{
    __shared__ unsigned s[256];
    int b = blockIdx.x, rel = b >> 8, c = b & 255, t = threadIdx.x;
    unsigned v = hist[(size_t)rel * NDPAD + c * 256 + t];
    s[t] = v; __syncthreads();
    for (int off = 1; off < 256; off <<= 1) {
        unsigned x = (t >= off) ? s[t - off] : 0u;
        __syncthreads();
        s[t] += x;
        __syncthreads();
    }
    rowptr[(size_t)rel * RPS + c * 256 + t] = s[t] - v;
    if (t == 255) blksum[rel * 256 + c] = s[255];
}

__global__ __launch_bounds__(256) void scan2(unsigned* __restrict__ blksum,
                                             unsigned* __restrict__ rowptr)
{
    __shared__ unsigned s[256];
    int rel = blockIdx.x, t = threadIdx.x;
    unsigned v = blksum[rel * 256 + t];
    s[t] = v; __syncthreads();
    for (int off = 1; off < 256; off <<= 1) {
        unsigned x = (t >= off) ? s[t - off] : 0u;
        __syncthreads();
        s[t] += x;
        __syncthreads();
    }
    blksum[rel * 256 + t] = s[t] - v;
    if (t == 255) rowptr[(size_t)rel * RPS + 65536] = s[255];
}

__global__ __launch_bounds__(256) void scan3(unsigned* __restrict__ rowptr,
                                             const unsigned* __restrict__ blksum)
{
    int b = blockIdx.x, rel = b >> 8, c = b & 255, t = threadIdx.x;
    rowptr[(size_t)rel * RPS + c * 256 + t] += blksum[rel * 256 + c];
}

__global__ __launch_bounds__(256) void scatter_all(P8 dsts, P8 srcs,
                                                   const unsigned* __restrict__ rowptr,
                                                   unsigned* __restrict__ cur,
                                                   int* __restrict__ esrc,
                                                   unsigned* __restrict__ eeid)
{
    int i = blockIdx.x * 256 + threadIdx.x;
    int rel = i >> 18, e = i & (E2 - 1);
    int d = dsts.a[rel][e];
    unsigned pos = atomicAdd(&cur[(size_t)rel * NDPAD + d], 1u);
    size_t idx = (size_t)rel * E2 + rowptr[(size_t)rel * RPS + d] + pos;
    esrc[idx] = srcs.a[rel][e];
    eeid[idx] = (unsigned)e;
}

// ---------------------------------------------------------------------------
// KineticConv gather, single pass, bf16 Z, 1 wave/dst, 2-deep pipeline.
// ---------------------------------------------------------------------------
__global__ __launch_bounds__(256) void phys_gather(
    const unsigned* __restrict__ rowptr, const int* __restrict__ esrc,
    const unsigned* __restrict__ Zp, unsigned* __restrict__ accp,
    int n_nodes, int accum)
{
    int t = threadIdx.x, w = t >> 6, l = t & 63;
    int d = blockIdx.x * 4 + w;
    if (d >= n_nodes) return;
    unsigned s0 = rowptr[d], s1 = rowptr[d + 1];
    int cnt = (int)(s1 - s0);
    float r0 = 0.f, r1 = 0.f;
    if (cnt > 0) {
        int sC = esrc[s0];
        unsigned zC = Zp[(size_t)sC * 64 + l];
        for (int j = 0; j < cnt; ++j) {
            int jn = (j + 1 < cnt) ? j + 1 : j;
            int sN = esrc[s0 + jn];
            unsigned zX = Zp[(size_t)sN * 64 + l];
            r0 += bf2f(zC & 0xffffu);
            r1 += bf2f(zC >> 16);
            zC = zX;
        }
    }
    float inv = 1.0f / (float)(cnt > 0 ? cnt : 1);
    r0 *= inv; r1 *= inv;
    unsigned* ap = accp + (size_t)d * 64 + l;
    if (accum) { unsigned o = *ap; r0 += bf2f(o & 0xffffu); r1 += bf2f(o >> 16); }
    *ap = pk2(r0, r1);
}

// ---------------------------------------------------------------------------
// GAT gather, single pass: num += e^lg * z; den += e^lg; out = num/den.
// Lane l covers cols (l, l+64) -> heads (l>>5, 2+(l>>5)).
// ---------------------------------------------------------------------------
template <bool HAS_EF>
__global__ __launch_bounds__(256) void gat_gather(
    const unsigned* __restrict__ rowptr, const int* __restrict__ esrc,
    const unsigned* __restrict__ eeid, const unsigned* __restrict__ Zp,
    const float* __restrict__ ls, const float* __restrict__ ld,
    const float* __restrict__ ef, const float* __restrict__ we,
    const float* __restrict__ ae,
    unsigned* __restrict__ accp, int n_nodes, int accum)
{
    __shared__ float M[8][4];
    int t = threadIdx.x;
    if (HAS_EF) {
        if (t < 32) {
            int f = t >> 2, hh = t & 3;
            float s = 0.f;
#pragma unroll 8
            for (int d2 = 0; d2 < 32; ++d2) s += we[f * 128 + hh * 32 + d2] * ae[hh * 32 + d2];
            M[f][hh] = s;
        }
        __syncthreads();
    }
    int w = t >> 6, l = t & 63;
    int d = blockIdx.x * 4 + w;
    if (d >= n_nodes) return;
    int hs = l >> 5;  // head select: lo head = hs, hi head = 2+hs
    float4 ldv = *(const float4*)(ld + (size_t)d * 4);
    float ldlo = hs ? ldv.y : ldv.x;
    float ldhi = hs ? ldv.w : ldv.z;
    float Mlo[8], Mhi[8];
    if (HAS_EF) {
#pragma unroll
        for (int f = 0; f < 8; ++f) { Mlo[f] = M[f][hs]; Mhi[f] = M[f][2 + hs]; }
    }
    unsigned s0 = rowptr[d], s1 = rowptr[d + 1];
    int cnt = (int)(s1 - s0);
    float r0 = 0.f, r1 = 0.f, dlo = 0.f, dhi = 0.f;
    if (cnt > 0) {
        int sC = esrc[s0];
        unsigned eC = HAS_EF ? eeid[s0] : 0u;
        float4 lsC = *(const float4*)(ls + (size_t)sC * 4);
        unsigned zC = Zp[(size_t)sC * 64 + l];
        float4 efC0, efC1;
        if (HAS_EF) {
            efC0 = *(const float4*)(ef + (size_t)eC * 8);
            efC1 = *(const float4*)(ef + (size_t)eC * 8 + 4);
        }
        for (int j = 0; j < cnt; ++j) {
            int jn = (j + 1 < cnt) ? j + 1 : j;
            int sN = esrc[s0 + jn];
            unsigned eN = HAS_EF ? eeid[s0 + jn] : 0u;
            // compute current logits
            float glo = (hs ? lsC.y : lsC.x) + ldlo;
            float ghi = (hs ? lsC.w : lsC.z) + ldhi;
            if (HAS_EF) {
                glo += efC0.x * Mlo[0] + efC0.y * Mlo[1] + efC0.z * Mlo[2] + efC0.w * Mlo[3]
                     + efC1.x * Mlo[4] + efC1.y * Mlo[5] + efC1.z * Mlo[6] + efC1.w * Mlo[7];
                ghi += efC0.x * Mhi[0] + efC0.y * Mhi[1] + efC0.z * Mhi[2] + efC0.w * Mhi[3]
                     + efC1.x * Mhi[4] + efC1.y * Mhi[5] + efC1.z * Mhi[6] + efC1.w * Mhi[7];
            }
            glo = glo > 0.f ? glo : 0.2f * glo;
            ghi = ghi > 0.f ? ghi : 0.2f * ghi;
            float exlo = __expf(glo), exhi = __expf(ghi);
            float zlo = bf2f(zC & 0xffffu), zhi = bf2f(zC >> 16);
            // issue next loads
            float4 lsX = *(const float4*)(ls + (size_t)sN * 4);
            unsigned zX = Zp[(size_t)sN * 64 + l];
            float4 efX0, efX1;
            if (HAS_EF) {
                efX0 = *(const float4*)(ef + (size_t)eN * 8);
                efX1 = *(const float4*)(ef + (size_t)eN * 8 + 4);
            }
            r0 += exlo * zlo; dlo += exlo;
            r1 += exhi * zhi; dhi += exhi;
            lsC = lsX; zC = zX;
            if (HAS_EF) { efC0 = efX0; efC1 = efX1; }
        }
    }
    r0 /= fmaxf(dlo, 1e-9f);
    r1 /= fmaxf(dhi, 1e-9f);
    unsigned* ap = accp + (size_t)d * 64 + l;
    if (accum) { unsigned o = *ap; r0 += bf2f(o & 0xffffu); r1 += bf2f(o >> 16); }
    *ap = pk2(r0, r1);
}

// ---------------------------------------------------------------------------
// FFN v3: barrier-free. 4 waves x 16 rows; LN + A-frags in registers;
// hidden in 4x128-col chunks via 8KB/wave private swizzled LDS transpose.
// ---------------------------------------------------------------------------
__global__ __launch_bounds__(256, 3) void ffn_v3(
    const float* __restrict__ h, const unsigned* __restrict__ accp,
    const float* __restrict__ g, const float* __restrict__ b,
    const unsigned short* __restrict__ w1t, const float* __restrict__ b1,
    const unsigned short* __restrict__ w2t, const float* __restrict__ b2,
    float* __restrict__ out, float invC)
{
    __shared__ float HW[4][16 * 128];
    int t = threadIdx.x, w = t >> 6, l = t & 63;
    int l15 = l & 15, lq = l >> 4;
    size_t rw = (size_t)blockIdx.x * 64 + w * 16;
    size_t myrow = rw + l15;
    float* myHW = &HW[w][0];

    // ---- step 1: h_new = h + acc*invC for my A-frag cols (32 per lane)
    const unsigned* ap = accp + myrow * 64 + lq * 8;
    uint4 ua0 = *(const uint4*)(ap);
    uint4 ua1 = *(const uint4*)(ap + 4);
    uint4 ub0 = *(const uint4*)(ap + 32);
    uint4 ub1 = *(const uint4*)(ap + 36);
    const float* hp = h + myrow * 128 + lq * 8;
    float4 hf[4][2];
    hf[0][0] = *(const float4*)(hp);      hf[0][1] = *(const float4*)(hp + 4);
    hf[1][0] = *(const float4*)(hp + 32); hf[1][1] = *(const float4*)(hp + 36);
    hf[2][0] = *(const float4*)(hp + 64); hf[2][1] = *(const float4*)(hp + 68);
    hf[3][0] = *(const float4*)(hp + 96); hf[3][1] = *(const float4*)(hp + 100);
    unsigned ua[8] = {ua0.x, ua0.y, ua0.z, ua0.w, ua1.x, ua1.y, ua1.z, ua1.w};
    unsigned ub[8] = {ub0.x, ub0.y, ub0.z, ub0.w, ub1.x, ub1.y, ub1.z, ub1.w};
    float hv[4][8];
#pragma unroll
    for (int j = 0; j < 8; ++j) {
        float a0 = ((const float*)hf[0])[j], a1 = ((const float*)hf[1])[j];
        float a2 = ((const float*)hf[2])[j], a3 = ((const float*)hf[3])[j];
        hv[0][j] = a0 + bf2f(ua[j] & 0xffffu) * invC;
        hv[1][j] = a1 + bf2f(ub[j] & 0xffffu) * invC;
        hv[2][j] = a2 + bf2f(ua[j] >> 16) * invC;
        hv[3][j] = a3 + bf2f(ub[j] >> 16) * invC;
    }
    // ---- LN over the row (4 lanes per row: offsets 16, 32)
    float s = 0.f;
#pragma unroll
    for (int ks = 0; ks < 4; ++ks)
#pragma unroll
        for (int j = 0; j < 8; ++j) s += hv[ks][j];
    s += __shfl_xor(s, 16); s += __shfl_xor(s, 32);
    float mean = s * (1.0f / 128.0f);
    float v = 0.f;
#pragma unroll
    for (int ks = 0; ks < 4; ++ks)
#pragma unroll
        for (int j = 0; j < 8; ++j) { float dd = hv[ks][j] - mean; v += dd * dd; }
    v += __shfl_xor(v, 16); v += __shfl_xor(v, 32);
    float rstd = rsqrtf(v * (1.0f / 128.0f) + 1e-5f);
    bf16x8 af[4];
#pragma unroll
    for (int ks = 0; ks < 4; ++ks) {
        int col0 = ks * 32 + lq * 8;
        float4 g0 = *(const float4*)(g + col0), g1 = *(const float4*)(g + col0 + 4);
        float4 b0 = *(const float4*)(b + col0), b1v = *(const float4*)(b + col0 + 4);
        float y[8];
        y[0] = g0.x * (hv[ks][0] - mean) * rstd + b0.x;
        y[1] = g0.y * (hv[ks][1] - mean) * rstd + b0.y;
        y[2] = g0.z * (hv[ks][2] - mean) * rstd + b0.z;
        y[3] = g0.w * (hv[ks][3] - mean) * rstd + b0.w;
        y[4] = g1.x * (hv[ks][4] - mean) * rstd + b1v.x;
        y[5] = g1.y * (hv[ks][5] - mean) * rstd + b1v.y;
        y[6] = g1.z * (hv[ks][6] - mean) * rstd + b1v.z;
        y[7] = g1.w * (hv[ks][7] - mean) * rstd + b1v.w;
        af[ks] = pack8(y);
    }

    // ---- chunks: 4 x 128 hidden cols
    f32x4 facc[8];
#pragma unroll
    for (int n = 0; n < 8; ++n) facc[n] = (f32x4){0.f, 0.f, 0.f, 0.f};
    int swR = (l15 & 7) << 2;   // read swizzle (row = l15)
    for (int ch = 0; ch < 4; ++ch) {
        f32x4 acc1[8];
#pragma unroll
        for (int n = 0; n < 8; ++n) acc1[n] = (f32x4){0.f, 0.f, 0.f, 0.f};
#pragma unroll
        for (int ks = 0; ks < 4; ++ks) {
            int k0 = ks * 32 + lq * 8;
#pragma unroll
            for (int nf = 0; nf < 8; ++nf) {
                bf16x8 bw = *(const bf16x8*)(w1t + (size_t)(ch * 128 + nf * 16 + l15) * 128 + k0);
                acc1[nf] = __builtin_amdgcn_mfma_f32_16x16x32_bf16(af[ks], bw, acc1[nf], 0, 0, 0);
            }
        }
        // GELU + b1 -> private LDS (XOR swizzled by row)
#pragma unroll
        for (int nf = 0; nf < 8; ++nf) {
            float bv1 = b1[ch * 128 + nf * 16 + l15];
#pragma unroll
            for (int reg = 0; reg < 4; ++reg) {
                int rowD = lq * 4 + reg;
                float x = acc1[nf][reg] + bv1;
                float ge = 0.5f * x * (1.0f + erff(x * 0.70710678118654752f));
                myHW[rowD * 128 + ((nf * 16 + l15) ^ ((rowD & 7) << 2))] = ge;
            }
        }
        // phase 2: read transposed (row = l15), cvt, MFMA into facc
#pragma unroll
        for (int kf = 0; kf < 4; ++kf) {
            int base = kf * 32 + lq * 8;
            f32x4 x0 = *(const f32x4*)(myHW + l15 * 128 + ((base) ^ swR));
            f32x4 x1 = *(const f32x4*)(myHW + l15 * 128 + ((base + 4) ^ swR));
            float y[8] = {x0[0], x0[1], x0[2], x0[3], x1[0], x1[1], x1[2], x1[3]};
            bf16x8 afh = pack8(y);
#pragma unroll
            for (int nf = 0; nf < 8; ++nf) {
                bf16x8 bw = *(const bf16x8*)(w2t + (size_t)(nf * 16 + l15) * 512 + ch * 128 + base);
                facc[nf] = __builtin_amdgcn_mfma_f32_16x16x32_bf16(afh, bw, facc[nf], 0, 0, 0);
            }
        }
    }
    // ---- epilogue: out = h + acc*invC + ffn + b2  (D layout)
#pragma unroll
    for (int nf = 0; nf < 8; ++nf) {
        int col = nf * 16 + l15;
        float bv = b2[col];
        int ci = (col < 64) ? col : col - 64;
        bool hi = col >= 64;
#pragma unroll
        for (int reg = 0; reg < 4; ++reg) {
            size_t row = rw + lq * 4 + reg;
            unsigned pv = accp[row * 64 + ci];
            float av = bf2f(hi ? (pv >> 16) : (pv & 0xffffu));
            out[row * 128 + col] = h[row * 128 + col] + av * invC + facc[nf][reg] + bv;
        }
    }
}

// ---------------------------------------------------------------------------
extern "C" void kernel_launch(void* const* d_in, const int* in_sizes, int n_in,
                              void* d_out, int out_size, void* d_ws, size_t ws_size,
                              hipStream_t stream)
{
    const float* h_enz  = (const float*)d_in[0];
    const float* h_met  = (const float*)d_in[1];
    const float* h_rxn  = (const float*)d_in[2];
    const float* ef_mod = (const float*)d_in[3];
    const float* ef_sig = (const float*)d_in[4];
    const float* ef_brg = (const float*)d_in[5];
    const float* ef_trn = (const float*)d_in[6];
    const float* ln1_g  = (const float*)d_in[7];
    const float* ln1_b  = (const float*)d_in[8];
    const float* ln2_g  = (const float*)d_in[9];
    const float* ln2_b  = (const float*)d_in[10];
    const float* wp     = (const float*)d_in[11];
    const float* bp     = (const float*)d_in[12];
    const float* wl     = (const float*)d_in[13];
    const float* a_src  = (const float*)d_in[14];
    const float* a_dst  = (const float*)d_in[15];
    const float* we     = (const float*)d_in[16];
    const float* a_edge = (const float*)d_in[17];
    const float* w1     = (const float*)d_in[18];
    const float* b1     = (const float*)d_in[19];
    const float* w2     = (const float*)d_in[20];
    const float* b2     = (const float*)d_in[21];
    const int* src_sub  = (const int*)d_in[22];
    const int* dst_sub  = (const int*)d_in[23];
    const int* src_prod = (const int*)d_in[24];
    const int* dst_prod = (const int*)d_in[25];
    const int* src_cat  = (const int*)d_in[26];
    const int* dst_cat  = (const int*)d_in[27];
    const int* src_mod  = (const int*)d_in[28];
    const int* dst_mod  = (const int*)d_in[29];
    const int* src_reg  = (const int*)d_in[30];
    const int* dst_reg  = (const int*)d_in[31];
    const int* src_sig  = (const int*)d_in[32];
    const int* dst_sig  = (const int*)d_in[33];
    const int* src_brg  = (const int*)d_in[34];
    const int* dst_brg  = (const int*)d_in[35];
    const int* src_trn  = (const int*)d_in[36];
    const int* dst_trn  = (const int*)d_in[37];
    float* out = (float*)d_out;

    // workspace layout (~79 MB; proven budget >= 116.6 MB)
    char* p = (char*)d_ws;
    unsigned* accp = (unsigned*)p;            p += (size_t)NTOT * 64 * 4;
    unsigned* Zp   = (unsigned*)p;            p += (size_t)NM * 64 * 4;
    float* lsb = (float*)p;                   p += (size_t)NM * 4 * 4;
    float* ldb = (float*)p;                   p += (size_t)NM * 4 * 4;
    unsigned short* wbf = (unsigned short*)p; p += (size_t)524288 * 2;
    unsigned* hist = (unsigned*)p;            p += (size_t)8 * NDPAD * 4;
    unsigned* rowptr = (unsigned*)p;          p += (size_t)8 * RPS * 4;
    int* esrc = (int*)p;                      p += (size_t)8 * E2 * 4;
    unsigned* eeid = (unsigned*)p;            p += (size_t)8 * E2 * 4;
    unsigned* blksum = (unsigned*)p;          p += (size_t)8 * 256 * 4;
    if (ws_size < (size_t)(p - (char*)d_ws)) return;

    // normalized feats (packed bf16) in d_out-as-scratch until ffn
    unsigned* nrm32 = (unsigned*)d_out;
    const unsigned short* nbf_enz = (const unsigned short*)d_out;
    const unsigned short* nbf_met = nbf_enz + (size_t)NE * 128;
    const unsigned short* nbf_rxn = nbf_enz + (size_t)(NE + NM) * 128;
    const unsigned* n32_enz = (const unsigned*)nbf_enz;
    const unsigned* n32_rxn = (const unsigned*)nbf_rxn;
    unsigned* acc_enz = accp;
    unsigned* acc_met = accp + (size_t)NE * 64;
    unsigned* acc_rxn = accp + (size_t)(NE + NM) * 64;

    P8 dsts, srcs;
    dsts.a[0] = dst_sub;  srcs.a[0] = src_sub;
    dsts.a[1] = dst_prod; srcs.a[1] = src_prod;
    dsts.a[2] = dst_cat;  srcs.a[2] = src_cat;
    dsts.a[3] = dst_mod;  srcs.a[3] = src_mod;
    dsts.a[4] = dst_reg;  srcs.a[4] = src_reg;
    dsts.a[5] = dst_sig;  srcs.a[5] = src_sig;
    dsts.a[6] = dst_brg;  srcs.a[6] = src_brg;
    dsts.a[7] = dst_trn;  srcs.a[7] = src_trn;

    // ---- prep
    hipMemsetAsync(hist, 0, (size_t)8 * NDPAD * 4, stream);
    convw<<<2048, 256, 0, stream>>>(wp, wl, w1, w2, wbf);
    ln1_kernel<<<NTOT / 4, 256, 0, stream>>>(h_enz, h_met, h_rxn, ln1_g, ln1_b, nrm32);
    hist_all<<<8192, 256, 0, stream>>>(dsts, hist);
    scan1<<<2048, 256, 0, stream>>>(hist, rowptr, blksum);
    scan2<<<8, 256, 0, stream>>>(blksum, rowptr);
    scan3<<<2048, 256, 0, stream>>>(rowptr, blksum);
    hipMemsetAsync(hist, 0, (size_t)8 * NDPAD * 4, stream);
    scatter_all<<<8192, 256, 0, stream>>>(dsts, srcs, rowptr, hist, esrc, eeid);

#define RP(r) (rowptr + (size_t)(r) * RPS)
#define ES(r) (esrc + (size_t)(r) * E2)
#define ED(r) (eeid + (size_t)(r) * E2)

    // ---- rel 0: substrate_of (met->rxn), wp0 (phys)
    gemm_mfma<0, true><<<NM / 128, 256, 0, stream>>>(nbf_met, wbf + 0 * 16384, bp + 0, Zp,
                                                     nullptr, nullptr, nullptr, nullptr);
    phys_gather<<<NR / 4, 256, 0, stream>>>(RP(0), ES(0), Zp, acc_rxn, NR, 0);
    // ---- rel 1: produces (rxn->met), wp1 (phys)
    gemm_mfma<0, true><<<NR / 128, 256, 0, stream>>>(nbf_rxn, wbf + 1 * 16384, bp + 128, Zp,
                                                     nullptr, nullptr, nullptr, nullptr);
    phys_gather<<<NM / 4, 256, 0, stream>>>(RP(1), ES(1), Zp, acc_met, NM, 0);
    // ---- rel 2: catalyzes (enz->rxn), wp2 (phys)
    gemm_mfma<0, true><<<NE / 128, 256, 0, stream>>>(nbf_enz, wbf + 2 * 16384, bp + 256, Zp,
                                                     nullptr, nullptr, nullptr, nullptr);
    phys_gather<<<NR / 4, 256, 0, stream>>>(RP(2), ES(2), Zp, acc_rxn, NR, 1);

    // ---- rel 3: modulates (enz->rxn), wl0, ef_mod/we0/ae0
    gemm_mfma<1, false><<<NE / 128, 256, 0, stream>>>(nbf_enz, wbf + 3 * 16384, nullptr, Zp,
                                                      a_src + 0, nullptr, lsb, nullptr);
    logits_fold<<<NR / 4, 256, 0, stream>>>(n32_rxn, wl + 0, a_dst + 0, ldb, NR);
    gat_gather<true><<<NR / 4, 256, 0, stream>>>(RP(3), ES(3), ED(3), Zp, lsb, ldb,
                                                 ef_mod, we + 0, a_edge + 0, acc_rxn, NR, 1);
    // ---- rel 4: regulates (enz->enz), wl1, no ef
    gemm_mfma<2, false><<<NE / 128, 256, 0, stream>>>(nbf_enz, wbf + 4 * 16384, nullptr, Zp,
                                                      a_src + 128, a_dst + 128, lsb, ldb);
    gat_gather<false><<<NE / 4, 256, 0, stream>>>(RP(4), ES(4), nullptr, Zp, lsb, ldb,
                                                  nullptr, nullptr, nullptr, acc_enz, NE, 0);
    // ---- rel 5: signaling (met->enz), wl2, ef_sig/we1/ae1
    gemm_mfma<1, false><<<NM / 128, 256, 0, stream>>>(nbf_met, wbf + 5 * 16384, nullptr, Zp,
                                                      a_src + 256, nullptr, lsb, nullptr);
    logits_fold<<<NE / 4, 256, 0, stream>>>(n32_enz, wl + 2 * 16384, a_dst + 256, ldb, NE);
    gat_gather<true><<<NE / 4, 256, 0, stream>>>(RP(5), ES(5), ED(5), Zp, lsb, ldb,
                                                 ef_sig, we + 1024, a_edge + 128, acc_enz, NE, 1);
    // ---- rel 6: bridges (met->met), wl3, ef_brg/we2/ae2
    gemm_mfma<2, false><<<NM / 128, 256, 0, stream>>>(nbf_met, wbf + 6 * 16384, nullptr, Zp,
                                                      a_src + 384, a_dst + 384, lsb, ldb);
    gat_gather<true><<<NM / 4, 256, 0, stream>>>(RP(6), ES(6), ED(6), Zp, lsb, ldb,
                                                 ef_brg, we + 2048, a_edge + 256, acc_met, NM, 1);
    // ---- rel 7: transports_to (met->met), wl4, ef_trn/we3/ae3
    gemm_mfma<2, false><<<NM / 128, 256, 0, stream>>>(nbf_met, wbf + 7 * 16384, nullptr, Zp,
                                                      a_src + 512, a_dst + 512, lsb, ldb);
    gat_gather<true><<<NM / 4, 256, 0, stream>>>(RP(7), ES(7), ED(7), Zp, lsb, ldb,
                                                 ef_trn, we + 3072, a_edge + 384, acc_met, NM, 1);

    // ---- fused combine + LN2 + FFN (+residual), per node type
    ffn_v3<<<NE / 64, 256, 0, stream>>>(h_enz, acc_enz, ln2_g + 0, ln2_b + 0,
                                        wbf + W1T_OFF + 0 * 65536, b1 + 0,
                                        wbf + W2T_OFF + 0 * 65536, b2 + 0,
                                        out + 0, 0.5f);
    ffn_v3<<<NM / 64, 256, 0, stream>>>(h_met, acc_met, ln2_g + 128, ln2_b + 128,
                                        wbf + W1T_OFF + 1 * 65536, b1 + 512,
                                        wbf + W2T_OFF + 1 * 65536, b2 + 128,
                                        out + (size_t)NE * 128, 1.0f / 3.0f);
    ffn_v3<<<NR / 64, 256, 0, stream>>>(h_rxn, acc_rxn, ln2_g + 256, ln2_b + 256,
                                        wbf + W1T_OFF + 2 * 65536, b1 + 1024,
                                        wbf + W2T_OFF + 2 * 65536, b2 + 256,
                                        out + (size_t)(NE + NM) * 128, 1.0f / 3.0f);
#undef RP
#undef ES
#undef ED
}

// Round 4
// 768.026 us; speedup vs baseline: 5.0323x; 1.6857x over previous
//
#include <hip/hip_runtime.h>
#include <cstddef>

#define NE 32768
#define NM 65536
#define NR 49152
#define NTOT 147456
#define E2 262144
#define NDPAD 65536
#define RPS 65537
#define W1T_OFF 131072
#define W2T_OFF 327680

typedef __attribute__((ext_vector_type(8))) short bf16x8;
typedef __attribute__((ext_vector_type(4))) float f32x4;

__device__ __forceinline__ unsigned short f2bf(float x) {
    unsigned u = __float_as_uint(x);
    return (unsigned short)((u + 0x7FFFu + ((u >> 16) & 1u)) >> 16);
}
__device__ __forceinline__ float bf2f(unsigned s) { return __uint_as_float(s << 16); }
__device__ __forceinline__ unsigned pk2(float a, float b) {
    return (unsigned)f2bf(a) | ((unsigned)f2bf(b) << 16);
}
__device__ __forceinline__ bf16x8 pack8(const float* v) {
    union { bf16x8 b; unsigned u[4]; } r;
#pragma unroll
    for (int i = 0; i < 4; ++i) r.u[i] = pk2(v[2 * i], v[2 * i + 1]);
    return r.b;
}
__device__ __forceinline__ bf16x8 pack8v(f32x4 a, f32x4 b) {
    union { bf16x8 v; unsigned u[4]; } r;
    r.u[0] = pk2(a[0], a[1]); r.u[1] = pk2(a[2], a[3]);
    r.u[2] = pk2(b[0], b[1]); r.u[3] = pk2(b[2], b[3]);
    return r.v;
}
// async global->LDS, 16B per lane (HK pattern: wave-uniform base + lane*16)
__device__ __forceinline__ void gll16(const void* g, void* l) {
    __builtin_amdgcn_global_load_lds(
        (const __attribute__((address_space(1))) void*)g,
        (__attribute__((address_space(3))) void*)l, 16, 0, 0);
}

// ---------------------------------------------------------------------------
// Weights -> bf16 FRAGMENT-PACKED: frag(nf,ks) stored as 64 lanes x 16B, lane
// l: n = nf*16+(l&15), k = ks*32+(l>>4)*8+j.  Square mats + w1t nf-major,
// w2t ks-major (so each 64-col ffn chunk is a contiguous 16 KB block).
// ---------------------------------------------------------------------------
__global__ __launch_bounds__(256) void convw(
    const float* __restrict__ wp, const float* __restrict__ wl,
    const float* __restrict__ w1, const float* __restrict__ w2,
    unsigned short* __restrict__ wbf)
{
    int i = blockIdx.x * 256 + threadIdx.x;
    float v;
    if (i < 131072) {                       // 8 square 128x128 (wp0..2, wl0..4)
        int mat = i >> 14, r = i & 16383;
        int frag = r >> 9, lane = (r >> 3) & 63, j = r & 7;
        int nf = frag >> 2, ks = frag & 3;
        int n = nf * 16 + (lane & 15);
        int k = ks * 32 + (lane >> 4) * 8 + j;
        const float* src = (mat < 3) ? (wp + mat * 16384) : (wl + (mat - 3) * 16384);
        v = src[k * 128 + n];
    } else if (i < 327680) {                // w1t per type: N=512,K=128, nf-major
        int ii = i - 131072; int mat = ii >> 16, r = ii & 65535;
        int frag = r >> 9, lane = (r >> 3) & 63, j = r & 7;
        int nf = frag >> 2, ks = frag & 3;
        int n = nf * 16 + (lane & 15);
        int k = ks * 32 + (lane >> 4) * 8 + j;
        v = w1[mat * 65536 + k * 512 + n];
    } else {                                // w2t per type: N=128,K=512, ks-major
        int ii = i - 327680; int mat = ii >> 16, r = ii & 65535;
        int frag = r >> 9, lane = (r >> 3) & 63, j = r & 7;
        int ks = frag >> 3, nf = frag & 7;
        int n = nf * 16 + (lane & 15);
        int k = ks * 32 + (lane >> 4) * 8 + j;
        v = w2[mat * 65536 + k * 128 + n];
    }
    wbf[i] = f2bf(v);
}

// ---------------------------------------------------------------------------
// WQ[site] = W . a  (128 x 8 logit-fold matrices), fragment-packed (4 frags).
// sites: 0:(wl0,ad0) 1:(wl2,ad2) 2:(wl0,as0) 3:(wl1,as1,ad1) 4:(wl2,as2)
//        5:(wl3,as3,ad3) 6:(wl4,as4,ad4).  cols 0..3 = lo set, 4..7 = hi set.
// ---------------------------------------------------------------------------
__global__ __launch_bounds__(256) void wqk(
    const float* __restrict__ wl, const float* __restrict__ a_src,
    const float* __restrict__ a_dst, unsigned short* __restrict__ wq)
{
    const int wi[7]  = {0, 2, 0, 1, 2, 3, 4};
    const int loi[7] = {0, 2, 0, 1, 2, 3, 4};
    const int lod[7] = {1, 1, 0, 0, 0, 0, 0};
    const int hii[7] = {-1, -1, -1, 1, -1, 3, 4};
    int site = blockIdx.x >> 2, ks = blockIdx.x & 3, t = threadIdx.x;
    const float* W = wl + wi[site] * 16384;
#pragma unroll
    for (int rep = 0; rep < 2; ++rep) {
        int e = t * 2 + rep;
        int lane = e >> 3, j = e & 7;
        int n = lane & 15;
        int k = ks * 32 + (lane >> 4) * 8 + j;
        float v = 0.f;
        if (n < 4) {
            const float* a = (lod[site] ? a_dst : a_src) + loi[site] * 128;
#pragma unroll 8
            for (int d = 0; d < 32; ++d) v += W[k * 128 + n * 32 + d] * a[n * 32 + d];
        } else if (n < 8 && hii[site] >= 0) {
            const float* a = a_dst + hii[site] * 128;
            int hh = n - 4;
#pragma unroll 8
            for (int d = 0; d < 32; ++d) v += W[k * 128 + hh * 32 + d] * a[hh * 32 + d];
        }
        wq[((site * 4 + ks) * 64 + lane) * 8 + j] = f2bf(v);
    }
}

// ---------------------------------------------------------------------------
__global__ __launch_bounds__(256) void ln1_kernel(
    const float* __restrict__ he, const float* __restrict__ hm, const float* __restrict__ hr,
    const float* __restrict__ g, const float* __restrict__ b, unsigned* __restrict__ nout)
{
    int row  = blockIdx.x * 4 + (threadIdx.x >> 6);
    int lane = threadIdx.x & 63;
    const float* src; int ti; int lr;
    if (row < NE)           { src = he; ti = 0; lr = row; }
    else if (row < NE + NM) { src = hm; ti = 1; lr = row - NE; }
    else                    { src = hr; ti = 2; lr = row - NE - NM; }
    float2 x = *(const float2*)(src + (size_t)lr * 128 + lane * 2);
    float s = x.x + x.y;
#pragma unroll
    for (int o = 32; o; o >>= 1) s += __shfl_xor(s, o);
    float mean = s * (1.0f / 128.0f);
    float dx = x.x - mean, dy = x.y - mean;
    float v = dx * dx + dy * dy;
#pragma unroll
    for (int o = 32; o; o >>= 1) v += __shfl_xor(v, o);
    float rstd = rsqrtf(v * (1.0f / 128.0f) + 1e-5f);
    int c = lane * 2;
    float y0 = g[ti * 128 + c]     * dx * rstd + b[ti * 128 + c];
    float y1 = g[ti * 128 + c + 1] * dy * rstd + b[ti * 128 + c + 1];
    nout[(size_t)row * 64 + lane] = pk2(y0, y1);
}

// ---------------------------------------------------------------------------
// GEMM: Z[M,128] = A @ W (+bias), weights LDS-staged once per block (32 KB,
// shared by 4 waves); logits via MFMA with tiny WQ B-frags.
// LOG: 0 none, 1 -> oa (cols 0..3), 2 -> oa + ob (cols 4..7).
// ---------------------------------------------------------------------------
template <int LOG, bool BIAS>
__global__ __launch_bounds__(256) void gemm_v2(
    const unsigned short* __restrict__ A, const unsigned short* __restrict__ Wt,
    const float* __restrict__ bias, unsigned* __restrict__ Zp,
    const unsigned short* __restrict__ WQ, float* __restrict__ oa, float* __restrict__ ob)
{
    __shared__ unsigned short WL[16384];   // 32 KB
    int t = threadIdx.x, w = t >> 6, l = t & 63;
    int l15 = l & 15, lq = l >> 4;
#pragma unroll
    for (int i = 0; i < 8; ++i)
        gll16(Wt + i * 2048 + t * 8, (char*)WL + i * 4096 + t * 16);
    size_t row0 = (size_t)blockIdx.x * 128 + w * 32;
    f32x4 acc[2][8]; f32x4 accl[2];
#pragma unroll
    for (int r = 0; r < 2; ++r) {
        accl[r] = (f32x4){0.f, 0.f, 0.f, 0.f};
#pragma unroll
        for (int n = 0; n < 8; ++n) acc[r][n] = (f32x4){0.f, 0.f, 0.f, 0.f};
    }
    bf16x8 qf[4];
    if constexpr (LOG >= 1) {
#pragma unroll
        for (int ks = 0; ks < 4; ++ks) qf[ks] = *(const bf16x8*)(WQ + (ks * 64 + l) * 8);
    }
    __syncthreads();
#pragma unroll
    for (int ks = 0; ks < 4; ++ks) {
        int k0 = ks * 32 + lq * 8;
        bf16x8 a0 = *(const bf16x8*)(A + (row0 + l15) * 128 + k0);
        bf16x8 a1 = *(const bf16x8*)(A + (row0 + 16 + l15) * 128 + k0);
#pragma unroll
        for (int n = 0; n < 8; ++n) {
            bf16x8 bw = *(const bf16x8*)(WL + ((n * 4 + ks) * 64 + l) * 8);
            acc[0][n] = __builtin_amdgcn_mfma_f32_16x16x32_bf16(a0, bw, acc[0][n], 0, 0, 0);
            acc[1][n] = __builtin_amdgcn_mfma_f32_16x16x32_bf16(a1, bw, acc[1][n], 0, 0, 0);
        }
        if constexpr (LOG >= 1) {
            accl[0] = __builtin_amdgcn_mfma_f32_16x16x32_bf16(a0, qf[ks], accl[0], 0, 0, 0);
            accl[1] = __builtin_amdgcn_mfma_f32_16x16x32_bf16(a1, qf[ks], accl[1], 0, 0, 0);
        }
    }
#pragma unroll
    for (int n = 0; n < 4; ++n) {
        float bl = BIAS ? bias[n * 16 + l15] : 0.f;
        float bh = BIAS ? bias[n * 16 + l15 + 64] : 0.f;
#pragma unroll
        for (int r = 0; r < 2; ++r)
#pragma unroll
            for (int reg = 0; reg < 4; ++reg) {
                size_t row = row0 + r * 16 + lq * 4 + reg;
                Zp[row * 64 + n * 16 + l15] = pk2(acc[r][n][reg] + bl, acc[r][n + 4][reg] + bh);
            }
    }
    if constexpr (LOG >= 1) {
#pragma unroll
        for (int r = 0; r < 2; ++r)
#pragma unroll
            for (int reg = 0; reg < 4; ++reg) {
                size_t row = row0 + r * 16 + lq * 4 + reg;
                if (l15 < 4) oa[row * 4 + l15] = accl[r][reg];
                else if (LOG == 2 && l15 < 8) ob[row * 4 + (l15 - 4)] = accl[r][reg];
            }
    }
}

// ---------------------------------------------------------------------------
// CSR build (dst side), value = {src, eid} packed int2.
// ---------------------------------------------------------------------------
struct P8 { const int* a[8]; };

__global__ __launch_bounds__(256) void hist_all(P8 dsts, unsigned* __restrict__ hist)
{
    int i = blockIdx.x * 256 + threadIdx.x;
    int rel = i >> 18, e = i & (E2 - 1);
    atomicAdd(&hist[(size_t)rel * NDPAD + dsts.a[rel][e]], 1u);
}

__global__ __launch_bounds__(256) void scan1(const unsigned* __restrict__ hist,
                                             unsigned* __restrict__ rowptr,
                                             unsigned* __restrict__ blksum)
{
    __shared__ unsigned s[256];
    int b = blockIdx.x, rel = b >> 8, c = b & 255, t = threadIdx.x;
    unsigned v = hist[(size_t)rel * NDPAD + c * 256 + t];
    s[t] = v; __syncthreads();
    for (int off = 1; off < 256; off <<= 1) {
        unsigned x = (t >= off) ? s[t - off] : 0u;
        __syncthreads();
        s[t] += x;
        __syncthreads();
    }
    rowptr[(size_t)rel * RPS + c * 256 + t] = s[t] - v;
    if (t == 255) blksum[rel * 256 + c] = s[255];
}

__global__ __launch_bounds__(256) void scan2(unsigned* __restrict__ blksum,
                                             unsigned* __restrict__ rowptr)
{
    __shared__ unsigned s[256];
    int rel = blockIdx.x, t = threadIdx.x;
    unsigned v = blksum[rel * 256 + t];
    s[t] = v; __syncthreads();
    for (int off = 1; off < 256; off <<= 1) {
        unsigned x = (t >= off) ? s[t - off] : 0u;
        __syncthreads();
        s[t] += x;
        __syncthreads();
    }
    blksum[rel * 256 + t] = s[t] - v;
    if (t == 255) rowptr[(size_t)rel * RPS + 65536] = s[255];
}

__global__ __launch_bounds__(256) void scan3(unsigned* __restrict__ rowptr,
                                             const unsigned* __restrict__ blksum)
{
    int b = blockIdx.x, rel = b >> 8, c = b & 255, t = threadIdx.x;
    rowptr[(size_t)rel * RPS + c * 256 + t] += blksum[rel * 256 + c];
}

__global__ __launch_bounds__(256) void scatter_all(P8 dsts, P8 srcs,
                                                   const unsigned* __restrict__ rowptr,
                                                   unsigned* __restrict__ cur,
                                                   int2* __restrict__ epair)
{
    int i = blockIdx.x * 256 + threadIdx.x;
    int rel = i >> 18, e = i & (E2 - 1);
    int d = dsts.a[rel][e];
    unsigned pos = atomicAdd(&cur[(size_t)rel * NDPAD + d], 1u);
    epair[(size_t)rel * E2 + rowptr[(size_t)rel * RPS + d] + pos] =
        make_int2(srcs.a[rel][e], e);
}

// ---------------------------------------------------------------------------
// Per-edge (ef @ M) in CSR order, for the 4 EF relations {3,5,6,7}.
// ---------------------------------------------------------------------------
__global__ __launch_bounds__(256) void efpre(
    const int2* __restrict__ epair,
    const float* __restrict__ efm, const float* __restrict__ efs,
    const float* __restrict__ efb, const float* __restrict__ eft,
    const float* __restrict__ we, const float* __restrict__ ae,
    float* __restrict__ ef4)
{
    __shared__ float M[8][4];
    int b = blockIdx.x, t = threadIdx.x;
    int er = b >> 10;
    const int relmap[4] = {3, 5, 6, 7};
    const float* ef = (er == 0) ? efm : (er == 1) ? efs : (er == 2) ? efb : eft;
    if (t < 32) {
        int f = t >> 2, hh = t & 3;
        float s = 0.f;
#pragma unroll 8
        for (int d = 0; d < 32; ++d) s += we[er * 1024 + f * 128 + hh * 32 + d] * ae[er * 128 + hh * 32 + d];
        M[f][hh] = s;
    }
    __syncthreads();
    int i = (b & 1023) * 256 + t;
    size_t idx = (size_t)relmap[er] * E2 + i;
    int eid = epair[idx].y;
    float4 a = *(const float4*)(ef + (size_t)eid * 8);
    float4 c = *(const float4*)(ef + (size_t)eid * 8 + 4);
    float4 o;
    o.x = a.x*M[0][0]+a.y*M[1][0]+a.z*M[2][0]+a.w*M[3][0]+c.x*M[4][0]+c.y*M[5][0]+c.z*M[6][0]+c.w*M[7][0];
    o.y = a.x*M[0][1]+a.y*M[1][1]+a.z*M[2][1]+a.w*M[3][1]+c.x*M[4][1]+c.y*M[5][1]+c.z*M[6][1]+c.w*M[7][1];
    o.z = a.x*M[0][2]+a.y*M[1][2]+a.z*M[2][2]+a.w*M[3][2]+c.x*M[4][2]+c.y*M[5][2]+c.z*M[6][2]+c.w*M[7][2];
    o.w = a.x*M[0][3]+a.y*M[1][3]+a.z*M[2][3]+a.w*M[3][3]+c.x*M[4][3]+c.y*M[5][3]+c.z*M[6][3]+c.w*M[7][3];
    *(float4*)(ef4 + ((size_t)er * E2 + i) * 4) = o;
}

// ---------------------------------------------------------------------------
// KineticConv gather: batch-4 deep memory pipeline.
// ---------------------------------------------------------------------------
__global__ __launch_bounds__(256) void phys_gather(
    const unsigned* __restrict__ rowptr, const int2* __restrict__ epair,
    const unsigned* __restrict__ Zp, unsigned* __restrict__ accp,
    int n_nodes, int accum)
{
    int t = threadIdx.x, w = t >> 6, l = t & 63;
    int d = blockIdx.x * 4 + w;
    if (d >= n_nodes) return;
    unsigned s0 = rowptr[d], s1 = rowptr[d + 1];
    float r0 = 0.f, r1 = 0.f;
    for (unsigned base = s0; base < s1; base += 4) {
        unsigned nb = s1 - base; if (nb > 4) nb = 4;
        int sidx[4];
#pragma unroll
        for (int i = 0; i < 4; ++i)
            sidx[i] = epair[base + ((unsigned)i < nb ? (unsigned)i : nb - 1)].x;
        unsigned z[4];
#pragma unroll
        for (int i = 0; i < 4; ++i) z[i] = Zp[(size_t)sidx[i] * 64 + l];
#pragma unroll
        for (int i = 0; i < 4; ++i)
            if ((unsigned)i < nb) { r0 += bf2f(z[i] & 0xffffu); r1 += bf2f(z[i] >> 16); }
    }
    int cnt = (int)(s1 - s0);
    float inv = 1.0f / (float)(cnt > 0 ? cnt : 1);
    r0 *= inv; r1 *= inv;
    unsigned* ap = accp + (size_t)d * 64 + l;
    if (accum) { unsigned o = *ap; r0 += bf2f(o & 0xffffu); r1 += bf2f(o >> 16); }
    *ap = pk2(r0, r1);
}

// ---------------------------------------------------------------------------
// GAT gather, single pass, batch-4: logit = ls[src] + ld[d] (+ef4_csr),
// leaky-relu, exp (shift-free softmax), num/den in regs.
// ---------------------------------------------------------------------------
template <bool HAS_EF>
__global__ __launch_bounds__(256) void gat_gather(
    const unsigned* __restrict__ rowptr, const int2* __restrict__ epair,
    const unsigned* __restrict__ Zp,
    const float* __restrict__ ls, const float* __restrict__ ld,
    const float* __restrict__ ef4,
    unsigned* __restrict__ accp, int n_nodes, int accum)
{
    int t = threadIdx.x, w = t >> 6, l = t & 63;
    int d = blockIdx.x * 4 + w;
    if (d >= n_nodes) return;
    int hs = l >> 5;  // lo head = hs, hi head = 2+hs
    float4 ldv4 = *(const float4*)(ld + (size_t)d * 4);
    float ldlo = hs ? ldv4.y : ldv4.x;
    float ldhi = hs ? ldv4.w : ldv4.z;
    unsigned s0 = rowptr[d], s1 = rowptr[d + 1];
    float r0 = 0.f, r1 = 0.f, dlo = 0.f, dhi = 0.f;
    for (unsigned base = s0; base < s1; base += 4) {
        unsigned nb = s1 - base; if (nb > 4) nb = 4;
        int sidx[4]; unsigned ci[4];
#pragma unroll
        for (int i = 0; i < 4; ++i) {
            ci[i] = base + ((unsigned)i < nb ? (unsigned)i : nb - 1);
            sidx[i] = epair[ci[i]].x;
        }
        unsigned z[4]; float4 lsv[4]; float4 e4[4];
#pragma unroll
        for (int i = 0; i < 4; ++i) {
            z[i] = Zp[(size_t)sidx[i] * 64 + l];
            lsv[i] = *(const float4*)(ls + (size_t)sidx[i] * 4);
            if (HAS_EF) e4[i] = *(const float4*)(ef4 + (size_t)ci[i] * 4);
        }
#pragma unroll
        for (int i = 0; i < 4; ++i) {
            if ((unsigned)i >= nb) break;
            float glo = (hs ? lsv[i].y : lsv[i].x) + ldlo;
            float ghi = (hs ? lsv[i].w : lsv[i].z) + ldhi;
            if (HAS_EF) {
                glo += hs ? e4[i].y : e4[i].x;
                ghi += hs ? e4[i].w : e4[i].z;
            }
            glo = glo > 0.f ? glo : 0.2f * glo;
            ghi = ghi > 0.f ? ghi : 0.2f * ghi;
            float xlo = __expf(glo), xhi = __expf(ghi);
            r0 += xlo * bf2f(z[i] & 0xffffu); dlo += xlo;
            r1 += xhi * bf2f(z[i] >> 16);     dhi += xhi;
        }
    }
    r0 /= fmaxf(dlo, 1e-9f);
    r1 /= fmaxf(dhi, 1e-9f);
    unsigned* ap = accp + (size_t)d * 64 + l;
    if (accum) { unsigned o = *ap; r0 += bf2f(o & 0xffffu); r1 += bf2f(o >> 16); }
    *ap = pk2(r0, r1);
}

// ---------------------------------------------------------------------------
// FFN v4: combine + LN2 + W2 GELU(W1 . ) + residual.  64 rows/block, 4 waves
// x 16 rows; weights LDS double-buffered in 64-col chunks (stage ch+1 under
// compute ch); per-wave 4 KB swizzled LDS transpose for the hidden.
// LDS = 64 KB weights + 16 KB HW = 80 KB -> 2 blocks/CU.
// ---------------------------------------------------------------------------
__global__ __launch_bounds__(256, 2) void ffn_v4(
    const float* __restrict__ h, const unsigned* __restrict__ accp,
    const float* __restrict__ g, const float* __restrict__ b,
    const unsigned short* __restrict__ w1t, const float* __restrict__ b1,
    const unsigned short* __restrict__ w2t, const float* __restrict__ b2,
    float* __restrict__ out, float invC)
{
    __shared__ unsigned short WB[2][16384];  // 2 x (16KB W1-chunk + 16KB W2-chunk)
    __shared__ float HW[4][1024];            // per-wave 16x64 f32, XOR-swizzled
    int t = threadIdx.x, w = t >> 6, l = t & 63;
    int l15 = l & 15, lq = l >> 4;
    size_t rw = (size_t)blockIdx.x * 64 + w * 16;
    size_t myrow = rw + l15;
    float* myHW = HW[w];

    // ---- h_new = h + acc*invC (32 cols/lane), LN, pack A-frags
    const unsigned* ap = accp + myrow * 64 + lq * 8;
    uint4 ua0 = *(const uint4*)(ap);
    uint4 ua1 = *(const uint4*)(ap + 4);
    uint4 ub0 = *(const uint4*)(ap + 32);
    uint4 ub1 = *(const uint4*)(ap + 36);
    const float* hp = h + myrow * 128 + lq * 8;
    float4 hf[4][2];
    hf[0][0] = *(const float4*)(hp);      hf[0][1] = *(const float4*)(hp + 4);
    hf[1][0] = *(const float4*)(hp + 32); hf[1][1] = *(const float4*)(hp + 36);
    hf[2][0] = *(const float4*)(hp + 64); hf[2][1] = *(const float4*)(hp + 68);
    hf[3][0] = *(const float4*)(hp + 96); hf[3][1] = *(const float4*)(hp + 100);
    unsigned ua[8] = {ua0.x, ua0.y, ua0.z, ua0.w, ua1.x, ua1.y, ua1.z, ua1.w};
    unsigned ub[8] = {ub0.x, ub0.y, ub0.z, ub0.w, ub1.x, ub1.y, ub1.z, ub1.w};
    float hv[4][8];
#pragma unroll
    for (int j = 0; j < 8; ++j) {
        hv[0][j] = ((const float*)hf[0])[j] + bf2f(ua[j] & 0xffffu) * invC;
        hv[1][j] = ((const float*)hf[1])[j] + bf2f(ub[j] & 0xffffu) * invC;
        hv[2][j] = ((const float*)hf[2])[j] + bf2f(ua[j] >> 16) * invC;
        hv[3][j] = ((const float*)hf[3])[j] + bf2f(ub[j] >> 16) * invC;
    }
    float s = 0.f;
#pragma unroll
    for (int ks = 0; ks < 4; ++ks)
#pragma unroll
        for (int j = 0; j < 8; ++j) s += hv[ks][j];
    s += __shfl_xor(s, 16); s += __shfl_xor(s, 32);
    float mean = s * (1.0f / 128.0f);
    float v = 0.f;
#pragma unroll
    for (int ks = 0; ks < 4; ++ks)
#pragma unroll
        for (int j = 0; j < 8; ++j) { float dd = hv[ks][j] - mean; v += dd * dd; }
    v += __shfl_xor(v, 16); v += __shfl_xor(v, 32);
    float rstd = rsqrtf(v * (1.0f / 128.0f) + 1e-5f);
    bf16x8 af[4];
#pragma unroll
    for (int ks = 0; ks < 4; ++ks) {
        int col0 = ks * 32 + lq * 8;
        float y[8];
#pragma unroll
        for (int j = 0; j < 8; ++j)
            y[j] = g[col0 + j] * (hv[ks][j] - mean) * rstd + b[col0 + j];
        af[ks] = pack8(y);
    }

    // ---- stage chunk 0
#pragma unroll
    for (int i = 0; i < 4; ++i) {
        gll16(w1t + i * 2048 + t * 8, (char*)WB[0] + i * 4096 + t * 16);
        gll16(w2t + i * 2048 + t * 8, (char*)WB[0] + 16384 + i * 4096 + t * 16);
    }
    f32x4 facc[8];
#pragma unroll
    for (int n = 0; n < 8; ++n) facc[n] = (f32x4){0.f, 0.f, 0.f, 0.f};
    __syncthreads();

    int buf = 0;
    int swR = (l15 & 7) << 2;
    for (int ch = 0; ch < 8; ++ch) {
        if (ch < 7) {
            const unsigned short* s1p = w1t + (ch + 1) * 8192;
            const unsigned short* s2p = w2t + (ch + 1) * 8192;
#pragma unroll
            for (int i = 0; i < 4; ++i) {
                gll16(s1p + i * 2048 + t * 8, (char*)WB[buf ^ 1] + i * 4096 + t * 16);
                gll16(s2p + i * 2048 + t * 8, (char*)WB[buf ^ 1] + 16384 + i * 4096 + t * 16);
            }
        }
        // gemm1: 16 rows x 64 hidden cols
        f32x4 acc1[4];
#pragma unroll
        for (int n = 0; n < 4; ++n) acc1[n] = (f32x4){0.f, 0.f, 0.f, 0.f};
#pragma unroll
        for (int ks = 0; ks < 4; ++ks)
#pragma unroll
            for (int nf = 0; nf < 4; ++nf) {
                bf16x8 bw = *(const bf16x8*)(WB[buf] + ((nf * 4 + ks) * 64 + l) * 8);
                acc1[nf] = __builtin_amdgcn_mfma_f32_16x16x32_bf16(af[ks], bw, acc1[nf], 0, 0, 0);
            }
        // GELU + b1 -> per-wave swizzled LDS
#pragma unroll
        for (int nf = 0; nf < 4; ++nf) {
            float bv = b1[ch * 64 + nf * 16 + l15];
#pragma unroll
            for (int reg = 0; reg < 4; ++reg) {
                int row = lq * 4 + reg;
                float x = acc1[nf][reg] + bv;
                float ge = 0.5f * x * (1.0f + erff(x * 0.70710678118654752f));
                myHW[row * 64 + ((nf * 16 + l15) ^ ((row & 7) << 2))] = ge;
            }
        }
        // gemm2: transpose-read, cvt, accumulate
#pragma unroll
        for (int ks2 = 0; ks2 < 2; ++ks2) {
            int cb = ks2 * 32 + lq * 8;
            f32x4 x0 = *(const f32x4*)(myHW + l15 * 64 + (cb ^ swR));
            f32x4 x1 = *(const f32x4*)(myHW + l15 * 64 + ((cb + 4) ^ swR));
            bf16x8 a2 = pack8v(x0, x1);
#pragma unroll
            for (int nf = 0; nf < 8; ++nf) {
                bf16x8 bw = *(const bf16x8*)(WB[buf] + 8192 + ((ks2 * 8 + nf) * 64 + l) * 8);
                facc[nf] = __builtin_amdgcn_mfma_f32_16x16x32_bf16(a2, bw, facc[nf], 0, 0, 0);
            }
        }
        __syncthreads();
        buf ^= 1;
    }
    // ---- epilogue: out = h + acc*invC + ffn + b2 (D layout)
#pragma unroll
    for (int nf = 0; nf < 8; ++nf) {
        int col = nf * 16 + l15;
        float bv = b2[col];
        int ci = (col < 64) ? col : col - 64;
        bool hi = col >= 64;
#pragma unroll
        for (int reg = 0; reg < 4; ++reg) {
            size_t row = rw + lq * 4 + reg;
            unsigned pv = accp[row * 64 + ci];
            float av = bf2f(hi ? (pv >> 16) : (pv & 0xffffu));
            out[row * 128 + col] = h[row * 128 + col] + av * invC + facc[nf][reg] + bv;
        }
    }
}

// ---------------------------------------------------------------------------
extern "C" void kernel_launch(void* const* d_in, const int* in_sizes, int n_in,
                              void* d_out, int out_size, void* d_ws, size_t ws_size,
                              hipStream_t stream)
{
    const float* h_enz  = (const float*)d_in[0];
    const float* h_met  = (const float*)d_in[1];
    const float* h_rxn  = (const float*)d_in[2];
    const float* ef_mod = (const float*)d_in[3];
    const float* ef_sig = (const float*)d_in[4];
    const float* ef_brg = (const float*)d_in[5];
    const float* ef_trn = (const float*)d_in[6];
    const float* ln1_g  = (const float*)d_in[7];
    const float* ln1_b  = (const float*)d_in[8];
    const float* ln2_g  = (const float*)d_in[9];
    const float* ln2_b  = (const float*)d_in[10];
    const float* wp     = (const float*)d_in[11];
    const float* bp     = (const float*)d_in[12];
    const float* wl     = (const float*)d_in[13];
    const float* a_src  = (const float*)d_in[14];
    const float* a_dst  = (const float*)d_in[15];
    const float* we     = (const float*)d_in[16];
    const float* a_edge = (const float*)d_in[17];
    const float* w1     = (const float*)d_in[18];
    const float* b1     = (const float*)d_in[19];
    const float* w2     = (const float*)d_in[20];
    const float* b2     = (const float*)d_in[21];
    const int* src_sub  = (const int*)d_in[22];
    const int* dst_sub  = (const int*)d_in[23];
    const int* src_prod = (const int*)d_in[24];
    const int* dst_prod = (const int*)d_in[25];
    const int* src_cat  = (const int*)d_in[26];
    const int* dst_cat  = (const int*)d_in[27];
    const int* src_mod  = (const int*)d_in[28];
    const int* dst_mod  = (const int*)d_in[29];
    const int* src_reg  = (const int*)d_in[30];
    const int* dst_reg  = (const int*)d_in[31];
    const int* src_sig  = (const int*)d_in[32];
    const int* dst_sig  = (const int*)d_in[33];
    const int* src_brg  = (const int*)d_in[34];
    const int* dst_brg  = (const int*)d_in[35];
    const int* src_trn  = (const int*)d_in[36];
    const int* dst_trn  = (const int*)d_in[37];
    float* out = (float*)d_out;

    // workspace (~97 MB; proven budget >= 116.6 MB)
    char* p = (char*)d_ws;
    unsigned* accp = (unsigned*)p;            p += (size_t)NTOT * 64 * 4;
    unsigned* Zp   = (unsigned*)p;            p += (size_t)NM * 64 * 4;
    float* lsb  = (float*)p;                  p += (size_t)NM * 4 * 4;
    float* ldb  = (float*)p;                  p += (size_t)NM * 4 * 4;
    float* ld3b = (float*)p;                  p += (size_t)NR * 4 * 4;
    float* ld5b = (float*)p;                  p += (size_t)NE * 4 * 4;
    unsigned short* wbf = (unsigned short*)p; p += (size_t)524288 * 2;
    unsigned short* wq  = (unsigned short*)p; p += (size_t)7 * 2048 * 2;
    unsigned* hist = (unsigned*)p;            p += (size_t)8 * NDPAD * 4;
    unsigned* rowptr = (unsigned*)p;          p += (size_t)8 * RPS * 4;
    int2* epair = (int2*)p;                   p += (size_t)8 * E2 * 8;
    float* ef4 = (float*)p;                   p += (size_t)4 * E2 * 16;
    unsigned* blksum = (unsigned*)p;          p += (size_t)8 * 256 * 4;
    if (ws_size < (size_t)(p - (char*)d_ws)) return;

    unsigned* nrm32 = (unsigned*)d_out;
    const unsigned short* nbf_enz = (const unsigned short*)d_out;
    const unsigned short* nbf_met = nbf_enz + (size_t)NE * 128;
    const unsigned short* nbf_rxn = nbf_enz + (size_t)(NE + NM) * 128;
    unsigned* acc_enz = accp;
    unsigned* acc_met = accp + (size_t)NE * 64;
    unsigned* acc_rxn = accp + (size_t)(NE + NM) * 64;

    P8 dsts, srcs;
    dsts.a[0] = dst_sub;  srcs.a[0] = src_sub;
    dsts.a[1] = dst_prod; srcs.a[1] = src_prod;
    dsts.a[2] = dst_cat;  srcs.a[2] = src_cat;
    dsts.a[3] = dst_mod;  srcs.a[3] = src_mod;
    dsts.a[4] = dst_reg;  srcs.a[4] = src_reg;
    dsts.a[5] = dst_sig;  srcs.a[5] = src_sig;
    dsts.a[6] = dst_brg;  srcs.a[6] = src_brg;
    dsts.a[7] = dst_trn;  srcs.a[7] = src_trn;

    // ---- prep
    hipMemsetAsync(hist, 0, (size_t)8 * NDPAD * 4, stream);
    convw<<<2048, 256, 0, stream>>>(wp, wl, w1, w2, wbf);
    ln1_kernel<<<NTOT / 4, 256, 0, stream>>>(h_enz, h_met, h_rxn, ln1_g, ln1_b, nrm32);
    wqk<<<28, 256, 0, stream>>>(wl, a_src, a_dst, wq);
    hist_all<<<8192, 256, 0, stream>>>(dsts, hist);
    scan1<<<2048, 256, 0, stream>>>(hist, rowptr, blksum);
    scan2<<<8, 256, 0, stream>>>(blksum, rowptr);
    scan3<<<2048, 256, 0, stream>>>(rowptr, blksum);
    hipMemsetAsync(hist, 0, (size_t)8 * NDPAD * 4, stream);
    scatter_all<<<8192, 256, 0, stream>>>(dsts, srcs, rowptr, hist, epair);
    efpre<<<4096, 256, 0, stream>>>(epair, ef_mod, ef_sig, ef_brg, ef_trn, we, a_edge, ef4);

#define RP(r) (rowptr + (size_t)(r) * RPS)
#define EP(r) (epair + (size_t)(r) * E2)
#define WQS(s) (wq + (size_t)(s) * 2048)
#define EF4(er) (ef4 + (size_t)(er) * E2 * 4)

    // ---- rel 0: substrate_of (met->rxn), phys wp0
    gemm_v2<0, true><<<NM / 128, 256, 0, stream>>>(nbf_met, wbf + 0 * 16384, bp + 0, Zp,
                                                   nullptr, nullptr, nullptr);
    phys_gather<<<NR / 4, 256, 0, stream>>>(RP(0), EP(0), Zp, acc_rxn, NR, 0);
    // ---- rel 1: produces (rxn->met), phys wp1 (+ rel3's dst logits via WQ site0)
    gemm_v2<1, true><<<NR / 128, 256, 0, stream>>>(nbf_rxn, wbf + 1 * 16384, bp + 128, Zp,
                                                   WQS(0), ld3b, nullptr);
    phys_gather<<<NM / 4, 256, 0, stream>>>(RP(1), EP(1), Zp, acc_met, NM, 0);
    // ---- rel 2: catalyzes (enz->rxn), phys wp2 (+ rel5's dst logits, site1)
    gemm_v2<1, true><<<NE / 128, 256, 0, stream>>>(nbf_enz, wbf + 2 * 16384, bp + 256, Zp,
                                                   WQS(1), ld5b, nullptr);
    phys_gather<<<NR / 4, 256, 0, stream>>>(RP(2), EP(2), Zp, acc_rxn, NR, 1);

    // ---- rel 3: modulates (enz->rxn), wl0 + ef_mod
    gemm_v2<1, false><<<NE / 128, 256, 0, stream>>>(nbf_enz, wbf + 3 * 16384, nullptr, Zp,
                                                    WQS(2), lsb, nullptr);
    gat_gather<true><<<NR / 4, 256, 0, stream>>>(RP(3), EP(3), Zp, lsb, ld3b, EF4(0),
                                                 acc_rxn, NR, 1);
    // ---- rel 4: regulates (enz->enz), wl1, no ef
    gemm_v2<2, false><<<NE / 128, 256, 0, stream>>>(nbf_enz, wbf + 4 * 16384, nullptr, Zp,
                                                    WQS(3), lsb, ldb);
    gat_gather<false><<<NE / 4, 256, 0, stream>>>(RP(4), EP(4), Zp, lsb, ldb, nullptr,
                                                  acc_enz, NE, 0);
    // ---- rel 5: signaling (met->enz), wl2 + ef_sig
    gemm_v2<1, false><<<NM / 128, 256, 0, stream>>>(nbf_met, wbf + 5 * 16384, nullptr, Zp,
                                                    WQS(4), lsb, nullptr);
    gat_gather<true><<<NE / 4, 256, 0, stream>>>(RP(5), EP(5), Zp, lsb, ld5b, EF4(1),
                                                 acc_enz, NE, 1);
    // ---- rel 6: bridges (met->met), wl3 + ef_brg
    gemm_v2<2, false><<<NM / 128, 256, 0, stream>>>(nbf_met, wbf + 6 * 16384, nullptr, Zp,
                                                    WQS(5), lsb, ldb);
    gat_gather<true><<<NM / 4, 256, 0, stream>>>(RP(6), EP(6), Zp, lsb, ldb, EF4(2),
                                                 acc_met, NM, 1);
    // ---- rel 7: transports_to (met->met), wl4 + ef_trn
    gemm_v2<2, false><<<NM / 128, 256, 0, stream>>>(nbf_met, wbf + 7 * 16384, nullptr, Zp,
                                                    WQS(6), lsb, ldb);
    gat_gather<true><<<NM / 4, 256, 0, stream>>>(RP(7), EP(7), Zp, lsb, ldb, EF4(3),
                                                 acc_met, NM, 1);

    // ---- fused combine + LN2 + FFN (+residual), per node type
    ffn_v4<<<NE / 64, 256, 0, stream>>>(h_enz, acc_enz, ln2_g + 0, ln2_b + 0,
                                        wbf + W1T_OFF + 0 * 65536, b1 + 0,
                                        wbf + W2T_OFF + 0 * 65536, b2 + 0,
                                        out + 0, 0.5f);
    ffn_v4<<<NM / 64, 256, 0, stream>>>(h_met, acc_met, ln2_g + 128, ln2_b + 128,
                                        wbf + W1T_OFF + 1 * 65536, b1 + 512,
                                        wbf + W2T_OFF + 1 * 65536, b2 + 128,
                                        out + (size_t)NE * 128, 1.0f / 3.0f);
    ffn_v4<<<NR / 64, 256, 0, stream>>>(h_rxn, acc_rxn, ln2_g + 256, ln2_b + 256,
                                        wbf + W1T_OFF + 2 * 65536, b1 + 1024,
                                        wbf + W2T_OFF + 2 * 65536, b2 + 256,
                                        out + (size_t)(NE + NM) * 128, 1.0f / 3.0f);
#undef RP
#undef EP
#undef WQS
#undef EF4
}

// Round 5
// 648.106 us; speedup vs baseline: 5.9634x; 1.1850x over previous
//
#include <hip/hip_runtime.h>
#include <cstddef>

#define NE 32768
#define NM 65536
#define NR 49152
#define NTOT 147456
#define E2 262144
#define NDPAD 65536
#define RPS 65537
#define W1T_OFF 131072
#define W2T_OFF 327680

typedef __attribute__((ext_vector_type(8))) short bf16x8;
typedef __attribute__((ext_vector_type(4))) float f32x4;

__device__ __forceinline__ unsigned short f2bf(float x) {
    unsigned u = __float_as_uint(x);
    return (unsigned short)((u + 0x7FFFu + ((u >> 16) & 1u)) >> 16);
}
__device__ __forceinline__ float bf2f(unsigned s) { return __uint_as_float(s << 16); }
__device__ __forceinline__ unsigned pk2(float a, float b) {
    return (unsigned)f2bf(a) | ((unsigned)f2bf(b) << 16);
}
__device__ __forceinline__ bf16x8 pack8(const float* v) {
    union { bf16x8 b; unsigned u[4]; } r;
#pragma unroll
    for (int i = 0; i < 4; ++i) r.u[i] = pk2(v[2 * i], v[2 * i + 1]);
    return r.b;
}
__device__ __forceinline__ bf16x8 pack8v(f32x4 a, f32x4 b) {
    union { bf16x8 v; unsigned u[4]; } r;
    r.u[0] = pk2(a[0], a[1]); r.u[1] = pk2(a[2], a[3]);
    r.u[2] = pk2(b[0], b[1]); r.u[3] = pk2(b[2], b[3]);
    return r.v;
}
// async global->LDS, 16B per lane (wave-uniform base + lane*16)
__device__ __forceinline__ void gll16(const void* g, void* l) {
    __builtin_amdgcn_global_load_lds(
        (const __attribute__((address_space(1))) void*)g,
        (__attribute__((address_space(3))) void*)l, 16, 0, 0);
}

// ---------------------------------------------------------------------------
// Weights -> bf16 FRAGMENT-PACKED (see round-3 comments).
// ---------------------------------------------------------------------------
__global__ __launch_bounds__(256) void convw(
    const float* __restrict__ wp, const float* __restrict__ wl,
    const float* __restrict__ w1, const float* __restrict__ w2,
    unsigned short* __restrict__ wbf)
{
    int i = blockIdx.x * 256 + threadIdx.x;
    float v;
    if (i < 131072) {
        int mat = i >> 14, r = i & 16383;
        int frag = r >> 9, lane = (r >> 3) & 63, j = r & 7;
        int nf = frag >> 2, ks = frag & 3;
        int n = nf * 16 + (lane & 15);
        int k = ks * 32 + (lane >> 4) * 8 + j;
        const float* src = (mat < 3) ? (wp + mat * 16384) : (wl + (mat - 3) * 16384);
        v = src[k * 128 + n];
    } else if (i < 327680) {
        int ii = i - 131072; int mat = ii >> 16, r = ii & 65535;
        int frag = r >> 9, lane = (r >> 3) & 63, j = r & 7;
        int nf = frag >> 2, ks = frag & 3;
        int n = nf * 16 + (lane & 15);
        int k = ks * 32 + (lane >> 4) * 8 + j;
        v = w1[mat * 65536 + k * 512 + n];
    } else {
        int ii = i - 327680; int mat = ii >> 16, r = ii & 65535;
        int frag = r >> 9, lane = (r >> 3) & 63, j = r & 7;
        int ks = frag >> 3, nf = frag & 7;
        int n = nf * 16 + (lane & 15);
        int k = ks * 32 + (lane >> 4) * 8 + j;
        v = w2[mat * 65536 + k * 128 + n];
    }
    wbf[i] = f2bf(v);
}

// ---------------------------------------------------------------------------
// WQ[site] = W . a  (128 x 8 logit-fold matrices), fragment-packed.
// ---------------------------------------------------------------------------
__global__ __launch_bounds__(256) void wqk(
    const float* __restrict__ wl, const float* __restrict__ a_src,
    const float* __restrict__ a_dst, unsigned short* __restrict__ wq)
{
    const int wi[7]  = {0, 2, 0, 1, 2, 3, 4};
    const int loi[7] = {0, 2, 0, 1, 2, 3, 4};
    const int lod[7] = {1, 1, 0, 0, 0, 0, 0};
    const int hii[7] = {-1, -1, -1, 1, -1, 3, 4};
    int site = blockIdx.x >> 2, ks = blockIdx.x & 3, t = threadIdx.x;
    const float* W = wl + wi[site] * 16384;
#pragma unroll
    for (int rep = 0; rep < 2; ++rep) {
        int e = t * 2 + rep;
        int lane = e >> 3, j = e & 7;
        int n = lane & 15;
        int k = ks * 32 + (lane >> 4) * 8 + j;
        float v = 0.f;
        if (n < 4) {
            const float* a = (lod[site] ? a_dst : a_src) + loi[site] * 128;
#pragma unroll 8
            for (int d = 0; d < 32; ++d) v += W[k * 128 + n * 32 + d] * a[n * 32 + d];
        } else if (n < 8 && hii[site] >= 0) {
            const float* a = a_dst + hii[site] * 128;
            int hh = n - 4;
#pragma unroll 8
            for (int d = 0; d < 32; ++d) v += W[k * 128 + hh * 32 + d] * a[hh * 32 + d];
        }
        wq[((site * 4 + ks) * 64 + lane) * 8 + j] = f2bf(v);
    }
}

// ---------------------------------------------------------------------------
__global__ __launch_bounds__(256) void ln1_kernel(
    const float* __restrict__ he, const float* __restrict__ hm, const float* __restrict__ hr,
    const float* __restrict__ g, const float* __restrict__ b, unsigned* __restrict__ nout)
{
    int row  = blockIdx.x * 4 + (threadIdx.x >> 6);
    int lane = threadIdx.x & 63;
    const float* src; int ti; int lr;
    if (row < NE)           { src = he; ti = 0; lr = row; }
    else if (row < NE + NM) { src = hm; ti = 1; lr = row - NE; }
    else                    { src = hr; ti = 2; lr = row - NE - NM; }
    float2 x = *(const float2*)(src + (size_t)lr * 128 + lane * 2);
    float s = x.x + x.y;
#pragma unroll
    for (int o = 32; o; o >>= 1) s += __shfl_xor(s, o);
    float mean = s * (1.0f / 128.0f);
    float dx = x.x - mean, dy = x.y - mean;
    float v = dx * dx + dy * dy;
#pragma unroll
    for (int o = 32; o; o >>= 1) v += __shfl_xor(v, o);
    float rstd = rsqrtf(v * (1.0f / 128.0f) + 1e-5f);
    int c = lane * 2;
    float y0 = g[ti * 128 + c]     * dx * rstd + b[ti * 128 + c];
    float y1 = g[ti * 128 + c + 1] * dy * rstd + b[ti * 128 + c + 1];
    nout[(size_t)row * 64 + lane] = pk2(y0, y1);
}

// ---------------------------------------------------------------------------
// GEMM: Z[M,128] = A @ W (+bias), weights LDS-staged per block; logits via
// MFMA with tiny WQ B-frags.  LOG: 0 none, 1 -> oa, 2 -> oa + ob.
// ---------------------------------------------------------------------------
template <int LOG, bool BIAS>
__global__ __launch_bounds__(256) void gemm_v2(
    const unsigned short* __restrict__ A, const unsigned short* __restrict__ Wt,
    const float* __restrict__ bias, unsigned* __restrict__ Zp,
    const unsigned short* __restrict__ WQ, float* __restrict__ oa, float* __restrict__ ob)
{
    __shared__ unsigned short WL[16384];   // 32 KB
    int t = threadIdx.x, w = t >> 6, l = t & 63;
    int l15 = l & 15, lq = l >> 4;
#pragma unroll
    for (int i = 0; i < 8; ++i)
        gll16(Wt + i * 2048 + t * 8, (char*)WL + i * 4096 + t * 16);
    size_t row0 = (size_t)blockIdx.x * 128 + w * 32;
    f32x4 acc[2][8]; f32x4 accl[2];
#pragma unroll
    for (int r = 0; r < 2; ++r) {
        accl[r] = (f32x4){0.f, 0.f, 0.f, 0.f};
#pragma unroll
        for (int n = 0; n < 8; ++n) acc[r][n] = (f32x4){0.f, 0.f, 0.f, 0.f};
    }
    bf16x8 qf[4];
    if constexpr (LOG >= 1) {
#pragma unroll
        for (int ks = 0; ks < 4; ++ks) qf[ks] = *(const bf16x8*)(WQ + (ks * 64 + l) * 8);
    }
    __syncthreads();
#pragma unroll
    for (int ks = 0; ks < 4; ++ks) {
        int k0 = ks * 32 + lq * 8;
        bf16x8 a0 = *(const bf16x8*)(A + (row0 + l15) * 128 + k0);
        bf16x8 a1 = *(const bf16x8*)(A + (row0 + 16 + l15) * 128 + k0);
#pragma unroll
        for (int n = 0; n < 8; ++n) {
            bf16x8 bw = *(const bf16x8*)(WL + ((n * 4 + ks) * 64 + l) * 8);
            acc[0][n] = __builtin_amdgcn_mfma_f32_16x16x32_bf16(a0, bw, acc[0][n], 0, 0, 0);
            acc[1][n] = __builtin_amdgcn_mfma_f32_16x16x32_bf16(a1, bw, acc[1][n], 0, 0, 0);
        }
        if constexpr (LOG >= 1) {
            accl[0] = __builtin_amdgcn_mfma_f32_16x16x32_bf16(a0, qf[ks], accl[0], 0, 0, 0);
            accl[1] = __builtin_amdgcn_mfma_f32_16x16x32_bf16(a1, qf[ks], accl[1], 0, 0, 0);
        }
    }
#pragma unroll
    for (int n = 0; n < 4; ++n) {
        float bl = BIAS ? bias[n * 16 + l15] : 0.f;
        float bh = BIAS ? bias[n * 16 + l15 + 64] : 0.f;
#pragma unroll
        for (int r = 0; r < 2; ++r)
#pragma unroll
            for (int reg = 0; reg < 4; ++reg) {
                size_t row = row0 + r * 16 + lq * 4 + reg;
                Zp[row * 64 + n * 16 + l15] = pk2(acc[r][n][reg] + bl, acc[r][n + 4][reg] + bh);
            }
    }
    if constexpr (LOG >= 1) {
#pragma unroll
        for (int r = 0; r < 2; ++r)
#pragma unroll
            for (int reg = 0; reg < 4; ++reg) {
                size_t row = row0 + r * 16 + lq * 4 + reg;
                if (l15 < 4) oa[row * 4 + l15] = accl[r][reg];
                else if (LOG == 2 && l15 < 8) ob[row * 4 + (l15 - 4)] = accl[r][reg];
            }
    }
}

// ---------------------------------------------------------------------------
// CSR build, two-level bucket partition.  bucket = dst >> 8 (256 buckets).
// Packed edge record: u64 = src | dst<<16 | eid<<32 (all fit their fields).
// ---------------------------------------------------------------------------
struct P8 { const int* a[8]; };
#define CHUNK 2048

// P0: global bucket counts (LDS-aggregated)
__global__ __launch_bounds__(256) void bucket_count(P8 dsts, unsigned* __restrict__ bcnt)
{
    __shared__ unsigned lh[256];
    int blk = blockIdx.x, rel = blk >> 7, cb = blk & 127, t = threadIdx.x;
    lh[t] = 0; __syncthreads();
    const int* dp = dsts.a[rel] + cb * CHUNK;
#pragma unroll
    for (int it = 0; it < 8; ++it) atomicAdd(&lh[dp[it * 256 + t] >> 8], 1u);
    __syncthreads();
    atomicAdd(&bcnt[rel * 256 + t], lh[t]);
}

// exclusive prefix over 2048 bucket counts -> bbase (+ copy to bcur)
__global__ __launch_bounds__(256) void scanB(const unsigned* __restrict__ bcnt,
                                             unsigned* __restrict__ bbase,
                                             unsigned* __restrict__ bcur)
{
    __shared__ unsigned ts[256];
    int t = threadIdx.x;
    unsigned v[8]; unsigned run = 0;
#pragma unroll
    for (int i = 0; i < 8; ++i) { v[i] = bcnt[t * 8 + i]; run += v[i]; }
    ts[t] = run; __syncthreads();
    for (int off = 1; off < 256; off <<= 1) {
        unsigned x = (t >= off) ? ts[t - off] : 0u;
        __syncthreads(); ts[t] += x; __syncthreads();
    }
    unsigned base = ts[t] - run;
#pragma unroll
    for (int i = 0; i < 8; ++i) { bbase[t * 8 + i] = base; bcur[t * 8 + i] = base; base += v[i]; }
    if (t == 255) bbase[2048] = base;
}

// P1: scatter packed records into contiguous bucket regions
__global__ __launch_bounds__(256) void bucket_fill(P8 dsts, P8 srcs,
                                                   unsigned* __restrict__ bcur,
                                                   unsigned long long* __restrict__ bb)
{
    __shared__ unsigned lh[256], lbase[256], lcur[256];
    int blk = blockIdx.x, rel = blk >> 7, cb = blk & 127, t = threadIdx.x;
    lh[t] = 0; lcur[t] = 0; __syncthreads();
    const int* dp = dsts.a[rel] + cb * CHUNK;
    const int* sp = srcs.a[rel] + cb * CHUNK;
    int dv[8];
#pragma unroll
    for (int it = 0; it < 8; ++it) { dv[it] = dp[it * 256 + t]; atomicAdd(&lh[dv[it] >> 8], 1u); }
    __syncthreads();
    lbase[t] = atomicAdd(&bcur[rel * 256 + t], lh[t]);
    __syncthreads();
#pragma unroll
    for (int it = 0; it < 8; ++it) {
        unsigned e = (unsigned)(cb * CHUNK + it * 256 + t);
        unsigned d = (unsigned)dv[it];
        unsigned s = (unsigned)sp[it * 256 + t];
        unsigned pos = atomicAdd(&lcur[d >> 8], 1u);
        bb[lbase[d >> 8] + pos] =
            (unsigned long long)s | ((unsigned long long)d << 16) | ((unsigned long long)e << 32);
    }
}

// P2a: per-dst histogram from bucket segments (coalesced hist write)
__global__ __launch_bounds__(256) void bucket_hist(const unsigned long long* __restrict__ bb,
                                                   const unsigned* __restrict__ bbase,
                                                   unsigned* __restrict__ hist)
{
    __shared__ unsigned lh[256];
    int blk = blockIdx.x, rel = blk >> 8, b = blk & 255, t = threadIdx.x;
    lh[t] = 0; __syncthreads();
    unsigned s0 = bbase[blk], s1 = bbase[blk + 1];
    for (unsigned i = s0 + t; i < s1; i += 256)
        atomicAdd(&lh[(unsigned)(bb[i] >> 16) & 255u], 1u);
    __syncthreads();
    hist[(size_t)rel * NDPAD + b * 256 + t] = lh[t];
}

__global__ __launch_bounds__(256) void scan1(const unsigned* __restrict__ hist,
                                             unsigned* __restrict__ rowptr,
                                             unsigned* __restrict__ blksum)
{
    __shared__ unsigned s[256];
    int b = blockIdx.x, rel = b >> 8, c = b & 255, t = threadIdx.x;
    unsigned v = hist[(size_t)rel * NDPAD + c * 256 + t];
    s[t] = v; __syncthreads();
    for (int off = 1; off < 256; off <<= 1) {
        unsigned x = (t >= off) ? s[t - off] : 0u;
        __syncthreads();
        s[t] += x;
        __syncthreads();
    }
    rowptr[(size_t)rel * RPS + c * 256 + t] = s[t] - v;
    if (t == 255) blksum[rel * 256 + c] = s[255];
}

__global__ __launch_bounds__(256) void scan2(unsigned* __restrict__ blksum,
                                             unsigned* __restrict__ rowptr)
{
    __shared__ unsigned s[256];
    int rel = blockIdx.x, t = threadIdx.x;
    unsigned v = blksum[rel * 256 + t];
    s[t] = v; __syncthreads();
    for (int off = 1; off < 256; off <<= 1) {
        unsigned x = (t >= off) ? s[t - off] : 0u;
        __syncthreads();
        s[t] += x;
        __syncthreads();
    }
    blksum[rel * 256 + t] = s[t] - v;
    if (t == 255) rowptr[(size_t)rel * RPS + 65536] = s[255];
}

__global__ __launch_bounds__(256) void scan3(unsigned* __restrict__ rowptr,
                                             const unsigned* __restrict__ blksum)
{
    int b = blockIdx.x, rel = b >> 8, c = b & 255, t = threadIdx.x;
    rowptr[(size_t)rel * RPS + c * 256 + t] += blksum[rel * 256 + c];
}

// P2b: place into final CSR; writes confined to this bucket's ~8-16KB window
__global__ __launch_bounds__(256) void bucket_place(const unsigned long long* __restrict__ bb,
                                                    const unsigned* __restrict__ bbase,
                                                    const unsigned* __restrict__ rowptr,
                                                    int2* __restrict__ epair)
{
    __shared__ unsigned lrp[256], lcur[256];
    int blk = blockIdx.x, rel = blk >> 8, b = blk & 255, t = threadIdx.x;
    lrp[t] = rowptr[(size_t)rel * RPS + b * 256 + t];
    lcur[t] = 0; __syncthreads();
    unsigned s0 = bbase[blk], s1 = bbase[blk + 1];
    for (unsigned i = s0 + t; i < s1; i += 256) {
        unsigned long long pk = bb[i];
        unsigned s = (unsigned)pk & 0xffffu;
        unsigned d8 = (unsigned)(pk >> 16) & 255u;
        unsigned e = (unsigned)(pk >> 32);
        unsigned pos = atomicAdd(&lcur[d8], 1u);
        epair[(size_t)rel * E2 + lrp[d8] + pos] = make_int2((int)s, (int)e);
    }
}

// ---------------------------------------------------------------------------
// Per-edge (ef @ M) in CSR order, packed bf16x4 (8 B/edge).
// ---------------------------------------------------------------------------
__global__ __launch_bounds__(256) void efpre(
    const int2* __restrict__ epair,
    const float* __restrict__ efm, const float* __restrict__ efs,
    const float* __restrict__ efb, const float* __restrict__ eft,
    const float* __restrict__ we, const float* __restrict__ ae,
    uint2* __restrict__ ef4p)
{
    __shared__ float M[8][4];
    int b = blockIdx.x, t = threadIdx.x;
    int er = b >> 10;
    const int relmap[4] = {3, 5, 6, 7};
    const float* ef = (er == 0) ? efm : (er == 1) ? efs : (er == 2) ? efb : eft;
    if (t < 32) {
        int f = t >> 2, hh = t & 3;
        float s = 0.f;
#pragma unroll 8
        for (int d = 0; d < 32; ++d) s += we[er * 1024 + f * 128 + hh * 32 + d] * ae[er * 128 + hh * 32 + d];
        M[f][hh] = s;
    }
    __syncthreads();
    int i = (b & 1023) * 256 + t;
    size_t idx = (size_t)relmap[er] * E2 + i;
    int eid = epair[idx].y;
    float4 a = *(const float4*)(ef + (size_t)eid * 8);
    float4 c = *(const float4*)(ef + (size_t)eid * 8 + 4);
    float o0 = a.x*M[0][0]+a.y*M[1][0]+a.z*M[2][0]+a.w*M[3][0]+c.x*M[4][0]+c.y*M[5][0]+c.z*M[6][0]+c.w*M[7][0];
    float o1 = a.x*M[0][1]+a.y*M[1][1]+a.z*M[2][1]+a.w*M[3][1]+c.x*M[4][1]+c.y*M[5][1]+c.z*M[6][1]+c.w*M[7][1];
    float o2 = a.x*M[0][2]+a.y*M[1][2]+a.z*M[2][2]+a.w*M[3][2]+c.x*M[4][2]+c.y*M[5][2]+c.z*M[6][2]+c.w*M[7][2];
    float o3 = a.x*M[0][3]+a.y*M[1][3]+a.z*M[2][3]+a.w*M[3][3]+c.x*M[4][3]+c.y*M[5][3]+c.z*M[6][3]+c.w*M[7][3];
    uint2 o; o.x = pk2(o0, o1); o.y = pk2(o2, o3);
    ef4p[(size_t)er * E2 + i] = o;
}

// ---------------------------------------------------------------------------
// KineticConv gather: batch-4 deep memory pipeline.
// ---------------------------------------------------------------------------
__global__ __launch_bounds__(256) void phys_gather(
    const unsigned* __restrict__ rowptr, const int2* __restrict__ epair,
    const unsigned* __restrict__ Zp, unsigned* __restrict__ accp,
    int n_nodes, int accum)
{
    int t = threadIdx.x, w = t >> 6, l = t & 63;
    int d = blockIdx.x * 4 + w;
    if (d >= n_nodes) return;
    unsigned s0 = rowptr[d], s1 = rowptr[d + 1];
    float r0 = 0.f, r1 = 0.f;
    for (unsigned base = s0; base < s1; base += 4) {
        unsigned nb = s1 - base; if (nb > 4) nb = 4;
        int sidx[4];
#pragma unroll
        for (int i = 0; i < 4; ++i)
            sidx[i] = epair[base + ((unsigned)i < nb ? (unsigned)i : nb - 1)].x;
        unsigned z[4];
#pragma unroll
        for (int i = 0; i < 4; ++i) z[i] = Zp[(size_t)sidx[i] * 64 + l];
#pragma unroll
        for (int i = 0; i < 4; ++i)
            if ((unsigned)i < nb) { r0 += bf2f(z[i] & 0xffffu); r1 += bf2f(z[i] >> 16); }
    }
    int cnt = (int)(s1 - s0);
    float inv = 1.0f / (float)(cnt > 0 ? cnt : 1);
    r0 *= inv; r1 *= inv;
    unsigned* ap = accp + (size_t)d * 64 + l;
    if (accum) { unsigned o = *ap; r0 += bf2f(o & 0xffffu); r1 += bf2f(o >> 16); }
    *ap = pk2(r0, r1);
}

// ---------------------------------------------------------------------------
// GAT gather, single pass, batch-4, shift-free softmax, ef packed bf16.
// ---------------------------------------------------------------------------
template <bool HAS_EF>
__global__ __launch_bounds__(256) void gat_gather(
    const unsigned* __restrict__ rowptr, const int2* __restrict__ epair,
    const unsigned* __restrict__ Zp,
    const float* __restrict__ ls, const float* __restrict__ ld,
    const uint2* __restrict__ ef4p,
    unsigned* __restrict__ accp, int n_nodes, int accum)
{
    int t = threadIdx.x, w = t >> 6, l = t & 63;
    int d = blockIdx.x * 4 + w;
    if (d >= n_nodes) return;
    int hs = l >> 5;  // lo head = hs, hi head = 2+hs
    float4 ldv4 = *(const float4*)(ld + (size_t)d * 4);
    float ldlo = hs ? ldv4.y : ldv4.x;
    float ldhi = hs ? ldv4.w : ldv4.z;
    unsigned s0 = rowptr[d], s1 = rowptr[d + 1];
    float r0 = 0.f, r1 = 0.f, dlo = 0.f, dhi = 0.f;
    for (unsigned base = s0; base < s1; base += 4) {
        unsigned nb = s1 - base; if (nb > 4) nb = 4;
        int sidx[4]; unsigned ci[4];
#pragma unroll
        for (int i = 0; i < 4; ++i) {
            ci[i] = base + ((unsigned)i < nb ? (unsigned)i : nb - 1);
            sidx[i] = epair[ci[i]].x;
        }
        unsigned z[4]; float4 lsv[4]; uint2 e4[4];
#pragma unroll
        for (int i = 0; i < 4; ++i) {
            z[i] = Zp[(size_t)sidx[i] * 64 + l];
            lsv[i] = *(const float4*)(ls + (size_t)sidx[i] * 4);
            if (HAS_EF) e4[i] = ef4p[ci[i]];
        }
#pragma unroll
        for (int i = 0; i < 4; ++i) {
            if ((unsigned)i >= nb) break;
            float glo = (hs ? lsv[i].y : lsv[i].x) + ldlo;
            float ghi = (hs ? lsv[i].w : lsv[i].z) + ldhi;
            if (HAS_EF) {
                glo += bf2f(hs ? (e4[i].x >> 16) : (e4[i].x & 0xffffu));
                ghi += bf2f(hs ? (e4[i].y >> 16) : (e4[i].y & 0xffffu));
            }
            glo = glo > 0.f ? glo : 0.2f * glo;
            ghi = ghi > 0.f ? ghi : 0.2f * ghi;
            float xlo = __expf(glo), xhi = __expf(ghi);
            r0 += xlo * bf2f(z[i] & 0xffffu); dlo += xlo;
            r1 += xhi * bf2f(z[i] >> 16);     dhi += xhi;
        }
    }
    r0 /= fmaxf(dlo, 1e-9f);
    r1 /= fmaxf(dhi, 1e-9f);
    unsigned* ap = accp + (size_t)d * 64 + l;
    if (accum) { unsigned o = *ap; r0 += bf2f(o & 0xffffu); r1 += bf2f(o >> 16); }
    *ap = pk2(r0, r1);
}

// ---------------------------------------------------------------------------
// FFN v4 (unchanged from round 4): double-buffered weight LDS, per-wave
// swizzled hidden transpose.
// ---------------------------------------------------------------------------
__global__ __launch_bounds__(256, 2) void ffn_v4(
    const float* __restrict__ h, const unsigned* __restrict__ accp,
    const float* __restrict__ g, const float* __restrict__ b,
    const unsigned short* __restrict__ w1t, const float* __restrict__ b1,
    const unsigned short* __restrict__ w2t, const float* __restrict__ b2,
    float* __restrict__ out, float invC)
{
    __shared__ unsigned short WB[2][16384];
    __shared__ float HW[4][1024];
    int t = threadIdx.x, w = t >> 6, l = t & 63;
    int l15 = l & 15, lq = l >> 4;
    size_t rw = (size_t)blockIdx.x * 64 + w * 16;
    size_t myrow = rw + l15;
    float* myHW = HW[w];

    const unsigned* ap = accp + myrow * 64 + lq * 8;
    uint4 ua0 = *(const uint4*)(ap);
    uint4 ua1 = *(const uint4*)(ap + 4);
    uint4 ub0 = *(const uint4*)(ap + 32);
    uint4 ub1 = *(const uint4*)(ap + 36);
    const float* hp = h + myrow * 128 + lq * 8;
    float4 hf[4][2];
    hf[0][0] = *(const float4*)(hp);      hf[0][1] = *(const float4*)(hp + 4);
    hf[1][0] = *(const float4*)(hp + 32); hf[1][1] = *(const float4*)(hp + 36);
    hf[2][0] = *(const float4*)(hp + 64); hf[2][1] = *(const float4*)(hp + 68);
    hf[3][0] = *(const float4*)(hp + 96); hf[3][1] = *(const float4*)(hp + 100);
    unsigned ua[8] = {ua0.x, ua0.y, ua0.z, ua0.w, ua1.x, ua1.y, ua1.z, ua1.w};
    unsigned ub[8] = {ub0.x, ub0.y, ub0.z, ub0.w, ub1.x, ub1.y, ub1.z, ub1.w};
    float hv[4][8];
#pragma unroll
    for (int j = 0; j < 8; ++j) {
        hv[0][j] = ((const float*)hf[0])[j] + bf2f(ua[j] & 0xffffu) * invC;
        hv[1][j] = ((const float*)hf[1])[j] + bf2f(ub[j] & 0xffffu) * invC;
        hv[2][j] = ((const float*)hf[2])[j] + bf2f(ua[j] >> 16) * invC;
        hv[3][j] = ((const float*)hf[3])[j] + bf2f(ub[j] >> 16) * invC;
    }
    float s = 0.f;
#pragma unroll
    for (int ks = 0; ks < 4; ++ks)
#pragma unroll
        for (int j = 0; j < 8; ++j) s += hv[ks][j];
    s += __shfl_xor(s, 16); s += __shfl_xor(s, 32);
    float mean = s * (1.0f / 128.0f);
    float v = 0.f;
#pragma unroll
    for (int ks = 0; ks < 4; ++ks)
#pragma unroll
        for (int j = 0; j < 8; ++j) { float dd = hv[ks][j] - mean; v += dd * dd; }
    v += __shfl_xor(v, 16); v += __shfl_xor(v, 32);
    float rstd = rsqrtf(v * (1.0f / 128.0f) + 1e-5f);
    bf16x8 af[4];
#pragma unroll
    for (int ks = 0; ks < 4; ++ks) {
        int col0 = ks * 32 + lq * 8;
        float y[8];
#pragma unroll
        for (int j = 0; j < 8; ++j)
            y[j] = g[col0 + j] * (hv[ks][j] - mean) * rstd + b[col0 + j];
        af[ks] = pack8(y);
    }

#pragma unroll
    for (int i = 0; i < 4; ++i) {
        gll16(w1t + i * 2048 + t * 8, (char*)WB[0] + i * 4096 + t * 16);
        gll16(w2t + i * 2048 + t * 8, (char*)WB[0] + 16384 + i * 4096 + t * 16);
    }
    f32x4 facc[8];
#pragma unroll
    for (int n = 0; n < 8; ++n) facc[n] = (f32x4){0.f, 0.f, 0.f, 0.f};
    __syncthreads();

    int buf = 0;
    int swR = (l15 & 7) << 2;
    for (int ch = 0; ch < 8; ++ch) {
        if (ch < 7) {
            const unsigned short* s1p = w1t + (ch + 1) * 8192;
            const unsigned short* s2p = w2t + (ch + 1) * 8192;
#pragma unroll
            for (int i = 0; i < 4; ++i) {
                gll16(s1p + i * 2048 + t * 8, (char*)WB[buf ^ 1] + i * 4096 + t * 16);
                gll16(s2p + i * 2048 + t * 8, (char*)WB[buf ^ 1] + 16384 + i * 4096 + t * 16);
            }
        }
        f32x4 acc1[4];
#pragma unroll
        for (int n = 0; n < 4; ++n) acc1[n] = (f32x4){0.f, 0.f, 0.f, 0.f};
#pragma unroll
        for (int ks = 0; ks < 4; ++ks)
#pragma unroll
            for (int nf = 0; nf < 4; ++nf) {
                bf16x8 bw = *(const bf16x8*)(WB[buf] + ((nf * 4 + ks) * 64 + l) * 8);
                acc1[nf] = __builtin_amdgcn_mfma_f32_16x16x32_bf16(af[ks], bw, acc1[nf], 0, 0, 0);
            }
#pragma unroll
        for (int nf = 0; nf < 4; ++nf) {
            float bv = b1[ch * 64 + nf * 16 + l15];
#pragma unroll
            for (int reg = 0; reg < 4; ++reg) {
                int row = lq * 4 + reg;
                float x = acc1[nf][reg] + bv;
                float ge = 0.5f * x * (1.0f + erff(x * 0.70710678118654752f));
                myHW[row * 64 + ((nf * 16 + l15) ^ ((row & 7) << 2))] = ge;
            }
        }
#pragma unroll
        for (int ks2 = 0; ks2 < 2; ++ks2) {
            int cb = ks2 * 32 + lq * 8;
            f32x4 x0 = *(const f32x4*)(myHW + l15 * 64 + (cb ^ swR));
            f32x4 x1 = *(const f32x4*)(myHW + l15 * 64 + ((cb + 4) ^ swR));
            bf16x8 a2 = pack8v(x0, x1);
#pragma unroll
            for (int nf = 0; nf < 8; ++nf) {
                bf16x8 bw = *(const bf16x8*)(WB[buf] + 8192 + ((ks2 * 8 + nf) * 64 + l) * 8);
                facc[nf] = __builtin_amdgcn_mfma_f32_16x16x32_bf16(a2, bw, facc[nf], 0, 0, 0);
            }
        }
        __syncthreads();
        buf ^= 1;
    }
#pragma unroll
    for (int nf = 0; nf < 8; ++nf) {
        int col = nf * 16 + l15;
        float bv = b2[col];
        int ci = (col < 64) ? col : col - 64;
        bool hi = col >= 64;
#pragma unroll
        for (int reg = 0; reg < 4; ++reg) {
            size_t row = rw + lq * 4 + reg;
            unsigned pv = accp[row * 64 + ci];
            float av = bf2f(hi ? (pv >> 16) : (pv & 0xffffu));
            out[row * 128 + col] = h[row * 128 + col] + av * invC + facc[nf][reg] + bv;
        }
    }
}

// ---------------------------------------------------------------------------
extern "C" void kernel_launch(void* const* d_in, const int* in_sizes, int n_in,
                              void* d_out, int out_size, void* d_ws, size_t ws_size,
                              hipStream_t stream)
{
    const float* h_enz  = (const float*)d_in[0];
    const float* h_met  = (const float*)d_in[1];
    const float* h_rxn  = (const float*)d_in[2];
    const float* ef_mod = (const float*)d_in[3];
    const float* ef_sig = (const float*)d_in[4];
    const float* ef_brg = (const float*)d_in[5];
    const float* ef_trn = (const float*)d_in[6];
    const float* ln1_g  = (const float*)d_in[7];
    const float* ln1_b  = (const float*)d_in[8];
    const float* ln2_g  = (const float*)d_in[9];
    const float* ln2_b  = (const float*)d_in[10];
    const float* wp     = (const float*)d_in[11];
    const float* bp     = (const float*)d_in[12];
    const float* wl     = (const float*)d_in[13];
    const float* a_src  = (const float*)d_in[14];
    const float* a_dst  = (const float*)d_in[15];
    const float* we     = (const float*)d_in[16];
    const float* a_edge = (const float*)d_in[17];
    const float* w1     = (const float*)d_in[18];
    const float* b1     = (const float*)d_in[19];
    const float* w2     = (const float*)d_in[20];
    const float* b2     = (const float*)d_in[21];
    const int* src_sub  = (const int*)d_in[22];
    const int* dst_sub  = (const int*)d_in[23];
    const int* src_prod = (const int*)d_in[24];
    const int* dst_prod = (const int*)d_in[25];
    const int* src_cat  = (const int*)d_in[26];
    const int* dst_cat  = (const int*)d_in[27];
    const int* src_mod  = (const int*)d_in[28];
    const int* dst_mod  = (const int*)d_in[29];
    const int* src_reg  = (const int*)d_in[30];
    const int* dst_reg  = (const int*)d_in[31];
    const int* src_sig  = (const int*)d_in[32];
    const int* dst_sig  = (const int*)d_in[33];
    const int* src_brg  = (const int*)d_in[34];
    const int* dst_brg  = (const int*)d_in[35];
    const int* src_trn  = (const int*)d_in[36];
    const int* dst_trn  = (const int*)d_in[37];
    float* out = (float*)d_out;

    // workspace (~97 MB; proven budget >= 116.6 MB)
    char* p = (char*)d_ws;
    unsigned* accp = (unsigned*)p;            p += (size_t)NTOT * 64 * 4;
    unsigned* Zp   = (unsigned*)p;            p += (size_t)NM * 64 * 4;
    float* lsb  = (float*)p;                  p += (size_t)NM * 4 * 4;
    float* ldb  = (float*)p;                  p += (size_t)NM * 4 * 4;
    float* ld3b = (float*)p;                  p += (size_t)NR * 4 * 4;
    float* ld5b = (float*)p;                  p += (size_t)NE * 4 * 4;
    unsigned short* wbf = (unsigned short*)p; p += (size_t)524288 * 2;
    unsigned short* wq  = (unsigned short*)p; p += (size_t)7 * 2048 * 2;
    unsigned* hist = (unsigned*)p;            p += (size_t)8 * NDPAD * 4;
    unsigned* rowptr = (unsigned*)p;          p += (size_t)8 * RPS * 4;
    int2* epair = (int2*)p;                   p += (size_t)8 * E2 * 8;
    unsigned long long* bukbuf = (unsigned long long*)p; p += (size_t)8 * E2 * 8;
    uint2* ef4p = (uint2*)p;                  p += (size_t)4 * E2 * 8;
    unsigned* bcnt = (unsigned*)p;            p += 2048 * 4;
    unsigned* bbase = (unsigned*)p;           p += 2049 * 4;
    unsigned* bcur = (unsigned*)p;            p += 2048 * 4;
    unsigned* blksum = (unsigned*)p;          p += (size_t)8 * 256 * 4;
    if (ws_size < (size_t)(p - (char*)d_ws)) return;

    unsigned* nrm32 = (unsigned*)d_out;
    const unsigned short* nbf_enz = (const unsigned short*)d_out;
    const unsigned short* nbf_met = nbf_enz + (size_t)NE * 128;
    const unsigned short* nbf_rxn = nbf_enz + (size_t)(NE + NM) * 128;
    unsigned* acc_enz = accp;
    unsigned* acc_met = accp + (size_t)NE * 64;
    unsigned* acc_rxn = accp + (size_t)(NE + NM) * 64;

    P8 dsts, srcs;
    dsts.a[0] = dst_sub;  srcs.a[0] = src_sub;
    dsts.a[1] = dst_prod; srcs.a[1] = src_prod;
    dsts.a[2] = dst_cat;  srcs.a[2] = src_cat;
    dsts.a[3] = dst_mod;  srcs.a[3] = src_mod;
    dsts.a[4] = dst_reg;  srcs.a[4] = src_reg;
    dsts.a[5] = dst_sig;  srcs.a[5] = src_sig;
    dsts.a[6] = dst_brg;  srcs.a[6] = src_brg;
    dsts.a[7] = dst_trn;  srcs.a[7] = src_trn;

    // ---- prep: weights, LN1, bucketed CSR build
    hipMemsetAsync(bcnt, 0, 2048 * 4, stream);
    convw<<<2048, 256, 0, stream>>>(wp, wl, w1, w2, wbf);
    ln1_kernel<<<NTOT / 4, 256, 0, stream>>>(h_enz, h_met, h_rxn, ln1_g, ln1_b, nrm32);
    wqk<<<28, 256, 0, stream>>>(wl, a_src, a_dst, wq);
    bucket_count<<<1024, 256, 0, stream>>>(dsts, bcnt);
    scanB<<<1, 256, 0, stream>>>(bcnt, bbase, bcur);
    bucket_fill<<<1024, 256, 0, stream>>>(dsts, srcs, bcur, bukbuf);
    bucket_hist<<<2048, 256, 0, stream>>>(bukbuf, bbase, hist);
    scan1<<<2048, 256, 0, stream>>>(hist, rowptr, blksum);
    scan2<<<8, 256, 0, stream>>>(blksum, rowptr);
    scan3<<<2048, 256, 0, stream>>>(rowptr, blksum);
    bucket_place<<<2048, 256, 0, stream>>>(bukbuf, bbase, rowptr, epair);
    efpre<<<4096, 256, 0, stream>>>(epair, ef_mod, ef_sig, ef_brg, ef_trn, we, a_edge, ef4p);

#define RP(r) (rowptr + (size_t)(r) * RPS)
#define EP(r) (epair + (size_t)(r) * E2)
#define WQS(s) (wq + (size_t)(s) * 2048)
#define EF4(er) (ef4p + (size_t)(er) * E2)

    // ---- rel 0: substrate_of (met->rxn), phys wp0
    gemm_v2<0, true><<<NM / 128, 256, 0, stream>>>(nbf_met, wbf + 0 * 16384, bp + 0, Zp,
                                                   nullptr, nullptr, nullptr);
    phys_gather<<<NR / 4, 256, 0, stream>>>(RP(0), EP(0), Zp, acc_rxn, NR, 0);
    // ---- rel 1: produces (rxn->met), phys wp1 (+ rel3's dst logits via WQ site0)
    gemm_v2<1, true><<<NR / 128, 256, 0, stream>>>(nbf_rxn, wbf + 1 * 16384, bp + 128, Zp,
                                                   WQS(0), ld3b, nullptr);
    phys_gather<<<NM / 4, 256, 0, stream>>>(RP(1), EP(1), Zp, acc_met, NM, 0);
    // ---- rel 2: catalyzes (enz->rxn), phys wp2 (+ rel5's dst logits, site1)
    gemm_v2<1, true><<<NE / 128, 256, 0, stream>>>(nbf_enz, wbf + 2 * 16384, bp + 256, Zp,
                                                   WQS(1), ld5b, nullptr);
    phys_gather<<<NR / 4, 256, 0, stream>>>(RP(2), EP(2), Zp, acc_rxn, NR, 1);

    // ---- rel 3: modulates (enz->rxn), wl0 + ef_mod
    gemm_v2<1, false><<<NE / 128, 256, 0, stream>>>(nbf_enz, wbf + 3 * 16384, nullptr, Zp,
                                                    WQS(2), lsb, nullptr);
    gat_gather<true><<<NR / 4, 256, 0, stream>>>(RP(3), EP(3), Zp, lsb, ld3b, EF4(0),
                                                 acc_rxn, NR, 1);
    // ---- rel 4: regulates (enz->enz), wl1, no ef
    gemm_v2<2, false><<<NE / 128, 256, 0, stream>>>(nbf_enz, wbf + 4 * 16384, nullptr, Zp,
                                                    WQS(3), lsb, ldb);
    gat_gather<false><<<NE / 4, 256, 0, stream>>>(RP(4), EP(4), Zp, lsb, ldb, nullptr,
                                                  acc_enz, NE, 0);
    // ---- rel 5: signaling (met->enz), wl2 + ef_sig
    gemm_v2<1, false><<<NM / 128, 256, 0, stream>>>(nbf_met, wbf + 5 * 16384, nullptr, Zp,
                                                    WQS(4), lsb, nullptr);
    gat_gather<true><<<NE / 4, 256, 0, stream>>>(RP(5), EP(5), Zp, lsb, ld5b, EF4(1),
                                                 acc_enz, NE, 1);
    // ---- rel 6: bridges (met->met), wl3 + ef_brg
    gemm_v2<2, false><<<NM / 128, 256, 0, stream>>>(nbf_met, wbf + 6 * 16384, nullptr, Zp,
                                                    WQS(5), lsb, ldb);
    gat_gather<true><<<NM / 4, 256, 0, stream>>>(RP(6), EP(6), Zp, lsb, ldb, EF4(2),
                                                 acc_met, NM, 1);
    // ---- rel 7: transports_to (met->met), wl4 + ef_trn
    gemm_v2<2, false><<<NM / 128, 256, 0, stream>>>(nbf_met, wbf + 7 * 16384, nullptr, Zp,
                                                    WQS(6), lsb, ldb);
    gat_gather<true><<<NM / 4, 256, 0, stream>>>(RP(7), EP(7), Zp, lsb, ldb, EF4(3),
                                                 acc_met, NM, 1);

    // ---- fused combine + LN2 + FFN (+residual), per node type
    ffn_v4<<<NE / 64, 256, 0, stream>>>(h_enz, acc_enz, ln2_g + 0, ln2_b + 0,
                                        wbf + W1T_OFF + 0 * 65536, b1 + 0,
                                        wbf + W2T_OFF + 0 * 65536, b2 + 0,
                                        out + 0, 0.5f);
    ffn_v4<<<NM / 64, 256, 0, stream>>>(h_met, acc_met, ln2_g + 128, ln2_b + 128,
                                        wbf + W1T_OFF + 1 * 65536, b1 + 512,
                                        wbf + W2T_OFF + 1 * 65536, b2 + 128,
                                        out + (size_t)NE * 128, 1.0f / 3.0f);
    ffn_v4<<<NR / 64, 256, 0, stream>>>(h_rxn, acc_rxn, ln2_g + 256, ln2_b + 256,
                                        wbf + W1T_OFF + 2 * 65536, b1 + 1024,
                                        wbf + W2T_OFF + 2 * 65536, b2 + 256,
                                        out + (size_t)(NE + NM) * 128, 1.0f / 3.0f);
#undef RP
#undef EP
#undef WQS
#undef EF4
}

// Round 6
// 592.837 us; speedup vs baseline: 6.5193x; 1.0932x over previous
//
#include <hip/hip_runtime.h>
#include <cstddef>

#define NE 32768
#define NM 65536
#define NR 49152
#define NTOT 147456
#define E2 262144
#define NDPAD 65536
#define RPS 65537
#define W1T_OFF 131072
#define W2T_OFF 327680

typedef __attribute__((ext_vector_type(8))) short bf16x8;
typedef __attribute__((ext_vector_type(4))) float f32x4;

__device__ __forceinline__ unsigned short f2bf(float x) {
    unsigned u = __float_as_uint(x);
    return (unsigned short)((u + 0x7FFFu + ((u >> 16) & 1u)) >> 16);
}
__device__ __forceinline__ float bf2f(unsigned s) { return __uint_as_float(s << 16); }
__device__ __forceinline__ unsigned pk2(float a, float b) {
    return (unsigned)f2bf(a) | ((unsigned)f2bf(b) << 16);
}
__device__ __forceinline__ bf16x8 pack8(const float* v) {
    union { bf16x8 b; unsigned u[4]; } r;
#pragma unroll
    for (int i = 0; i < 4; ++i) r.u[i] = pk2(v[2 * i], v[2 * i + 1]);
    return r.b;
}
__device__ __forceinline__ bf16x8 pack8v(f32x4 a, f32x4 b) {
    union { bf16x8 v; unsigned u[4]; } r;
    r.u[0] = pk2(a[0], a[1]); r.u[1] = pk2(a[2], a[3]);
    r.u[2] = pk2(b[0], b[1]); r.u[3] = pk2(b[2], b[3]);
    return r.v;
}
__device__ __forceinline__ void gll16(const void* g, void* l) {
    __builtin_amdgcn_global_load_lds(
        (const __attribute__((address_space(1))) void*)g,
        (__attribute__((address_space(3))) void*)l, 16, 0, 0);
}

// ---------------------------------------------------------------------------
// Weights -> bf16 FRAGMENT-PACKED (square mats; w1t nf-major; w2t ks-major).
// ---------------------------------------------------------------------------
__global__ __launch_bounds__(256) void convw(
    const float* __restrict__ wp, const float* __restrict__ wl,
    const float* __restrict__ w1, const float* __restrict__ w2,
    unsigned short* __restrict__ wbf)
{
    int i = blockIdx.x * 256 + threadIdx.x;
    float v;
    if (i < 131072) {
        int mat = i >> 14, r = i & 16383;
        int frag = r >> 9, lane = (r >> 3) & 63, j = r & 7;
        int nf = frag >> 2, ks = frag & 3;
        int n = nf * 16 + (lane & 15);
        int k = ks * 32 + (lane >> 4) * 8 + j;
        const float* src = (mat < 3) ? (wp + mat * 16384) : (wl + (mat - 3) * 16384);
        v = src[k * 128 + n];
    } else if (i < 327680) {
        int ii = i - 131072; int mat = ii >> 16, r = ii & 65535;
        int frag = r >> 9, lane = (r >> 3) & 63, j = r & 7;
        int nf = frag >> 2, ks = frag & 3;
        int n = nf * 16 + (lane & 15);
        int k = ks * 32 + (lane >> 4) * 8 + j;
        v = w1[mat * 65536 + k * 512 + n];
    } else {
        int ii = i - 327680; int mat = ii >> 16, r = ii & 65535;
        int frag = r >> 9, lane = (r >> 3) & 63, j = r & 7;
        int ks = frag >> 3, nf = frag & 7;
        int n = nf * 16 + (lane & 15);
        int k = ks * 32 + (lane >> 4) * 8 + j;
        v = w2[mat * 65536 + k * 128 + n];
    }
    wbf[i] = f2bf(v);
}

// ---------------------------------------------------------------------------
// WQ[site] = W . a  (128 x 8 logit-fold matrices), fragment-packed.
// ---------------------------------------------------------------------------
__global__ __launch_bounds__(256) void wqk(
    const float* __restrict__ wl, const float* __restrict__ a_src,
    const float* __restrict__ a_dst, unsigned short* __restrict__ wq)
{
    const int wi[7]  = {0, 2, 0, 1, 2, 3, 4};
    const int loi[7] = {0, 2, 0, 1, 2, 3, 4};
    const int lod[7] = {1, 1, 0, 0, 0, 0, 0};
    const int hii[7] = {-1, -1, -1, 1, -1, 3, 4};
    int site = blockIdx.x >> 2, ks = blockIdx.x & 3, t = threadIdx.x;
    const float* W = wl + wi[site] * 16384;
#pragma unroll
    for (int rep = 0; rep < 2; ++rep) {
        int e = t * 2 + rep;
        int lane = e >> 3, j = e & 7;
        int n = lane & 15;
        int k = ks * 32 + (lane >> 4) * 8 + j;
        float v = 0.f;
        if (n < 4) {
            const float* a = (lod[site] ? a_dst : a_src) + loi[site] * 128;
#pragma unroll 8
            for (int d = 0; d < 32; ++d) v += W[k * 128 + n * 32 + d] * a[n * 32 + d];
        } else if (n < 8 && hii[site] >= 0) {
            const float* a = a_dst + hii[site] * 128;
            int hh = n - 4;
#pragma unroll 8
            for (int d = 0; d < 32; ++d) v += W[k * 128 + hh * 32 + d] * a[hh * 32 + d];
        }
        wq[((site * 4 + ks) * 64 + lane) * 8 + j] = f2bf(v);
    }
}

// ---------------------------------------------------------------------------
__global__ __launch_bounds__(256) void ln1_kernel(
    const float* __restrict__ he, const float* __restrict__ hm, const float* __restrict__ hr,
    const float* __restrict__ g, const float* __restrict__ b, unsigned* __restrict__ nout)
{
    int row  = blockIdx.x * 4 + (threadIdx.x >> 6);
    int lane = threadIdx.x & 63;
    const float* src; int ti; int lr;
    if (row < NE)           { src = he; ti = 0; lr = row; }
    else if (row < NE + NM) { src = hm; ti = 1; lr = row - NE; }
    else                    { src = hr; ti = 2; lr = row - NE - NM; }
    float2 x = *(const float2*)(src + (size_t)lr * 128 + lane * 2);
    float s = x.x + x.y;
#pragma unroll
    for (int o = 32; o; o >>= 1) s += __shfl_xor(s, o);
    float mean = s * (1.0f / 128.0f);
    float dx = x.x - mean, dy = x.y - mean;
    float v = dx * dx + dy * dy;
#pragma unroll
    for (int o = 32; o; o >>= 1) v += __shfl_xor(v, o);
    float rstd = rsqrtf(v * (1.0f / 128.0f) + 1e-5f);
    int c = lane * 2;
    float y0 = g[ti * 128 + c]     * dx * rstd + b[ti * 128 + c];
    float y1 = g[ti * 128 + c + 1] * dy * rstd + b[ti * 128 + c + 1];
    nout[(size_t)row * 64 + lane] = pk2(y0, y1);
}

// ---------------------------------------------------------------------------
// GEMM + optional fused logits (unchanged from round 5).
// ---------------------------------------------------------------------------
template <int LOG, bool BIAS>
__global__ __launch_bounds__(256) void gemm_v2(
    const unsigned short* __restrict__ A, const unsigned short* __restrict__ Wt,
    const float* __restrict__ bias, unsigned* __restrict__ Zp,
    const unsigned short* __restrict__ WQ, float* __restrict__ oa, float* __restrict__ ob)
{
    __shared__ unsigned short WL[16384];
    int t = threadIdx.x, w = t >> 6, l = t & 63;
    int l15 = l & 15, lq = l >> 4;
#pragma unroll
    for (int i = 0; i < 8; ++i)
        gll16(Wt + i * 2048 + t * 8, (char*)WL + i * 4096 + t * 16);
    size_t row0 = (size_t)blockIdx.x * 128 + w * 32;
    f32x4 acc[2][8]; f32x4 accl[2];
#pragma unroll
    for (int r = 0; r < 2; ++r) {
        accl[r] = (f32x4){0.f, 0.f, 0.f, 0.f};
#pragma unroll
        for (int n = 0; n < 8; ++n) acc[r][n] = (f32x4){0.f, 0.f, 0.f, 0.f};
    }
    bf16x8 qf[4];
    if constexpr (LOG >= 1) {
#pragma unroll
        for (int ks = 0; ks < 4; ++ks) qf[ks] = *(const bf16x8*)(WQ + (ks * 64 + l) * 8);
    }
    __syncthreads();
#pragma unroll
    for (int ks = 0; ks < 4; ++ks) {
        int k0 = ks * 32 + lq * 8;
        bf16x8 a0 = *(const bf16x8*)(A + (row0 + l15) * 128 + k0);
        bf16x8 a1 = *(const bf16x8*)(A + (row0 + 16 + l15) * 128 + k0);
#pragma unroll
        for (int n = 0; n < 8; ++n) {
            bf16x8 bw = *(const bf16x8*)(WL + ((n * 4 + ks) * 64 + l) * 8);
            acc[0][n] = __builtin_amdgcn_mfma_f32_16x16x32_bf16(a0, bw, acc[0][n], 0, 0, 0);
            acc[1][n] = __builtin_amdgcn_mfma_f32_16x16x32_bf16(a1, bw, acc[1][n], 0, 0, 0);
        }
        if constexpr (LOG >= 1) {
            accl[0] = __builtin_amdgcn_mfma_f32_16x16x32_bf16(a0, qf[ks], accl[0], 0, 0, 0);
            accl[1] = __builtin_amdgcn_mfma_f32_16x16x32_bf16(a1, qf[ks], accl[1], 0, 0, 0);
        }
    }
#pragma unroll
    for (int n = 0; n < 4; ++n) {
        float bl = BIAS ? bias[n * 16 + l15] : 0.f;
        float bh = BIAS ? bias[n * 16 + l15 + 64] : 0.f;
#pragma unroll
        for (int r = 0; r < 2; ++r)
#pragma unroll
            for (int reg = 0; reg < 4; ++reg) {
                size_t row = row0 + r * 16 + lq * 4 + reg;
                Zp[row * 64 + n * 16 + l15] = pk2(acc[r][n][reg] + bl, acc[r][n + 4][reg] + bh);
            }
    }
    if constexpr (LOG >= 1) {
#pragma unroll
        for (int r = 0; r < 2; ++r)
#pragma unroll
            for (int reg = 0; reg < 4; ++reg) {
                size_t row = row0 + r * 16 + lq * 4 + reg;
                if (l15 < 4) oa[row * 4 + l15] = accl[r][reg];
                else if (LOG == 2 && l15 < 8) ob[row * 4 + (l15 - 4)] = accl[r][reg];
            }
    }
}

// ---------------------------------------------------------------------------
// CSR build, two-level bucket partition (unchanged).
// ---------------------------------------------------------------------------
struct P8 { const int* a[8]; };
#define CHUNK 2048

__global__ __launch_bounds__(256) void bucket_count(P8 dsts, unsigned* __restrict__ bcnt)
{
    __shared__ unsigned lh[256];
    int blk = blockIdx.x, rel = blk >> 7, cb = blk & 127, t = threadIdx.x;
    lh[t] = 0; __syncthreads();
    const int* dp = dsts.a[rel] + cb * CHUNK;
#pragma unroll
    for (int it = 0; it < 8; ++it) atomicAdd(&lh[dp[it * 256 + t] >> 8], 1u);
    __syncthreads();
    atomicAdd(&bcnt[rel * 256 + t], lh[t]);
}

__global__ __launch_bounds__(256) void scanB(const unsigned* __restrict__ bcnt,
                                             unsigned* __restrict__ bbase,
                                             unsigned* __restrict__ bcur)
{
    __shared__ unsigned ts[256];
    int t = threadIdx.x;
    unsigned v[8]; unsigned run = 0;
#pragma unroll
    for (int i = 0; i < 8; ++i) { v[i] = bcnt[t * 8 + i]; run += v[i]; }
    ts[t] = run; __syncthreads();
    for (int off = 1; off < 256; off <<= 1) {
        unsigned x = (t >= off) ? ts[t - off] : 0u;
        __syncthreads(); ts[t] += x; __syncthreads();
    }
    unsigned base = ts[t] - run;
#pragma unroll
    for (int i = 0; i < 8; ++i) { bbase[t * 8 + i] = base; bcur[t * 8 + i] = base; base += v[i]; }
    if (t == 255) bbase[2048] = base;
}

__global__ __launch_bounds__(256) void bucket_fill(P8 dsts, P8 srcs,
                                                   unsigned* __restrict__ bcur,
                                                   unsigned long long* __restrict__ bb)
{
    __shared__ unsigned lh[256], lbase[256], lcur[256];
    int blk = blockIdx.x, rel = blk >> 7, cb = blk & 127, t = threadIdx.x;
    lh[t] = 0; lcur[t] = 0; __syncthreads();
    const int* dp = dsts.a[rel] + cb * CHUNK;
    const int* sp = srcs.a[rel] + cb * CHUNK;
    int dv[8];
#pragma unroll
    for (int it = 0; it < 8; ++it) { dv[it] = dp[it * 256 + t]; atomicAdd(&lh[dv[it] >> 8], 1u); }
    __syncthreads();
    lbase[t] = atomicAdd(&bcur[rel * 256 + t], lh[t]);
    __syncthreads();
#pragma unroll
    for (int it = 0; it < 8; ++it) {
        unsigned e = (unsigned)(cb * CHUNK + it * 256 + t);
        unsigned d = (unsigned)dv[it];
        unsigned s = (unsigned)sp[it * 256 + t];
        unsigned pos = atomicAdd(&lcur[d >> 8], 1u);
        bb[lbase[d >> 8] + pos] =
            (unsigned long long)s | ((unsigned long long)d << 16) | ((unsigned long long)e << 32);
    }
}

__global__ __launch_bounds__(256) void bucket_hist(const unsigned long long* __restrict__ bb,
                                                   const unsigned* __restrict__ bbase,
                                                   unsigned* __restrict__ hist)
{
    __shared__ unsigned lh[256];
    int blk = blockIdx.x, rel = blk >> 8, b = blk & 255, t = threadIdx.x;
    lh[t] = 0; __syncthreads();
    unsigned s0 = bbase[blk], s1 = bbase[blk + 1];
    for (unsigned i = s0 + t; i < s1; i += 256)
        atomicAdd(&lh[(unsigned)(bb[i] >> 16) & 255u], 1u);
    __syncthreads();
    hist[(size_t)rel * NDPAD + b * 256 + t] = lh[t];
}

__global__ __launch_bounds__(256) void scan1(const unsigned* __restrict__ hist,
                                             unsigned* __restrict__ rowptr,
                                             unsigned* __restrict__ blksum)
{
    __shared__ unsigned s[256];
    int b = blockIdx.x, rel = b >> 8, c = b & 255, t = threadIdx.x;
    unsigned v = hist[(size_t)rel * NDPAD + c * 256 + t];
    s[t] = v; __syncthreads();
    for (int off = 1; off < 256; off <<= 1) {
        unsigned x = (t >= off) ? s[t - off] : 0u;
        __syncthreads();
        s[t] += x;
        __syncthreads();
    }
    rowptr[(size_t)rel * RPS + c * 256 + t] = s[t] - v;
    if (t == 255) blksum[rel * 256 + c] = s[255];
}

__global__ __launch_bounds__(256) void scan2(unsigned* __restrict__ blksum,
                                             unsigned* __restrict__ rowptr)
{
    __shared__ unsigned s[256];
    int rel = blockIdx.x, t = threadIdx.x;
    unsigned v = blksum[rel * 256 + t];
    s[t] = v; __syncthreads();
    for (int off = 1; off < 256; off <<= 1) {
        unsigned x = (t >= off) ? s[t - off] : 0u;
        __syncthreads();
        s[t] += x;
        __syncthreads();
    }
    blksum[rel * 256 + t] = s[t] - v;
    if (t == 255) rowptr[(size_t)rel * RPS + 65536] = s[255];
}

__global__ __launch_bounds__(256) void scan3(unsigned* __restrict__ rowptr,
                                             const unsigned* __restrict__ blksum)
{
    int b = blockIdx.x, rel = b >> 8, c = b & 255, t = threadIdx.x;
    rowptr[(size_t)rel * RPS + c * 256 + t] += blksum[rel * 256 + c];
}

__global__ __launch_bounds__(256) void bucket_place(const unsigned long long* __restrict__ bb,
                                                    const unsigned* __restrict__ bbase,
                                                    const unsigned* __restrict__ rowptr,
                                                    int2* __restrict__ epair)
{
    __shared__ unsigned lrp[256], lcur[256];
    int blk = blockIdx.x, rel = blk >> 8, b = blk & 255, t = threadIdx.x;
    lrp[t] = rowptr[(size_t)rel * RPS + b * 256 + t];
    lcur[t] = 0; __syncthreads();
    unsigned s0 = bbase[blk], s1 = bbase[blk + 1];
    for (unsigned i = s0 + t; i < s1; i += 256) {
        unsigned long long pk = bb[i];
        unsigned s = (unsigned)pk & 0xffffu;
        unsigned d8 = (unsigned)(pk >> 16) & 255u;
        unsigned e = (unsigned)(pk >> 32);
        unsigned pos = atomicAdd(&lcur[d8], 1u);
        epair[(size_t)rel * E2 + lrp[d8] + pos] = make_int2((int)s, (int)e);
    }
}

// ---------------------------------------------------------------------------
// Per-edge (ef @ M) EDGE-ORDERED (sequential read AND write); gathers index
// it by eid (random 8B within 2.1 MB -> L2-resident).
// ---------------------------------------------------------------------------
__global__ __launch_bounds__(256) void ef4e_kernel(
    const float* __restrict__ efm, const float* __restrict__ efs,
    const float* __restrict__ efb, const float* __restrict__ eft,
    const float* __restrict__ we, const float* __restrict__ ae,
    uint2* __restrict__ ef4e)
{
    __shared__ float M[8][4];
    int b = blockIdx.x, t = threadIdx.x;
    int er = b >> 10;
    const float* ef = (er == 0) ? efm : (er == 1) ? efs : (er == 2) ? efb : eft;
    if (t < 32) {
        int f = t >> 2, hh = t & 3;
        float s = 0.f;
#pragma unroll 8
        for (int d = 0; d < 32; ++d) s += we[er * 1024 + f * 128 + hh * 32 + d] * ae[er * 128 + hh * 32 + d];
        M[f][hh] = s;
    }
    __syncthreads();
    int e = (b & 1023) * 256 + t;
    float4 a = *(const float4*)(ef + (size_t)e * 8);
    float4 c = *(const float4*)(ef + (size_t)e * 8 + 4);
    float o0 = a.x*M[0][0]+a.y*M[1][0]+a.z*M[2][0]+a.w*M[3][0]+c.x*M[4][0]+c.y*M[5][0]+c.z*M[6][0]+c.w*M[7][0];
    float o1 = a.x*M[0][1]+a.y*M[1][1]+a.z*M[2][1]+a.w*M[3][1]+c.x*M[4][1]+c.y*M[5][1]+c.z*M[6][1]+c.w*M[7][1];
    float o2 = a.x*M[0][2]+a.y*M[1][2]+a.z*M[2][2]+a.w*M[3][2]+c.x*M[4][2]+c.y*M[5][2]+c.z*M[6][2]+c.w*M[7][2];
    float o3 = a.x*M[0][3]+a.y*M[1][3]+a.z*M[2][3]+a.w*M[3][3]+c.x*M[4][3]+c.y*M[5][3]+c.z*M[6][3]+c.w*M[7][3];
    uint2 o; o.x = pk2(o0, o1); o.y = pk2(o2, o3);
    ef4e[(size_t)er * E2 + e] = o;
}

// ---------------------------------------------------------------------------
// Segment helpers: batch-8 deep pipelines.
// ---------------------------------------------------------------------------
__device__ __forceinline__ void phys_seg(
    const unsigned* __restrict__ rowptr, const int2* __restrict__ epair,
    const unsigned* __restrict__ Zp, int d, int l, float& r0, float& r1)
{
    unsigned s0 = rowptr[d], s1 = rowptr[d + 1];
    float a0 = 0.f, a1 = 0.f;
    for (unsigned base = s0; base < s1; base += 8) {
        unsigned nb = s1 - base; if (nb > 8) nb = 8;
        int sidx[8];
#pragma unroll
        for (int i = 0; i < 8; ++i)
            sidx[i] = epair[base + ((unsigned)i < nb ? (unsigned)i : nb - 1)].x;
        unsigned z[8];
#pragma unroll
        for (int i = 0; i < 8; ++i) z[i] = Zp[(size_t)sidx[i] * 64 + l];
#pragma unroll
        for (int i = 0; i < 8; ++i)
            if ((unsigned)i < nb) { a0 += bf2f(z[i] & 0xffffu); a1 += bf2f(z[i] >> 16); }
    }
    int cnt = (int)(s1 - s0);
    float inv = 1.0f / (float)(cnt > 0 ? cnt : 1);
    r0 += a0 * inv; r1 += a1 * inv;
}

template <bool HAS_EF>
__device__ __forceinline__ void gat_seg(
    const unsigned* __restrict__ rowptr, const int2* __restrict__ epair,
    const unsigned* __restrict__ Zp, const float* __restrict__ ls,
    const float* __restrict__ ld, const uint2* __restrict__ ef4e,
    int d, int l, int hs, float& r0, float& r1)
{
    float4 ldv4 = *(const float4*)(ld + (size_t)d * 4);
    float ldlo = hs ? ldv4.y : ldv4.x;
    float ldhi = hs ? ldv4.w : ldv4.z;
    unsigned s0 = rowptr[d], s1 = rowptr[d + 1];
    float n0 = 0.f, n1 = 0.f, dlo = 0.f, dhi = 0.f;
    for (unsigned base = s0; base < s1; base += 8) {
        unsigned nb = s1 - base; if (nb > 8) nb = 8;
        int2 ep[8];
#pragma unroll
        for (int i = 0; i < 8; ++i)
            ep[i] = epair[base + ((unsigned)i < nb ? (unsigned)i : nb - 1)];
        unsigned z[8]; float4 lsv[8]; uint2 e4[8];
#pragma unroll
        for (int i = 0; i < 8; ++i) {
            z[i] = Zp[(size_t)ep[i].x * 64 + l];
            lsv[i] = *(const float4*)(ls + (size_t)ep[i].x * 4);
            if (HAS_EF) e4[i] = ef4e[ep[i].y];
        }
#pragma unroll
        for (int i = 0; i < 8; ++i) {
            if ((unsigned)i >= nb) break;
            float glo = (hs ? lsv[i].y : lsv[i].x) + ldlo;
            float ghi = (hs ? lsv[i].w : lsv[i].z) + ldhi;
            if (HAS_EF) {
                glo += bf2f(hs ? (e4[i].x >> 16) : (e4[i].x & 0xffffu));
                ghi += bf2f(hs ? (e4[i].y >> 16) : (e4[i].y & 0xffffu));
            }
            glo = glo > 0.f ? glo : 0.2f * glo;
            ghi = ghi > 0.f ? ghi : 0.2f * ghi;
            float xlo = __expf(glo), xhi = __expf(ghi);
            n0 += xlo * bf2f(z[i] & 0xffffu); dlo += xlo;
            n1 += xhi * bf2f(z[i] >> 16);     dhi += xhi;
        }
    }
    r0 += n0 / fmaxf(dlo, 1e-9f);
    r1 += n1 / fmaxf(dhi, 1e-9f);
}

// ---------------------------------------------------------------------------
// Gather kernels: single + dual-relation fused (one acc write per target).
// ---------------------------------------------------------------------------
template <bool ACC>
__global__ __launch_bounds__(256) void phys_gather(
    const unsigned* __restrict__ rowptr, const int2* __restrict__ epair,
    const unsigned* __restrict__ Zp, unsigned* __restrict__ accp, int n_nodes)
{
    int t = threadIdx.x, w = t >> 6, l = t & 63;
    int d = blockIdx.x * 4 + w;
    if (d >= n_nodes) return;
    float r0 = 0.f, r1 = 0.f;
    phys_seg(rowptr, epair, Zp, d, l, r0, r1);
    unsigned* ap = accp + (size_t)d * 64 + l;
    if (ACC) { unsigned o = *ap; r0 += bf2f(o & 0xffffu); r1 += bf2f(o >> 16); }
    *ap = pk2(r0, r1);
}

template <bool ACC>
__global__ __launch_bounds__(256) void dual_phys(
    const unsigned* __restrict__ rpA, const int2* __restrict__ epA,
    const unsigned* __restrict__ ZA,
    const unsigned* __restrict__ rpB, const int2* __restrict__ epB,
    const unsigned* __restrict__ ZB,
    unsigned* __restrict__ accp, int n_nodes)
{
    int t = threadIdx.x, w = t >> 6, l = t & 63;
    int d = blockIdx.x * 4 + w;
    if (d >= n_nodes) return;
    float r0 = 0.f, r1 = 0.f;
    phys_seg(rpA, epA, ZA, d, l, r0, r1);
    phys_seg(rpB, epB, ZB, d, l, r0, r1);
    unsigned* ap = accp + (size_t)d * 64 + l;
    if (ACC) { unsigned o = *ap; r0 += bf2f(o & 0xffffu); r1 += bf2f(o >> 16); }
    *ap = pk2(r0, r1);
}

template <bool EF, bool ACC>
__global__ __launch_bounds__(256) void gat_gather(
    const unsigned* __restrict__ rowptr, const int2* __restrict__ epair,
    const unsigned* __restrict__ Zp, const float* __restrict__ ls,
    const float* __restrict__ ld, const uint2* __restrict__ ef4e,
    unsigned* __restrict__ accp, int n_nodes)
{
    int t = threadIdx.x, w = t >> 6, l = t & 63;
    int d = blockIdx.x * 4 + w;
    if (d >= n_nodes) return;
    int hs = l >> 5;
    float r0 = 0.f, r1 = 0.f;
    gat_seg<EF>(rowptr, epair, Zp, ls, ld, ef4e, d, l, hs, r0, r1);
    unsigned* ap = accp + (size_t)d * 64 + l;
    if (ACC) { unsigned o = *ap; r0 += bf2f(o & 0xffffu); r1 += bf2f(o >> 16); }
    *ap = pk2(r0, r1);
}

template <bool EFA, bool EFB, bool ACC>
__global__ __launch_bounds__(256) void dual_gat(
    const unsigned* __restrict__ rpA, const int2* __restrict__ epA,
    const unsigned* __restrict__ ZA, const float* __restrict__ lsA,
    const float* __restrict__ ldA, const uint2* __restrict__ efA,
    const unsigned* __restrict__ rpB, const int2* __restrict__ epB,
    const unsigned* __restrict__ ZB, const float* __restrict__ lsB,
    const float* __restrict__ ldB, const uint2* __restrict__ efB,
    unsigned* __restrict__ accp, int n_nodes)
{
    int t = threadIdx.x, w = t >> 6, l = t & 63;
    int d = blockIdx.x * 4 + w;
    if (d >= n_nodes) return;
    int hs = l >> 5;
    float r0 = 0.f, r1 = 0.f;
    gat_seg<EFA>(rpA, epA, ZA, lsA, ldA, efA, d, l, hs, r0, r1);
    gat_seg<EFB>(rpB, epB, ZB, lsB, ldB, efB, d, l, hs, r0, r1);
    unsigned* ap = accp + (size_t)d * 64 + l;
    if (ACC) { unsigned o = *ap; r0 += bf2f(o & 0xffffu); r1 += bf2f(o >> 16); }
    *ap = pk2(r0, r1);
}

// ---------------------------------------------------------------------------
// FFN v5: 128 rows/block (2 row-frags/wave) -- halves weight staging traffic,
// doubles compute per stage.  LDS = 64 KB WB + 16 KB HW -> 2 blocks/CU.
// ---------------------------------------------------------------------------
__global__ __launch_bounds__(256, 2) void ffn_v5(
    const float* __restrict__ h, const unsigned* __restrict__ accp,
    const float* __restrict__ g, const float* __restrict__ b,
    const unsigned short* __restrict__ w1t, const float* __restrict__ b1,
    const unsigned short* __restrict__ w2t, const float* __restrict__ b2,
    float* __restrict__ out, float invC)
{
    __shared__ unsigned short WB[2][16384];
    __shared__ float HW[4][1024];
    int t = threadIdx.x, w = t >> 6, l = t & 63;
    int l15 = l & 15, lq = l >> 4;
    size_t rw = (size_t)blockIdx.x * 128 + w * 32;
    float* myHW = HW[w];

    // ---- LN + A-frag pack for both 16-row frags
    bf16x8 af[2][4];
#pragma unroll
    for (int rf = 0; rf < 2; ++rf) {
        size_t myrow = rw + rf * 16 + l15;
        const unsigned* ap = accp + myrow * 64 + lq * 8;
        uint4 ua0 = *(const uint4*)(ap);
        uint4 ua1 = *(const uint4*)(ap + 4);
        uint4 ub0 = *(const uint4*)(ap + 32);
        uint4 ub1 = *(const uint4*)(ap + 36);
        const float* hp = h + myrow * 128 + lq * 8;
        float4 hf[4][2];
        hf[0][0] = *(const float4*)(hp);      hf[0][1] = *(const float4*)(hp + 4);
        hf[1][0] = *(const float4*)(hp + 32); hf[1][1] = *(const float4*)(hp + 36);
        hf[2][0] = *(const float4*)(hp + 64); hf[2][1] = *(const float4*)(hp + 68);
        hf[3][0] = *(const float4*)(hp + 96); hf[3][1] = *(const float4*)(hp + 100);
        unsigned ua[8] = {ua0.x, ua0.y, ua0.z, ua0.w, ua1.x, ua1.y, ua1.z, ua1.w};
        unsigned ub[8] = {ub0.x, ub0.y, ub0.z, ub0.w, ub1.x, ub1.y, ub1.z, ub1.w};
        float hv[4][8];
#pragma unroll
        for (int j = 0; j < 8; ++j) {
            hv[0][j] = ((const float*)hf[0])[j] + bf2f(ua[j] & 0xffffu) * invC;
            hv[1][j] = ((const float*)hf[1])[j] + bf2f(ub[j] & 0xffffu) * invC;
            hv[2][j] = ((const float*)hf[2])[j] + bf2f(ua[j] >> 16) * invC;
            hv[3][j] = ((const float*)hf[3])[j] + bf2f(ub[j] >> 16) * invC;
        }
        float s = 0.f;
#pragma unroll
        for (int ks = 0; ks < 4; ++ks)
#pragma unroll
            for (int j = 0; j < 8; ++j) s += hv[ks][j];
        s += __shfl_xor(s, 16); s += __shfl_xor(s, 32);
        float mean = s * (1.0f / 128.0f);
        float v = 0.f;
#pragma unroll
        for (int ks = 0; ks < 4; ++ks)
#pragma unroll
            for (int j = 0; j < 8; ++j) { float dd = hv[ks][j] - mean; v += dd * dd; }
        v += __shfl_xor(v, 16); v += __shfl_xor(v, 32);
        float rstd = rsqrtf(v * (1.0f / 128.0f) + 1e-5f);
#pragma unroll
        for (int ks = 0; ks < 4; ++ks) {
            int col0 = ks * 32 + lq * 8;
            float y[8];
#pragma unroll
            for (int j = 0; j < 8; ++j)
                y[j] = g[col0 + j] * (hv[ks][j] - mean) * rstd + b[col0 + j];
            af[rf][ks] = pack8(y);
        }
    }

    // ---- stage chunk 0
#pragma unroll
    for (int i = 0; i < 4; ++i) {
        gll16(w1t + i * 2048 + t * 8, (char*)WB[0] + i * 4096 + t * 16);
        gll16(w2t + i * 2048 + t * 8, (char*)WB[0] + 16384 + i * 4096 + t * 16);
    }
    f32x4 facc[2][8];
#pragma unroll
    for (int rf = 0; rf < 2; ++rf)
#pragma unroll
        for (int n = 0; n < 8; ++n) facc[rf][n] = (f32x4){0.f, 0.f, 0.f, 0.f};
    __syncthreads();

    int buf = 0;
    int swR = (l15 & 7) << 2;
    for (int ch = 0; ch < 8; ++ch) {
        if (ch < 7) {
            const unsigned short* s1p = w1t + (ch + 1) * 8192;
            const unsigned short* s2p = w2t + (ch + 1) * 8192;
#pragma unroll
            for (int i = 0; i < 4; ++i) {
                gll16(s1p + i * 2048 + t * 8, (char*)WB[buf ^ 1] + i * 4096 + t * 16);
                gll16(s2p + i * 2048 + t * 8, (char*)WB[buf ^ 1] + 16384 + i * 4096 + t * 16);
            }
        }
        // gemm1: 32 rows x 64 hidden cols
        f32x4 acc1[2][4];
#pragma unroll
        for (int rf = 0; rf < 2; ++rf)
#pragma unroll
            for (int n = 0; n < 4; ++n) acc1[rf][n] = (f32x4){0.f, 0.f, 0.f, 0.f};
#pragma unroll
        for (int ks = 0; ks < 4; ++ks)
#pragma unroll
            for (int nf = 0; nf < 4; ++nf) {
                bf16x8 bw = *(const bf16x8*)(WB[buf] + ((nf * 4 + ks) * 64 + l) * 8);
                acc1[0][nf] = __builtin_amdgcn_mfma_f32_16x16x32_bf16(af[0][ks], bw, acc1[0][nf], 0, 0, 0);
                acc1[1][nf] = __builtin_amdgcn_mfma_f32_16x16x32_bf16(af[1][ks], bw, acc1[1][nf], 0, 0, 0);
            }
        // GELU + transpose + gemm2, per row-frag through the 4KB wave LDS
#pragma unroll
        for (int rf = 0; rf < 2; ++rf) {
#pragma unroll
            for (int nf = 0; nf < 4; ++nf) {
                float bv = b1[ch * 64 + nf * 16 + l15];
#pragma unroll
                for (int reg = 0; reg < 4; ++reg) {
                    int row = lq * 4 + reg;
                    float x = acc1[rf][nf][reg] + bv;
                    float ge = 0.5f * x * (1.0f + erff(x * 0.70710678118654752f));
                    myHW[row * 64 + ((nf * 16 + l15) ^ ((row & 7) << 2))] = ge;
                }
            }
#pragma unroll
            for (int ks2 = 0; ks2 < 2; ++ks2) {
                int cb = ks2 * 32 + lq * 8;
                f32x4 x0 = *(const f32x4*)(myHW + l15 * 64 + (cb ^ swR));
                f32x4 x1 = *(const f32x4*)(myHW + l15 * 64 + ((cb + 4) ^ swR));
                bf16x8 a2 = pack8v(x0, x1);
#pragma unroll
                for (int nf = 0; nf < 8; ++nf) {
                    bf16x8 bw = *(const bf16x8*)(WB[buf] + 8192 + ((ks2 * 8 + nf) * 64 + l) * 8);
                    facc[rf][nf] = __builtin_amdgcn_mfma_f32_16x16x32_bf16(a2, bw, facc[rf][nf], 0, 0, 0);
                }
            }
        }
        __syncthreads();
        buf ^= 1;
    }
    // ---- epilogue
#pragma unroll
    for (int rf = 0; rf < 2; ++rf)
#pragma unroll
        for (int nf = 0; nf < 8; ++nf) {
            int col = nf * 16 + l15;
            float bv = b2[col];
            int ci = col & 63;
            bool hi = col >= 64;
#pragma unroll
            for (int reg = 0; reg < 4; ++reg) {
                size_t row = rw + rf * 16 + lq * 4 + reg;
                unsigned pv = accp[row * 64 + ci];
                float av = bf2f(hi ? (pv >> 16) : (pv & 0xffffu));
                out[row * 128 + col] = h[row * 128 + col] + av * invC + facc[rf][nf][reg] + bv;
            }
        }
}

// ---------------------------------------------------------------------------
extern "C" void kernel_launch(void* const* d_in, const int* in_sizes, int n_in,
                              void* d_out, int out_size, void* d_ws, size_t ws_size,
                              hipStream_t stream)
{
    const float* h_enz  = (const float*)d_in[0];
    const float* h_met  = (const float*)d_in[1];
    const float* h_rxn  = (const float*)d_in[2];
    const float* ef_mod = (const float*)d_in[3];
    const float* ef_sig = (const float*)d_in[4];
    const float* ef_brg = (const float*)d_in[5];
    const float* ef_trn = (const float*)d_in[6];
    const float* ln1_g  = (const float*)d_in[7];
    const float* ln1_b  = (const float*)d_in[8];
    const float* ln2_g  = (const float*)d_in[9];
    const float* ln2_b  = (const float*)d_in[10];
    const float* wp     = (const float*)d_in[11];
    const float* bp     = (const float*)d_in[12];
    const float* wl     = (const float*)d_in[13];
    const float* a_src  = (const float*)d_in[14];
    const float* a_dst  = (const float*)d_in[15];
    const float* we     = (const float*)d_in[16];
    const float* a_edge = (const float*)d_in[17];
    const float* w1     = (const float*)d_in[18];
    const float* b1     = (const float*)d_in[19];
    const float* w2     = (const float*)d_in[20];
    const float* b2     = (const float*)d_in[21];
    const int* src_sub  = (const int*)d_in[22];
    const int* dst_sub  = (const int*)d_in[23];
    const int* src_prod = (const int*)d_in[24];
    const int* dst_prod = (const int*)d_in[25];
    const int* src_cat  = (const int*)d_in[26];
    const int* dst_cat  = (const int*)d_in[27];
    const int* src_mod  = (const int*)d_in[28];
    const int* dst_mod  = (const int*)d_in[29];
    const int* src_reg  = (const int*)d_in[30];
    const int* dst_reg  = (const int*)d_in[31];
    const int* src_sig  = (const int*)d_in[32];
    const int* dst_sig  = (const int*)d_in[33];
    const int* src_brg  = (const int*)d_in[34];
    const int* dst_brg  = (const int*)d_in[35];
    const int* src_trn  = (const int*)d_in[36];
    const int* dst_trn  = (const int*)d_in[37];
    float* out = (float*)d_out;

    // workspace (~108 MB; proven budget >= 116.6 MB)
    char* p = (char*)d_ws;
    unsigned* accp = (unsigned*)p;            p += (size_t)NTOT * 64 * 4;     // 37.75 MB
    unsigned* ZpA  = (unsigned*)p;            p += (size_t)NM * 64 * 4;       // 16.78 MB
    unsigned long long* bukbuf = (unsigned long long*)p;                      // alias:
    unsigned* ZpB  = (unsigned*)p;            p += (size_t)8 * E2 * 8;        // 16.78 MB
    int2* epair = (int2*)p;                   p += (size_t)8 * E2 * 8;        // 16.78 MB
    unsigned* hist = (unsigned*)p;                                            // alias:
    uint2* ef4e = (uint2*)p;                  p += (size_t)4 * E2 * 8;        // 8.39 MB
    float* ls3 = (float*)p;                   p += (size_t)NE * 4 * 4;
    float* ld3 = (float*)p;                   p += (size_t)NR * 4 * 4;
    float* ls4 = (float*)p;                   p += (size_t)NE * 4 * 4;
    float* ld4 = (float*)p;                   p += (size_t)NE * 4 * 4;
    float* ls5 = (float*)p;                   p += (size_t)NM * 4 * 4;
    float* ld5 = (float*)p;                   p += (size_t)NE * 4 * 4;
    float* ls6 = (float*)p;                   p += (size_t)NM * 4 * 4;
    float* ld6 = (float*)p;                   p += (size_t)NM * 4 * 4;
    float* ls7 = (float*)p;                   p += (size_t)NM * 4 * 4;
    float* ld7 = (float*)p;                   p += (size_t)NM * 4 * 4;
    unsigned short* wbf = (unsigned short*)p; p += (size_t)524288 * 2;
    unsigned short* wq  = (unsigned short*)p; p += (size_t)7 * 2048 * 2;
    unsigned* rowptr = (unsigned*)p;          p += (size_t)8 * RPS * 4;
    unsigned* bcnt = (unsigned*)p;            p += 2048 * 4;
    unsigned* bbase = (unsigned*)p;           p += 2049 * 4;
    unsigned* bcur = (unsigned*)p;            p += 2048 * 4;
    unsigned* blksum = (unsigned*)p;          p += (size_t)8 * 256 * 4;
    if (ws_size < (size_t)(p - (char*)d_ws)) return;

    unsigned* nrm32 = (unsigned*)d_out;
    const unsigned short* nbf_enz = (const unsigned short*)d_out;
    const unsigned short* nbf_met = nbf_enz + (size_t)NE * 128;
    const unsigned short* nbf_rxn = nbf_enz + (size_t)(NE + NM) * 128;
    unsigned* acc_enz = accp;
    unsigned* acc_met = accp + (size_t)NE * 64;
    unsigned* acc_rxn = accp + (size_t)(NE + NM) * 64;

    P8 dsts, srcs;
    dsts.a[0] = dst_sub;  srcs.a[0] = src_sub;
    dsts.a[1] = dst_prod; srcs.a[1] = src_prod;
    dsts.a[2] = dst_cat;  srcs.a[2] = src_cat;
    dsts.a[3] = dst_mod;  srcs.a[3] = src_mod;
    dsts.a[4] = dst_reg;  srcs.a[4] = src_reg;
    dsts.a[5] = dst_sig;  srcs.a[5] = src_sig;
    dsts.a[6] = dst_brg;  srcs.a[6] = src_brg;
    dsts.a[7] = dst_trn;  srcs.a[7] = src_trn;

    // ---- prep: weights, LN1, bucketed CSR, edge-ordered ef.M
    hipMemsetAsync(bcnt, 0, 2048 * 4, stream);
    convw<<<2048, 256, 0, stream>>>(wp, wl, w1, w2, wbf);
    ln1_kernel<<<NTOT / 4, 256, 0, stream>>>(h_enz, h_met, h_rxn, ln1_g, ln1_b, nrm32);
    wqk<<<28, 256, 0, stream>>>(wl, a_src, a_dst, wq);
    bucket_count<<<1024, 256, 0, stream>>>(dsts, bcnt);
    scanB<<<1, 256, 0, stream>>>(bcnt, bbase, bcur);
    bucket_fill<<<1024, 256, 0, stream>>>(dsts, srcs, bcur, bukbuf);
    bucket_hist<<<2048, 256, 0, stream>>>(bukbuf, bbase, hist);
    scan1<<<2048, 256, 0, stream>>>(hist, rowptr, blksum);
    scan2<<<8, 256, 0, stream>>>(blksum, rowptr);
    scan3<<<2048, 256, 0, stream>>>(rowptr, blksum);
    bucket_place<<<2048, 256, 0, stream>>>(bukbuf, bbase, rowptr, epair);
    ef4e_kernel<<<4096, 256, 0, stream>>>(ef_mod, ef_sig, ef_brg, ef_trn, we, a_edge, ef4e);

#define RP(r) (rowptr + (size_t)(r) * RPS)
#define EP(r) (epair + (size_t)(r) * E2)
#define WQS(s) (wq + (size_t)(s) * 2048)
#define EF4(er) (ef4e + (size_t)(er) * E2)

    // ---- rxn: rel0 (met, phys) + rel2 (enz, phys) fused; then rel3 (gat)
    gemm_v2<0, true><<<NM / 128, 256, 0, stream>>>(nbf_met, wbf + 0 * 16384, bp + 0, ZpA,
                                                   nullptr, nullptr, nullptr);
    gemm_v2<1, true><<<NE / 128, 256, 0, stream>>>(nbf_enz, wbf + 2 * 16384, bp + 256, ZpB,
                                                   WQS(1), ld5, nullptr);
    dual_phys<false><<<NR / 4, 256, 0, stream>>>(RP(0), EP(0), ZpA, RP(2), EP(2), ZpB,
                                                 acc_rxn, NR);
    // ---- rel1 (rxn->met, phys) init acc_met; gemm also emits rel3 dst logits
    gemm_v2<1, true><<<NR / 128, 256, 0, stream>>>(nbf_rxn, wbf + 1 * 16384, bp + 128, ZpA,
                                                   WQS(0), ld3, nullptr);
    phys_gather<false><<<NM / 4, 256, 0, stream>>>(RP(1), EP(1), ZpA, acc_met, NM);
    // ---- rel3 (enz->rxn, gat + ef) accum acc_rxn
    gemm_v2<1, false><<<NE / 128, 256, 0, stream>>>(nbf_enz, wbf + 3 * 16384, nullptr, ZpB,
                                                    WQS(2), ls3, nullptr);
    gat_gather<true, true><<<NR / 4, 256, 0, stream>>>(RP(3), EP(3), ZpB, ls3, ld3, EF4(0),
                                                       acc_rxn, NR);
    // ---- enz: rel4 (no ef) + rel5 (ef) fused, single write
    gemm_v2<2, false><<<NE / 128, 256, 0, stream>>>(nbf_enz, wbf + 4 * 16384, nullptr, ZpA,
                                                    WQS(3), ls4, ld4);
    gemm_v2<1, false><<<NM / 128, 256, 0, stream>>>(nbf_met, wbf + 5 * 16384, nullptr, ZpB,
                                                    WQS(4), ls5, nullptr);
    dual_gat<false, true, false><<<NE / 4, 256, 0, stream>>>(
        RP(4), EP(4), ZpA, ls4, ld4, nullptr,
        RP(5), EP(5), ZpB, ls5, ld5, EF4(1), acc_enz, NE);
    // ---- met: rel6 + rel7 fused, accum onto rel1's init
    gemm_v2<2, false><<<NM / 128, 256, 0, stream>>>(nbf_met, wbf + 6 * 16384, nullptr, ZpA,
                                                    WQS(5), ls6, ld6);
    gemm_v2<2, false><<<NM / 128, 256, 0, stream>>>(nbf_met, wbf + 7 * 16384, nullptr, ZpB,
                                                    WQS(6), ls7, ld7);
    dual_gat<true, true, true><<<NM / 4, 256, 0, stream>>>(
        RP(6), EP(6), ZpA, ls6, ld6, EF4(2),
        RP(7), EP(7), ZpB, ls7, ld7, EF4(3), acc_met, NM);

    // ---- fused combine + LN2 + FFN (+residual), per node type
    ffn_v5<<<NE / 128, 256, 0, stream>>>(h_enz, acc_enz, ln2_g + 0, ln2_b + 0,
                                         wbf + W1T_OFF + 0 * 65536, b1 + 0,
                                         wbf + W2T_OFF + 0 * 65536, b2 + 0,
                                         out + 0, 0.5f);
    ffn_v5<<<NM / 128, 256, 0, stream>>>(h_met, acc_met, ln2_g + 128, ln2_b + 128,
                                         wbf + W1T_OFF + 1 * 65536, b1 + 512,
                                         wbf + W2T_OFF + 1 * 65536, b2 + 128,
                                         out + (size_t)NE * 128, 1.0f / 3.0f);
    ffn_v5<<<NR / 128, 256, 0, stream>>>(h_rxn, acc_rxn, ln2_g + 256, ln2_b + 256,
                                         wbf + W1T_OFF + 2 * 65536, b1 + 1024,
                                         wbf + W2T_OFF + 2 * 65536, b2 + 256,
                                         out + (size_t)(NE + NM) * 128, 1.0f / 3.0f);
#undef RP
#undef EP
#undef WQS
#undef EF4
}